// Round 9
// baseline (6559.441 us; speedup 1.0000x reference)
//
#include <hip/hip_runtime.h>

#define DEV __device__ __forceinline__

typedef __attribute__((ext_vector_type(4))) int i32x4;

// ---------------------------------------------------------------------------
// TernaryMVAdapter forward on MI355X. Round 9: round-8 numerics (f64-exact,
// absmax floor ~0.035, replay-safe) + bijective XCD-locality swizzle on both
// GEMM kernels. Round-8 post-mortem: k_dgemm FETCH_SIZE=807MB (x_cond=48MB,
// ~17x refetch across XCD-private L2s) == dur x BW -> HBM-refetch-bound.
// Swizzle clusters blocks sharing an operand panel onto one XCD. Pure block
// remap: bitwise-identical outputs, no cross-block deps.
// ---------------------------------------------------------------------------

struct WList { const float* p[37]; long long n[37]; };
struct WOffs { long long o[37]; };

// bijective XCD swizzle (m204 form): HW round-robins block id % 8 across
// XCDs; give XCD k a CONTIGUOUS range of logical tiles. Works for any nwg.
DEV int2 xcd_swz(int gridx)
{
    const int nwg = (int)gridDim.x, b = (int)blockIdx.x;
    const int q = nwg >> 3, r = nwg & 7, xcd = b & 7, idx = b >> 3;
    const int lb = (xcd < r ? xcd*(q+1) : r*(q+1) + (xcd-r)*q) + idx;
    return make_int2(lb % gridx, lb / gridx);   // (x fast, y slow)
}

// ---------------- fused deterministic |w| sums (37 slots) ------------------
__global__ void k_abssum_all(WList wl, double* __restrict__ partials)
{
    const int slot = blockIdx.y;
    const float* w = wl.p[slot];
    const long long n = wl.n[slot];
    __shared__ double sm[256];
    double s = 0.0;
    for (long long i = (long long)blockIdx.x*256 + threadIdx.x; i < n; i += 32LL*256)
        s += (double)fabsf(w[i]);
    sm[threadIdx.x] = s;
    __syncthreads();
    for (int k = 128; k > 0; k >>= 1) {
        if ((int)threadIdx.x < k) sm[threadIdx.x] += sm[threadIdx.x + k];
        __syncthreads();
    }
    if (threadIdx.x == 0) partials[slot*32 + blockIdx.x] = sm[0];
}

__global__ void k_abssum_fin(const double* __restrict__ partials, double* __restrict__ out)
{
    const int slot = blockIdx.x;
    if (threadIdx.x == 0) {
        double s = 0.0;
        for (int i = 0; i < 32; ++i) s += partials[slot*32 + i];
        out[slot] = s;
    }
}

// ---------------- one-time weight ternarization (f64-exact decision) -------
__global__ void k_ternarize(WList wl, WOffs wo, const double* __restrict__ scales,
                            signed char* __restrict__ W8)
{
    const int slot = blockIdx.y;
    const float* w = wl.p[slot];
    const long long n4 = wl.n[slot] >> 2;           // all sizes divisible by 4
    const double dqw = fmax(scales[slot] / (double)wl.n[slot], 1e-5);
    const double thr = 0.5 * dqw;
    signed char* o = W8 + wo.o[slot];
    for (long long i = (long long)blockIdx.x*256 + threadIdx.x; i < n4; i += 64LL*256) {
        float4 v = *reinterpret_cast<const float4*>(w + i*4);
        float we[4] = {v.x, v.y, v.z, v.w};
        char r[4];
#pragma unroll
        for (int e = 0; e < 4; ++e) {
            double wd = (double)we[e];
            r[e] = (char)((wd > thr) - (wd < -thr));
        }
        *reinterpret_cast<char4*>(o + i*4) = make_char4(r[0], r[1], r[2], r[3]);
    }
}

// ---------------- timestep frequency embedding (f64) -----------------------
__global__ void k_temb(const float* __restrict__ t, double* __restrict__ out)
{
    int b = blockIdx.x, j = threadIdx.x;               // 8 x 128
    double fr  = exp(-9.210340371976184 * (double)j / 128.0);
    double ang = (double)t[b] * fr;
    out[b*256 + j]       = cos(ang);
    out[b*256 + 128 + j] = sin(ang);
}

// ---------------- rmsnorm + int8 absmax quant (f64, LDS-free) --------------
template<typename TI>
__global__ void k_rsq8(const TI* __restrict__ x, signed char* __restrict__ q8,
                       double* __restrict__ dscale, int K, int pre_silu)
{
    __shared__ double red[256], red2[256];
    const int row = blockIdx.x, tid = threadIdx.x;
    const TI* xr = x + (size_t)row*K;
    double ss = 0.0, am = 0.0;
    for (int i = tid; i < K; i += 256) {
        double v = (double)xr[i];
        if (pre_silu) v = v / (1.0 + exp(-v));
        ss += v*v; am = fmax(am, fabs(v));
    }
    red[tid] = ss; red2[tid] = am;
    __syncthreads();
    for (int s = 128; s > 0; s >>= 1) {
        if (tid < s) { red[tid] += red[tid+s]; red2[tid] = fmax(red2[tid], red2[tid+s]); }
        __syncthreads();
    }
    double rms = 1.0 / sqrt(red[0]/(double)K + 1e-8);
    double s   = 127.0 / fmax(red2[0]*rms, 1e-5);
    signed char* orow = q8 + (size_t)row*K;
    for (int i = tid; i < K; i += 256) {
        double v = (double)xr[i];
        if (pre_silu) v = v / (1.0 + exp(-v));
        orow[i] = (signed char)(int)fmin(fmax(rint(v*rms*s), -128.0), 127.0);
    }
    if (tid == 0) dscale[row] = s;
}

// ---------------- layernorm(+gb/+mod) + rmsnorm + int8 quant (f64) ---------
__global__ void k_lnq8(const double* __restrict__ x, signed char* __restrict__ q8,
                       double* __restrict__ dscale, int K,
                       const float* __restrict__ gamma, const float* __restrict__ beta,
                       const double* __restrict__ sh, const double* __restrict__ sc,
                       int modstride, double eps)
{
    extern __shared__ double rb[];
    __shared__ double red[256], red2[256];
    const int row = blockIdx.x, tid = threadIdx.x;
    const double* xr = x + (size_t)row*K;
    double s1 = 0.0;
    for (int i = tid; i < K; i += 256) { double v = xr[i]; rb[i] = v; s1 += v; }
    red[tid] = s1; __syncthreads();
    for (int s = 128; s > 0; s >>= 1) { if (tid < s) red[tid] += red[tid+s]; __syncthreads(); }
    double mu = red[0]/(double)K;
    __syncthreads();
    double s2 = 0.0;
    for (int i = tid; i < K; i += 256) { double d = rb[i]-mu; s2 += d*d; }
    red[tid] = s2; __syncthreads();
    for (int s = 128; s > 0; s >>= 1) { if (tid < s) red[tid] += red[tid+s]; __syncthreads(); }
    double r = 1.0 / sqrt(red[0]/(double)K + eps);
    const int bn = row >> 8;
    __syncthreads();
    double ss = 0.0, am = 0.0;
    for (int i = tid; i < K; i += 256) {
        double y = (rb[i]-mu)*r;
        if (gamma) y = y*(double)gamma[i] + (double)beta[i];
        if (sh)    y = y*(1.0 + sc[(size_t)bn*modstride + i]) + sh[(size_t)bn*modstride + i];
        rb[i] = y; ss += y*y; am = fmax(am, fabs(y));
    }
    red[tid] = ss; red2[tid] = am;
    __syncthreads();
    for (int s = 128; s > 0; s >>= 1) {
        if (tid < s) { red[tid] += red[tid+s]; red2[tid] = fmax(red2[tid], red2[tid+s]); }
        __syncthreads();
    }
    double rms = 1.0 / sqrt(red[0]/(double)K + 1e-8);
    double s   = 127.0 / fmax(red2[0]*rms, 1e-5);
    signed char* orow = q8 + (size_t)row*K;
    for (int i = tid; i < K; i += 256)
        orow[i] = (signed char)(int)fmin(fmax(rint(rb[i]*rms*s), -128.0), 127.0);
    if (tid == 0) dscale[row] = s;
}

// ---------------- ogate (rmsnorm*g*sig(g)) + rmsnorm + quant (f64) ---------
__global__ void k_ogateq8(const double* __restrict__ O, const double* __restrict__ G,
                          signed char* __restrict__ q8, double* __restrict__ dscale, int K)
{
    extern __shared__ double rb[];
    __shared__ double red[256], red2[256];
    const int row = blockIdx.x, tid = threadIdx.x;
    const double* orow = O + (size_t)row*K;
    const double* grow = G + (size_t)row*K;
    double ss = 0.0;
    for (int i = tid; i < K; i += 256) { double v = orow[i]; rb[i] = v; ss += v*v; }
    red[tid] = ss; __syncthreads();
    for (int s = 128; s > 0; s >>= 1) { if (tid < s) red[tid] += red[tid+s]; __syncthreads(); }
    double rmso = 1.0 / sqrt(red[0]/(double)K + 1e-8);
    __syncthreads();
    double ss2 = 0.0, am = 0.0;
    for (int i = tid; i < K; i += 256) {
        double g = grow[i];
        double y = rb[i]*rmso * g / (1.0 + exp(-g));
        rb[i] = y; ss2 += y*y; am = fmax(am, fabs(y));
    }
    red[tid] = ss2; red2[tid] = am;
    __syncthreads();
    for (int s = 128; s > 0; s >>= 1) {
        if (tid < s) { red[tid] += red[tid+s]; red2[tid] = fmax(red2[tid], red2[tid+s]); }
        __syncthreads();
    }
    double rms = 1.0 / sqrt(red[0]/(double)K + 1e-8);
    double s   = 127.0 / fmax(red2[0]*rms, 1e-5);
    signed char* qrow = q8 + (size_t)row*K;
    for (int i = tid; i < K; i += 256)
        qrow[i] = (signed char)(int)fmin(fmax(rint(rb[i]*rms*s), -128.0), 127.0);
    if (tid == 0) dscale[row] = s;
}

// ---------------- HGRN gate precompute + lean serial scan ------------------
__global__ void k_gatepre(double* __restrict__ F, double* __restrict__ I, long long n)
{
    long long i = (long long)blockIdx.x*256 + threadIdx.x;
    if (i >= n) return;
    double fp = F[i], ip = I[i];
    double f = 1.0/(1.0+exp(-fp));
    double v = (ip/(1.0+exp(-ip)))*(1.0-f);
    F[i] = f; I[i] = v;
}

__global__ void k_scan2(const double* __restrict__ F, const double* __restrict__ V,
                        double* __restrict__ O, int n_outer, long long outer_stride,
                        int n_inner, long long t_stride, int T)
{
    long long chain = (long long)blockIdx.x*blockDim.x + threadIdx.x;
    if (chain >= (long long)n_outer*n_inner) return;
    long long base = (chain / n_inner)*outer_stride + (chain % n_inner);
    double h = 0.0;
    for (int t = 0; t < T; ++t) {
        long long idx = base + (long long)t*t_stride;
        h = F[idx]*h + V[idx];
        O[idx] = h;
    }
}

// ---------------- misc elementwise (f64) -----------------------------------
__global__ void k_add(const double* __restrict__ a, const double* __restrict__ b,
                      double* __restrict__ o, int n)
{
    int i = blockIdx.x*256 + threadIdx.x;
    if (i < n) o[i] = a[i] + b[i];
}

__global__ void k_resid_attn(double* __restrict__ xt, const double* __restrict__ acc,
                             const double* __restrict__ refo, const double* __restrict__ mod)
{
    int idx = blockIdx.x*256 + threadIdx.x;            // 2048*1152 exact
    int r = idx / 1152, d = idx - r*1152;
    int bn = r >> 8, l = r & 255;
    double ga = mod[(size_t)bn*6912 + 2*1152 + d];
    double rv = refo[((size_t)((bn>>2)*256 + l))*1152 + d];
    xt[idx] += ga*(acc[idx] + rv);
}

__global__ void k_resid_mlp(double* __restrict__ xt, const double* __restrict__ t2,
                            const double* __restrict__ mod)
{
    int idx = blockIdx.x*256 + threadIdx.x;
    int r = idx / 1152, d = idx - r*1152;
    int bn = r >> 8;
    xt[idx] += mod[(size_t)bn*6912 + 5*1152 + d] * t2[idx];
}

// xt = patchify(x)@xe_w + xe_b + pos + feats0   (f64)
__global__ void k_patchify(const float* __restrict__ x, const float* __restrict__ w,
                           const float* __restrict__ bias, const float* __restrict__ pos,
                           const double* __restrict__ f0, double* __restrict__ xt)
{
    int idx = blockIdx.x*256 + threadIdx.x;            // 2048*1152 exact
    int r = idx / 1152, o = idx - r*1152;
    int bn = r >> 8, p = r & 255;
    int y = p >> 4, xx = p & 15;
    double acc = (double)bias[o] + (double)pos[(size_t)p*1152 + o] + f0[idx];
#pragma unroll
    for (int c = 0; c < 4; ++c)
#pragma unroll
        for (int ky = 0; ky < 2; ++ky)
#pragma unroll
            for (int kx = 0; kx < 2; ++kx)
                acc += (double)x[((size_t)(bn*4 + c)*32 + 2*y+ky)*32 + 2*xx+kx]
                     * (double)w[o*16 + c*4 + ky*2 + kx];
    xt[idx] = acc;
}

__global__ void k_unpatch(const double* __restrict__ flo, float* __restrict__ out)
{
    int idx = blockIdx.x*256 + threadIdx.x;            // 65536 exact
    int xx = idx & 31, y = (idx>>5)&31, ch = (idx>>10)&7, b = idx>>13;
    int hp = y>>1, py = y&1, wp = xx>>1, px = xx&1;
    out[idx] = (float)flo[((size_t)(b*256 + hp*16 + wp))*32 + (py*2+px)*8 + ch];
}

// ---------------- f64 SIMT GEMM, conflict-free LDS + XCD swizzle -----------
// 1D grid; logical (x=n-tile, y=m-tile) via xcd_swz so blocks sharing an
// A-strip run on ONE XCD (L2-resident). Arithmetic identical to round 8.
template<int AMODE>
DEV void load_a4d(const void* __restrict__ A, int row, int k, int M, double o[4])
{
    if (row >= M) { o[0]=o[1]=o[2]=o[3]=0.0; return; }
    if constexpr (AMODE == 1) {
        const float* Af = (const float*)A;
        int b = row>>10, p = row&1023, oy = p>>5, ox = p&31;
        int c = k>>8, ky = (k>>4)&15, kx = k&15;
        float4 v = *reinterpret_cast<const float4*>(
            Af + (((size_t)(b*6+c)*512 + (size_t)(oy*16+ky))*512 + (size_t)(ox*16+kx)));
        o[0]=v.x; o[1]=v.y; o[2]=v.z; o[3]=v.w;
    } else {
        const double* Ad = (const double*)A;
        int b = row>>8, y = (row>>4)&15, x = row&15;
        int q = k/1152, c = k - q*1152, ky = q>>1, kx = q&1;
        const double* p = Ad + (size_t)(b*1024 + (2*y+ky)*32 + 2*x+kx)*1152 + c;
        o[0]=p[0]; o[1]=p[1]; o[2]=p[2]; o[3]=p[3];
    }
}

template<int WMODE>
DEV void load_w4d(const float* __restrict__ W, int row, int k, int Nb, int K, double o[4])
{
    if (row >= Nb) { o[0]=o[1]=o[2]=o[3]=0.0; return; }
    if constexpr (WMODE == 0) {
        float4 v = *reinterpret_cast<const float4*>(W + (size_t)row*K + k);
        o[0]=v.x; o[1]=v.y; o[2]=v.z; o[3]=v.w;
    } else {
        int q = k/1152, c = k - q*1152;
        const float* p = W + (size_t)row*4608 + (size_t)c*4 + q;
        o[0]=p[0]; o[1]=p[4]; o[2]=p[8]; o[3]=p[12];
    }
}

template<int AMODE, int WMODE>
__global__ __launch_bounds__(256)
void k_dgemm(const void* __restrict__ A, const float* __restrict__ W,
             const float* __restrict__ bias, double* __restrict__ C,
             int M, int N, int K, int gridx)
{
    __shared__ double As[64][17];                  // [m][k], pad kills conflicts
    __shared__ double Ws[64][17];                  // [n][k]
    const int tid = threadIdx.x;
    const int tx = tid & 15, ty = tid >> 4;
    const int2 bxy = xcd_swz(gridx);
    const int m0 = bxy.y*64, n0 = bxy.x*64;
    const int lr = tid >> 2;                       // staging row 0..63
    const int lc = (tid & 3) * 4;                  // staging k {0,4,8,12}

    double acc[4][4] = {};

    for (int kt = 0; kt < K; kt += 16) {
        {
            double v[4];
            load_a4d<AMODE>(A, m0+lr, kt+lc, M, v);
            As[lr][lc+0]=v[0]; As[lr][lc+1]=v[1]; As[lr][lc+2]=v[2]; As[lr][lc+3]=v[3];
        }
        {
            double wv[4];
            load_w4d<WMODE>(W, n0+lr, kt+lc, N, K, wv);
            Ws[lr][lc+0]=wv[0]; Ws[lr][lc+1]=wv[1]; Ws[lr][lc+2]=wv[2]; Ws[lr][lc+3]=wv[3];
        }
        __syncthreads();
#pragma unroll
        for (int k = 0; k < 16; ++k) {
            double a[4], b[4];
#pragma unroll
            for (int e = 0; e < 4; ++e) { a[e] = As[ty + 16*e][k]; b[e] = Ws[tx + 16*e][k]; }
#pragma unroll
            for (int i = 0; i < 4; ++i)
#pragma unroll
                for (int j = 0; j < 4; ++j) acc[i][j] += a[i]*b[j];
        }
        __syncthreads();
    }

#pragma unroll
    for (int i = 0; i < 4; ++i) {
        int row = m0 + ty + 16*i;
        if (row >= M) continue;
#pragma unroll
        for (int j = 0; j < 4; ++j) {
            int col = n0 + tx + 16*j;
            if (col >= N) continue;
            C[(size_t)row*N + col] = acc[i][j] + (bias ? (double)bias[col] : 0.0);
        }
    }
}

// ---------------- int8 MFMA GEMM (exact), 256 thr + XCD swizzle ------------
// 1D grid; logical (x=m-tile, y=n-tile): same-y blocks share the W8 strip ->
// cluster them on one XCD. PRE=1: W8 pre-ternarized; PRE=0: on-the-fly.
template<int GATE, int PRE>
__global__ __launch_bounds__(256)
void k_qgemm(const signed char* __restrict__ A8, const double* __restrict__ ascale,
             const float* __restrict__ Wf, const signed char* __restrict__ W8,
             const double* __restrict__ wsum, long long wcount,
             const float* __restrict__ bias, double* __restrict__ C,
             int M, int N, int K, int accum, int gridM)
{
    __shared__ __align__(16) signed char Als[4][128][16];
    __shared__ __align__(16) signed char Bls[4][128][16];
    __shared__ __align__(16) signed char B2ls[GATE?4:1][GATE?128:1][16];
    const int tid = threadIdx.x;
    const int lane = tid & 63, wid = tid >> 6;
    const int wr = wid >> 1, wc = wid & 1;             // 2x2 waves, 64x64 each
    const int2 bxy = xcd_swz(gridM);
    const int m0 = bxy.x*128, n0 = bxy.y*128;
    const int ks = lane >> 4, fr = lane & 15;

    const double dqw = fmax(*wsum / (double)wcount, 1e-5);  // mean|w|
    const double thr = 0.5 * dqw;                           // ternary threshold

    i32x4 acc[4][4];
    i32x4 acc2[GATE?4:1][4];
#pragma unroll
    for (int i = 0; i < 4; ++i)
#pragma unroll
        for (int j = 0; j < 4; ++j) {
            acc[i][j] = i32x4{0,0,0,0};
            if constexpr (GATE) acc2[i][j] = i32x4{0,0,0,0};
        }

    for (int kt = 0; kt < K; kt += 64) {
#pragma unroll
        for (int c = 0; c < 2; ++c) {
            int idx = tid + c*256;
            int row = idx & 127, kslot = idx >> 7;
            i32x4 v = {0,0,0,0};
            if (m0 + row < M)
                v = *reinterpret_cast<const i32x4*>(A8 + (size_t)(m0+row)*K + kt + kslot*16);
            *reinterpret_cast<i32x4*>(&Als[kslot][row][0]) = v;
        }
#pragma unroll
        for (int c = 0; c < 2; ++c) {
            int idx = tid + c*256;
            int row = idx & 127, kslot = idx >> 7;
            i32x4 pv = {0,0,0,0};
            if (n0 + row < N) {
                if constexpr (PRE) {
                    pv = *reinterpret_cast<const i32x4*>(W8 + (size_t)(n0+row)*K + kt + kslot*16);
                } else {
                    const float* wp = Wf + (size_t)(n0+row)*K + kt + kslot*16;
#pragma unroll
                    for (int d = 0; d < 4; ++d) {
                        float4 wv = *reinterpret_cast<const float4*>(wp + d*4);
                        float we[4] = {wv.x, wv.y, wv.z, wv.w};
                        unsigned p = 0;
#pragma unroll
                        for (int e = 0; e < 4; ++e) {
                            double wd = (double)we[e];
                            int q = (wd > thr) - (wd < -thr);
                            p |= ((unsigned)(q & 255)) << (8*e);
                        }
                        pv[d] = (int)p;
                    }
                }
            }
            *reinterpret_cast<i32x4*>(&Bls[kslot][row][0]) = pv;
        }
        if constexpr (GATE) {
#pragma unroll
            for (int c = 0; c < 2; ++c) {
                int idx = tid + c*256;
                int row = idx & 127, kslot = idx >> 7;
                i32x4 pv = {0,0,0,0};
                if (n0 + row < N) {
                    if constexpr (PRE) {
                        pv = *reinterpret_cast<const i32x4*>(W8 + (size_t)(n0+row+N)*K + kt + kslot*16);
                    } else {
                        const float* wp = Wf + (size_t)(n0+row+N)*K + kt + kslot*16;
#pragma unroll
                        for (int d = 0; d < 4; ++d) {
                            float4 wv = *reinterpret_cast<const float4*>(wp + d*4);
                            float we[4] = {wv.x, wv.y, wv.z, wv.w};
                            unsigned p = 0;
#pragma unroll
                            for (int e = 0; e < 4; ++e) {
                                double wd = (double)we[e];
                                int q = (wd > thr) - (wd < -thr);
                                p |= ((unsigned)(q & 255)) << (8*e);
                            }
                            pv[d] = (int)p;
                        }
                    }
                }
                *reinterpret_cast<i32x4*>(&B2ls[kslot][row][0]) = pv;
            }
        }
        __syncthreads();
        i32x4 a[4];
#pragma unroll
        for (int i = 0; i < 4; ++i)
            a[i] = *reinterpret_cast<const i32x4*>(&Als[ks][wr*64 + i*16 + fr][0]);
#pragma unroll
        for (int j = 0; j < 4; ++j) {
            i32x4 b = *reinterpret_cast<const i32x4*>(&Bls[ks][wc*64 + j*16 + fr][0]);
#pragma unroll
            for (int i = 0; i < 4; ++i)
                acc[i][j] = __builtin_amdgcn_mfma_i32_16x16x64_i8(a[i], b, acc[i][j], 0, 0, 0);
            if constexpr (GATE) {
                i32x4 b2 = *reinterpret_cast<const i32x4*>(&B2ls[ks][wc*64 + j*16 + fr][0]);
#pragma unroll
                for (int i = 0; i < 4; ++i)
                    acc2[i][j] = __builtin_amdgcn_mfma_i32_16x16x64_i8(a[i], b2, acc2[i][j], 0, 0, 0);
            }
        }
        __syncthreads();
    }

    // epilogue: f64 dequant.  C/D map: col=lane&15, row=(lane>>4)*4+reg
#pragma unroll
    for (int i = 0; i < 4; ++i) {
#pragma unroll
        for (int r = 0; r < 4; ++r) {
            int row = m0 + wr*64 + i*16 + (lane>>4)*4 + r;
            if (row >= M) continue;
            double mul = dqw / ascale[row];
#pragma unroll
            for (int j = 0; j < 4; ++j) {
                int col = n0 + wc*64 + j*16 + (lane & 15);
                if (col >= N) continue;
                size_t o = (size_t)row*N + col;
                if constexpr (GATE) {
                    double g = (double)acc[i][j][r] * mul;
                    double y = (double)acc2[i][j][r] * mul;
                    C[o] = g/(1.0+exp(-g)) * y;
                } else {
                    double v = (double)acc[i][j][r] * mul;
                    if (bias) v += (double)bias[col];
                    C[o] = accum ? C[o] + v : v;
                }
            }
        }
    }
}

// ---------------------------------------------------------------------------
extern "C" void kernel_launch(void* const* d_in, const int* in_sizes, int n_in,
                              void* d_out, int out_size, void* d_ws, size_t ws_size,
                              hipStream_t stream)
{
    (void)in_sizes; (void)n_in; (void)out_size;
    auto in = [&](int i){ return (const float*)d_in[i]; };

    const float *X = in(0), *T = in(1), *Y = in(2), *XC = in(3), *REF = in(4);
    const float *xe_w = in(6), *xe_b = in(7), *pos = in(8);
    const float *te_w1 = in(9), *te_b1 = in(10), *te_w2 = in(11), *te_b2 = in(12);
    const float *pp_w = in(13), *pp_b = in(14);
    const float *sa_pe_w = in(15), *sa_pe_b = in(16);
    const float *sa_ln_g = in(17), *sa_ln_b = in(18);
    const float *sa_gate_w = in(19), *sa_down_w = in(20);
    const float *sa_dc_w = in(21), *sa_dc_b = in(22);
    const float *ada_w = in(23), *ada_b = in(24);
    const float *sa_wi = in(25), *sa_wf = in(26), *sa_wg = in(27), *sa_wo = in(28);
    const float *mv_wi = in(29), *mv_wf = in(30), *mv_wg = in(31), *mv_wo = in(32);
    const float *rf_wi = in(33), *rf_wf = in(34), *rf_wg = in(35), *rf_wo = in(36);
    const float *gate_w = in(37), *down_w = in(38);
    const float *fl_w = in(39), *fl_b = in(40), *fl_ada_w = in(41), *fl_ada_b = in(42);
    float* OUT = (float*)d_out;

    // ---------- workspace layout (base ~223 MB; W8 optional +101 MB) -------
    size_t off = 0;
    auto AL = [&](size_t bytes){ off = (off+255)&~(size_t)255; size_t r = off; off += bytes; return r; };
    const size_t oScale = AL(37*8);
    const size_t oPart  = AL(37*32*8);
    const size_t oSM1 = AL(8*1152*8), oSM2 = AL(8*1152*8), oSM3 = AL(8*1152*8);
    const size_t oCB  = AL(8*1152*8);
    const size_t oMOD = AL(8*6912*8);
    const size_t oH   = AL((size_t)8192*1152*8);    // 75.5 MB; reused as OB later
    const size_t oINT = AL((size_t)1024*4608*8);    // 37.7 MB (1024-row chunks)
    const size_t oF0  = AL((size_t)2048*1152*8);    // also ACC in block loop
    const size_t oXT  = AL((size_t)2048*1152*8);
    const size_t oFB  = AL((size_t)2048*1152*8);
    const size_t oIB  = AL((size_t)2048*1152*8);
    const size_t oGB  = AL((size_t)2048*1152*8);
    const size_t oRO  = AL((size_t)512*1152*8);
    const size_t oQ8X = AL((size_t)2048*1152);
    const size_t oQ8I = AL((size_t)1024*4608);
    const size_t oQ8O = AL((size_t)2048*1152);
    const size_t oQ8R = AL((size_t)512*1152);
    const size_t oQ8T = AL((size_t)8*1152);
    const size_t oQ8C = AL((size_t)8*1152);
    const size_t oDSX = AL(2048*8), oDSI = AL(1024*8), oDSO = AL(2048*8);
    const size_t oDSR = AL(512*8),  oDST = AL(8*8),    oDSC = AL(8*8);
    if (off > ws_size) return;

    // ---------- weight list + optional pre-ternarized region ----------
    WList wl{}; WOffs wo{};
    long long wn[37];
    int nw = 0;
    auto addw = [&](const float* w, long long n){ wl.p[nw]=w; wl.n[nw]=n; wn[nw]=n; nw++; };
    addw(te_w1, 294912); addw(te_w2, 1327104); addw(pp_w, 884736);
    addw(sa_gate_w, 10616832); addw(sa_down_w, 5308416);
    for (int l = 0; l < 2; ++l) {
        addw(ada_w + (size_t)l*7962624, 7962624);
        addw(sa_wi + (size_t)l*1327104, 1327104);
        addw(sa_wf + (size_t)l*1327104, 1327104);
        addw(sa_wg + (size_t)l*1327104, 1327104);
        addw(sa_wo + (size_t)l*1327104, 1327104);
        addw(mv_wi + (size_t)l*1327104, 1327104);
        addw(mv_wf + (size_t)l*1327104, 1327104);
        addw(mv_wg + (size_t)l*1327104, 1327104);
        addw(mv_wo + (size_t)l*1327104, 1327104);
        addw(rf_wi + (size_t)l*1327104, 1327104);
        addw(rf_wf + (size_t)l*1327104, 1327104);
        addw(rf_wg + (size_t)l*1327104, 1327104);
        addw(rf_wo + (size_t)l*1327104, 1327104);
        addw(gate_w + (size_t)l*10616832, 10616832);
        addw(down_w + (size_t)l*5308416, 5308416);
    }
    addw(fl_ada_w, 2654208); addw(fl_w, 36864);

    size_t off_saved = off;
    long long wtot = 0;
    for (int i = 0; i < 37; ++i) { wo.o[i] = wtot; wtot += (wn[i] + 255) & ~255LL; }
    const size_t oW8 = AL((size_t)wtot);
    const bool useW8 = (off <= ws_size);
    if (!useW8) off = off_saved;

    char* w8p = (char*)d_ws;
    double* scales = (double*)(w8p + oScale);
    double* parts  = (double*)(w8p + oPart);
    double *SM1=(double*)(w8p+oSM1), *SM2=(double*)(w8p+oSM2), *SM3=(double*)(w8p+oSM3);
    double *CB=(double*)(w8p+oCB), *MOD=(double*)(w8p+oMOD);
    double *H=(double*)(w8p+oH), *INT=(double*)(w8p+oINT);
    double *F0=(double*)(w8p+oF0), *XT=(double*)(w8p+oXT);
    double *FB=(double*)(w8p+oFB), *IB=(double*)(w8p+oIB), *GB=(double*)(w8p+oGB);
    double *ACC=F0, *OB=H, *RO=(double*)(w8p+oRO);
    signed char *Q8X=(signed char*)(w8p+oQ8X), *Q8I=(signed char*)(w8p+oQ8I);
    signed char *Q8O=(signed char*)(w8p+oQ8O), *Q8R=(signed char*)(w8p+oQ8R);
    signed char *Q8T=(signed char*)(w8p+oQ8T), *Q8C=(signed char*)(w8p+oQ8C);
    double *DSX=(double*)(w8p+oDSX), *DSI=(double*)(w8p+oDSI), *DSO=(double*)(w8p+oDSO);
    double *DSR=(double*)(w8p+oDSR), *DST=(double*)(w8p+oDST), *DSC=(double*)(w8p+oDSC);
    signed char* W8 = (signed char*)(w8p + oW8);

    // ---------- weight scales (+ one-time ternarize) ----------
    k_abssum_all<<<dim3(32,37), 256, 0, stream>>>(wl, parts);
    k_abssum_fin<<<37, 64, 0, stream>>>(parts, scales);
    if (useW8)
        k_ternarize<<<dim3(64,37), 256, 0, stream>>>(wl, wo, scales, W8);

    // ---------- launch helpers (1D grids, XCD-swizzled in-kernel) ----------
    auto qgemm = [&](const signed char* A8, const double* as, const float* Win, int slot,
                     const float* b, double* Cout, int M, int N, int K, int accum){
        int gm = (M+127)/128, gn = (N+127)/128;
        if (useW8)
            k_qgemm<0,1><<<gm*gn, 256, 0, stream>>>(A8, as, Win, W8 + wo.o[slot],
                                                    scales+slot, wn[slot], b, Cout, M, N, K, accum, gm);
        else
            k_qgemm<0,0><<<gm*gn, 256, 0, stream>>>(A8, as, Win, nullptr,
                                                    scales+slot, wn[slot], b, Cout, M, N, K, accum, gm);
    };
    auto qgemmGate = [&](const signed char* A8, const double* as, const float* Win, int slot,
                         double* Cout, int M){
        int gm = (M+127)/128;
        if (useW8)
            k_qgemm<1,1><<<gm*36, 256, 0, stream>>>(A8, as, Win, W8 + wo.o[slot],
                                                    scales+slot, wn[slot], nullptr, Cout, M, 4608, 1152, 0, gm);
        else
            k_qgemm<1,0><<<gm*36, 256, 0, stream>>>(A8, as, Win, nullptr,
                                                    scales+slot, wn[slot], nullptr, Cout, M, 4608, 1152, 0, gm);
    };

    // ---------- conditioning vector c ----------
    k_temb<<<8, 128, 0, stream>>>(T, SM1);
    k_rsq8<double><<<8, 256, 0, stream>>>(SM1, Q8T, DST, 256, 0);
    qgemm(Q8T, DST, te_w1, 0, te_b1, SM3, 8, 1152, 256, 0);
    k_rsq8<double><<<8, 256, 0, stream>>>(SM3, Q8T, DST, 1152, 1);
    qgemm(Q8T, DST, te_w2, 1, te_b2, SM2, 8, 1152, 1152, 0);
    k_rsq8<float><<<8, 256, 0, stream>>>(Y, Q8T, DST, 768, 0);
    qgemm(Q8T, DST, pp_w, 2, pp_b, SM3, 8, 1152, 768, 0);
    k_add<<<36, 256, 0, stream>>>(SM2, SM3, CB, 9216);
    k_rsq8<double><<<8, 256, 0, stream>>>(CB, Q8C, DSC, 1152, 1);

    // ---------- spatial adapter: patch embed + block 0 only ----------
    k_dgemm<1,0><<<18*128, 256, 0, stream>>>(XC, sa_pe_w, sa_pe_b, H, 8192, 1152, 1536, 18);
    for (int ch = 0; ch < 8; ++ch) {
        double* Hrow = H + (size_t)ch*1024*1152;
        k_lnq8<<<1024, 256, 1152*8, stream>>>(Hrow, Q8X, DSX, 1152, sa_ln_g, sa_ln_b,
                                              nullptr, nullptr, 0, 1e-5);
        qgemmGate(Q8X, DSX, sa_gate_w, 3, INT, 1024);
        k_rsq8<double><<<1024, 256, 0, stream>>>(INT, Q8I, DSI, 4608, 0);
        qgemm(Q8I, DSI, sa_down_w, 4, nullptr, Hrow, 1024, 1152, 4608, 0);
    }
    k_dgemm<2,1><<<18*32, 256, 0, stream>>>(H, sa_dc_w, sa_dc_b, F0, 2048, 1152, 4608, 18);

    // ---------- patchify latents + pos + feats0 ----------
    k_patchify<<<9216, 256, 0, stream>>>(X, xe_w, xe_b, pos, F0, XT);
    k_rsq8<float><<<512, 256, 0, stream>>>(REF, Q8R, DSR, 1152, 0);

    // ---------- transformer blocks (OB aliases dead H) ----------
    for (int l = 0; l < 2; ++l) {
        int sb = 5 + l*15;
        const float *wada = ada_w + (size_t)l*7962624, *bada = ada_b + (size_t)l*6912;
        const float *swi = sa_wi + (size_t)l*1327104, *swf = sa_wf + (size_t)l*1327104;
        const float *swg = sa_wg + (size_t)l*1327104, *swo = sa_wo + (size_t)l*1327104;
        const float *mwi = mv_wi + (size_t)l*1327104, *mwf = mv_wf + (size_t)l*1327104;
        const float *mwg = mv_wg + (size_t)l*1327104, *mwo = mv_wo + (size_t)l*1327104;
        const float *rwi = rf_wi + (size_t)l*1327104, *rwf = rf_wf + (size_t)l*1327104;
        const float *rwg = rf_wg + (size_t)l*1327104, *rwo = rf_wo + (size_t)l*1327104;
        const float *wgt = gate_w + (size_t)l*10616832, *wdn = down_w + (size_t)l*5308416;

        qgemm(Q8C, DSC, wada, sb+0, bada, MOD, 8, 6912, 1152, 0);

        k_lnq8<<<2048, 256, 1152*8, stream>>>(XT, Q8X, DSX, 1152, nullptr, nullptr,
                                              MOD+0, MOD+1152, 6912, 1e-6);

        // self attention (seq = 256 tokens)
        qgemm(Q8X, DSX, swf, sb+2, nullptr, FB, 2048, 1152, 1152, 0);
        qgemm(Q8X, DSX, swi, sb+1, nullptr, IB, 2048, 1152, 1152, 0);
        qgemm(Q8X, DSX, swg, sb+3, nullptr, GB, 2048, 1152, 1152, 0);
        k_gatepre<<<9216, 256, 0, stream>>>(FB, IB, 2359296LL);
        k_scan2<<<36, 256, 0, stream>>>(FB, IB, OB, 8, 294912LL, 1152, 1152LL, 256);
        k_ogateq8<<<2048, 256, 1152*8, stream>>>(OB, GB, Q8O, DSO, 1152);
        qgemm(Q8O, DSO, swo, sb+4, nullptr, ACC, 2048, 1152, 1152, 0);

        // multi-view attention (seq = 4 views; token layout unchanged)
        qgemm(Q8X, DSX, mwf, sb+6, nullptr, FB, 2048, 1152, 1152, 0);
        qgemm(Q8X, DSX, mwi, sb+5, nullptr, IB, 2048, 1152, 1152, 0);
        qgemm(Q8X, DSX, mwg, sb+7, nullptr, GB, 2048, 1152, 1152, 0);
        k_gatepre<<<9216, 256, 0, stream>>>(FB, IB, 2359296LL);
        k_scan2<<<2304, 256, 0, stream>>>(FB, IB, OB, 2, 1179648LL, 294912, 294912LL, 4);
        k_ogateq8<<<2048, 256, 1152*8, stream>>>(OB, GB, Q8O, DSO, 1152);
        qgemm(Q8O, DSO, mwo, sb+8, nullptr, ACC, 2048, 1152, 1152, 1);   // +=

        // ref attention on 2 unique batches
        qgemm(Q8R, DSR, rwf, sb+10, nullptr, FB, 512, 1152, 1152, 0);
        qgemm(Q8R, DSR, rwi, sb+9,  nullptr, IB, 512, 1152, 1152, 0);
        qgemm(Q8R, DSR, rwg, sb+11, nullptr, GB, 512, 1152, 1152, 0);
        k_gatepre<<<2304, 256, 0, stream>>>(FB, IB, 589824LL);
        k_scan2<<<9, 256, 0, stream>>>(FB, IB, OB, 2, 294912LL, 1152, 1152LL, 256);
        k_ogateq8<<<512, 256, 1152*8, stream>>>(OB, GB, Q8O, DSO, 1152);
        qgemm(Q8O, DSO, rwo, sb+12, nullptr, RO, 512, 1152, 1152, 0);

        k_resid_attn<<<9216, 256, 0, stream>>>(XT, ACC, RO, MOD);

        // MLP (1024-row chunks through INT)
        k_lnq8<<<2048, 256, 1152*8, stream>>>(XT, Q8X, DSX, 1152, nullptr, nullptr,
                                              MOD+3*1152, MOD+4*1152, 6912, 1e-6);
        for (int ch = 0; ch < 2; ++ch) {
            qgemmGate(Q8X + (size_t)ch*1024*1152, DSX + ch*1024, wgt, sb+13, INT, 1024);
            k_rsq8<double><<<1024, 256, 0, stream>>>(INT, Q8I, DSI, 4608, 0);
            qgemm(Q8I, DSI, wdn, sb+14, nullptr, OB + (size_t)ch*1024*1152, 1024, 1152, 4608, 0);
        }
        k_resid_mlp<<<9216, 256, 0, stream>>>(XT, OB, MOD);
    }

    // ---------- final layer + unpatchify ----------
    qgemm(Q8C, DSC, fl_ada_w, 35, fl_ada_b, MOD, 8, 2304, 1152, 0);
    k_lnq8<<<2048, 256, 1152*8, stream>>>(XT, Q8X, DSX, 1152, nullptr, nullptr,
                                          MOD+0, MOD+1152, 2304, 1e-6);
    qgemm(Q8X, DSX, fl_w, 36, fl_b, FB, 2048, 32, 1152, 0);
    k_unpatch<<<256, 256, 0, stream>>>(FB, OUT);
}

// Round 10
// 5596.181 us; speedup vs baseline: 1.1721x; 1.1721x over previous
//
#include <hip/hip_runtime.h>

#define DEV __device__ __forceinline__

typedef __attribute__((ext_vector_type(4))) int i32x4;
typedef __attribute__((ext_vector_type(4))) double f64x4;

// ---------------------------------------------------------------------------
// TernaryMVAdapter forward on MI355X. Round 10: round-9 numerics (f64-exact,
// absmax floor ~0.035, replay-safe) +
//  * on-device-PROBED f64 MFMA (v_mfma_f64_16x16x4) for the two convs:
//    a 1-wave probe computes one MFMA on exact-integer asymmetric A,B; a
//    checker classifies the D layout {assumed, transposed, neither} into a
//    flag; k_dgemm uses the MFMA path only if verified, else proven SIMT.
//  * SA/MLP chunk enlargement (4096/2048 rows, ws-size tiered) to fix the
//    sub-1-block/CU qgemm grids. Row-independent -> bitwise identical.
// ---------------------------------------------------------------------------

struct WList { const float* p[37]; long long n[37]; };
struct WOffs { long long o[37]; };

DEV int2 xcd_swz(int gridx)
{
    const int nwg = (int)gridDim.x, b = (int)blockIdx.x;
    const int q = nwg >> 3, r = nwg & 7, xcd = b & 7, idx = b >> 3;
    const int lb = (xcd < r ? xcd*(q+1) : r*(q+1) + (xcd-r)*q) + idx;
    return make_int2(lb % gridx, lb / gridx);
}

// ---------------- f64 MFMA layout probe (exact-integer check) --------------
// Assumed layout: lane l holds A[row=l&15][k=l>>4], B[k=l>>4][col=l&15];
// D: col=l&15, row=(l>>4)*4+reg.  flag: 1=assumed, 2=row/col-swapped D, 0=no.
__global__ void k_mfma64_probe(double* __restrict__ out)
{
    const int lane = threadIdx.x;                      // 64 threads
    double a = (double)((lane & 15)*4 + (lane >> 4) + 1);          // A[r][k]=4r+k+1
    double b = 1.0 + (double)(lane >> 4) + 0.25*(double)(lane & 15); // B[k][c]=1+k+c/4
    f64x4 acc = {0.0, 0.0, 0.0, 0.0};
    acc = __builtin_amdgcn_mfma_f64_16x16x4f64(a, b, acc, 0, 0, 0);
#pragma unroll
    for (int r = 0; r < 4; ++r) out[lane*4 + r] = acc[r];
}

__global__ void k_mfma64_check(const double* __restrict__ probe, int* __restrict__ flag)
{
    if (threadIdx.x != 0) return;
    double Cref[16][16];
    for (int r = 0; r < 16; ++r)
        for (int c = 0; c < 16; ++c) {
            double s = 0.0;
            for (int k = 0; k < 4; ++k)
                s += (double)(4*r + k + 1) * (1.0 + (double)k + 0.25*(double)c);
            Cref[r][c] = s;                            // exact in f64
        }
    bool nrm = true, swp = true;
    for (int lane = 0; lane < 64; ++lane)
        for (int r = 0; r < 4; ++r) {
            double v = probe[lane*4 + r];
            int rr = (lane >> 4)*4 + r, cc = lane & 15;
            if (v != Cref[rr][cc]) nrm = false;
            if (v != Cref[cc][rr]) swp = false;
        }
    *flag = nrm ? 1 : (swp ? 2 : 0);
}

// ---------------- fused deterministic |w| sums (37 slots) ------------------
__global__ void k_abssum_all(WList wl, double* __restrict__ partials)
{
    const int slot = blockIdx.y;
    const float* w = wl.p[slot];
    const long long n = wl.n[slot];
    __shared__ double sm[256];
    double s = 0.0;
    for (long long i = (long long)blockIdx.x*256 + threadIdx.x; i < n; i += 32LL*256)
        s += (double)fabsf(w[i]);
    sm[threadIdx.x] = s;
    __syncthreads();
    for (int k = 128; k > 0; k >>= 1) {
        if ((int)threadIdx.x < k) sm[threadIdx.x] += sm[threadIdx.x + k];
        __syncthreads();
    }
    if (threadIdx.x == 0) partials[slot*32 + blockIdx.x] = sm[0];
}

__global__ void k_abssum_fin(const double* __restrict__ partials, double* __restrict__ out)
{
    const int slot = blockIdx.x;
    if (threadIdx.x == 0) {
        double s = 0.0;
        for (int i = 0; i < 32; ++i) s += partials[slot*32 + i];
        out[slot] = s;
    }
}

// ---------------- one-time weight ternarization (f64-exact decision) -------
__global__ void k_ternarize(WList wl, WOffs wo, const double* __restrict__ scales,
                            signed char* __restrict__ W8)
{
    const int slot = blockIdx.y;
    const float* w = wl.p[slot];
    const long long n4 = wl.n[slot] >> 2;
    const double dqw = fmax(scales[slot] / (double)wl.n[slot], 1e-5);
    const double thr = 0.5 * dqw;
    signed char* o = W8 + wo.o[slot];
    for (long long i = (long long)blockIdx.x*256 + threadIdx.x; i < n4; i += 64LL*256) {
        float4 v = *reinterpret_cast<const float4*>(w + i*4);
        float we[4] = {v.x, v.y, v.z, v.w};
        char r[4];
#pragma unroll
        for (int e = 0; e < 4; ++e) {
            double wd = (double)we[e];
            r[e] = (char)((wd > thr) - (wd < -thr));
        }
        *reinterpret_cast<char4*>(o + i*4) = make_char4(r[0], r[1], r[2], r[3]);
    }
}

// ---------------- timestep frequency embedding (f64) -----------------------
__global__ void k_temb(const float* __restrict__ t, double* __restrict__ out)
{
    int b = blockIdx.x, j = threadIdx.x;               // 8 x 128
    double fr  = exp(-9.210340371976184 * (double)j / 128.0);
    double ang = (double)t[b] * fr;
    out[b*256 + j]       = cos(ang);
    out[b*256 + 128 + j] = sin(ang);
}

// ---------------- rmsnorm + int8 absmax quant (f64, LDS-free) --------------
template<typename TI>
__global__ void k_rsq8(const TI* __restrict__ x, signed char* __restrict__ q8,
                       double* __restrict__ dscale, int K, int pre_silu)
{
    __shared__ double red[256], red2[256];
    const int row = blockIdx.x, tid = threadIdx.x;
    const TI* xr = x + (size_t)row*K;
    double ss = 0.0, am = 0.0;
    for (int i = tid; i < K; i += 256) {
        double v = (double)xr[i];
        if (pre_silu) v = v / (1.0 + exp(-v));
        ss += v*v; am = fmax(am, fabs(v));
    }
    red[tid] = ss; red2[tid] = am;
    __syncthreads();
    for (int s = 128; s > 0; s >>= 1) {
        if (tid < s) { red[tid] += red[tid+s]; red2[tid] = fmax(red2[tid], red2[tid+s]); }
        __syncthreads();
    }
    double rms = 1.0 / sqrt(red[0]/(double)K + 1e-8);
    double s   = 127.0 / fmax(red2[0]*rms, 1e-5);
    signed char* orow = q8 + (size_t)row*K;
    for (int i = tid; i < K; i += 256) {
        double v = (double)xr[i];
        if (pre_silu) v = v / (1.0 + exp(-v));
        orow[i] = (signed char)(int)fmin(fmax(rint(v*rms*s), -128.0), 127.0);
    }
    if (tid == 0) dscale[row] = s;
}

// ---------------- layernorm(+gb/+mod) + rmsnorm + int8 quant (f64) ---------
__global__ void k_lnq8(const double* __restrict__ x, signed char* __restrict__ q8,
                       double* __restrict__ dscale, int K,
                       const float* __restrict__ gamma, const float* __restrict__ beta,
                       const double* __restrict__ sh, const double* __restrict__ sc,
                       int modstride, double eps)
{
    extern __shared__ double rb[];
    __shared__ double red[256], red2[256];
    const int row = blockIdx.x, tid = threadIdx.x;
    const double* xr = x + (size_t)row*K;
    double s1 = 0.0;
    for (int i = tid; i < K; i += 256) { double v = xr[i]; rb[i] = v; s1 += v; }
    red[tid] = s1; __syncthreads();
    for (int s = 128; s > 0; s >>= 1) { if (tid < s) red[tid] += red[tid+s]; __syncthreads(); }
    double mu = red[0]/(double)K;
    __syncthreads();
    double s2 = 0.0;
    for (int i = tid; i < K; i += 256) { double d = rb[i]-mu; s2 += d*d; }
    red[tid] = s2; __syncthreads();
    for (int s = 128; s > 0; s >>= 1) { if (tid < s) red[tid] += red[tid+s]; __syncthreads(); }
    double r = 1.0 / sqrt(red[0]/(double)K + eps);
    const int bn = row >> 8;
    __syncthreads();
    double ss = 0.0, am = 0.0;
    for (int i = tid; i < K; i += 256) {
        double y = (rb[i]-mu)*r;
        if (gamma) y = y*(double)gamma[i] + (double)beta[i];
        if (sh)    y = y*(1.0 + sc[(size_t)bn*modstride + i]) + sh[(size_t)bn*modstride + i];
        rb[i] = y; ss += y*y; am = fmax(am, fabs(y));
    }
    red[tid] = ss; red2[tid] = am;
    __syncthreads();
    for (int s = 128; s > 0; s >>= 1) {
        if (tid < s) { red[tid] += red[tid+s]; red2[tid] = fmax(red2[tid], red2[tid+s]); }
        __syncthreads();
    }
    double rms = 1.0 / sqrt(red[0]/(double)K + 1e-8);
    double s   = 127.0 / fmax(red2[0]*rms, 1e-5);
    signed char* orow = q8 + (size_t)row*K;
    for (int i = tid; i < K; i += 256)
        orow[i] = (signed char)(int)fmin(fmax(rint(rb[i]*rms*s), -128.0), 127.0);
    if (tid == 0) dscale[row] = s;
}

// ---------------- ogate (rmsnorm*g*sig(g)) + rmsnorm + quant (f64) ---------
__global__ void k_ogateq8(const double* __restrict__ O, const double* __restrict__ G,
                          signed char* __restrict__ q8, double* __restrict__ dscale, int K)
{
    extern __shared__ double rb[];
    __shared__ double red[256], red2[256];
    const int row = blockIdx.x, tid = threadIdx.x;
    const double* orow = O + (size_t)row*K;
    const double* grow = G + (size_t)row*K;
    double ss = 0.0;
    for (int i = tid; i < K; i += 256) { double v = orow[i]; rb[i] = v; ss += v*v; }
    red[tid] = ss; __syncthreads();
    for (int s = 128; s > 0; s >>= 1) { if (tid < s) red[tid] += red[tid+s]; __syncthreads(); }
    double rmso = 1.0 / sqrt(red[0]/(double)K + 1e-8);
    __syncthreads();
    double ss2 = 0.0, am = 0.0;
    for (int i = tid; i < K; i += 256) {
        double g = grow[i];
        double y = rb[i]*rmso * g / (1.0 + exp(-g));
        rb[i] = y; ss2 += y*y; am = fmax(am, fabs(y));
    }
    red[tid] = ss2; red2[tid] = am;
    __syncthreads();
    for (int s = 128; s > 0; s >>= 1) {
        if (tid < s) { red[tid] += red[tid+s]; red2[tid] = fmax(red2[tid], red2[tid+s]); }
        __syncthreads();
    }
    double rms = 1.0 / sqrt(red[0]/(double)K + 1e-8);
    double s   = 127.0 / fmax(red2[0]*rms, 1e-5);
    signed char* qrow = q8 + (size_t)row*K;
    for (int i = tid; i < K; i += 256)
        qrow[i] = (signed char)(int)fmin(fmax(rint(rb[i]*rms*s), -128.0), 127.0);
    if (tid == 0) dscale[row] = s;
}

// ---------------- HGRN gate precompute + lean serial scan ------------------
__global__ void k_gatepre(double* __restrict__ F, double* __restrict__ I, long long n)
{
    long long i = (long long)blockIdx.x*256 + threadIdx.x;
    if (i >= n) return;
    double fp = F[i], ip = I[i];
    double f = 1.0/(1.0+exp(-fp));
    double v = (ip/(1.0+exp(-ip)))*(1.0-f);
    F[i] = f; I[i] = v;
}

__global__ void k_scan2(const double* __restrict__ F, const double* __restrict__ V,
                        double* __restrict__ O, int n_outer, long long outer_stride,
                        int n_inner, long long t_stride, int T)
{
    long long chain = (long long)blockIdx.x*blockDim.x + threadIdx.x;
    if (chain >= (long long)n_outer*n_inner) return;
    long long base = (chain / n_inner)*outer_stride + (chain % n_inner);
    double h = 0.0;
    for (int t = 0; t < T; ++t) {
        long long idx = base + (long long)t*t_stride;
        h = F[idx]*h + V[idx];
        O[idx] = h;
    }
}

// ---------------- misc elementwise (f64) -----------------------------------
__global__ void k_add(const double* __restrict__ a, const double* __restrict__ b,
                      double* __restrict__ o, int n)
{
    int i = blockIdx.x*256 + threadIdx.x;
    if (i < n) o[i] = a[i] + b[i];
}

__global__ void k_resid_attn(double* __restrict__ xt, const double* __restrict__ acc,
                             const double* __restrict__ refo, const double* __restrict__ mod)
{
    int idx = blockIdx.x*256 + threadIdx.x;            // 2048*1152 exact
    int r = idx / 1152, d = idx - r*1152;
    int bn = r >> 8, l = r & 255;
    double ga = mod[(size_t)bn*6912 + 2*1152 + d];
    double rv = refo[((size_t)((bn>>2)*256 + l))*1152 + d];
    xt[idx] += ga*(acc[idx] + rv);
}

__global__ void k_resid_mlp(double* __restrict__ xt, const double* __restrict__ t2,
                            const double* __restrict__ mod)
{
    int idx = blockIdx.x*256 + threadIdx.x;
    int r = idx / 1152, d = idx - r*1152;
    int bn = r >> 8;
    xt[idx] += mod[(size_t)bn*6912 + 5*1152 + d] * t2[idx];
}

__global__ void k_patchify(const float* __restrict__ x, const float* __restrict__ w,
                           const float* __restrict__ bias, const float* __restrict__ pos,
                           const double* __restrict__ f0, double* __restrict__ xt)
{
    int idx = blockIdx.x*256 + threadIdx.x;            // 2048*1152 exact
    int r = idx / 1152, o = idx - r*1152;
    int bn = r >> 8, p = r & 255;
    int y = p >> 4, xx = p & 15;
    double acc = (double)bias[o] + (double)pos[(size_t)p*1152 + o] + f0[idx];
#pragma unroll
    for (int c = 0; c < 4; ++c)
#pragma unroll
        for (int ky = 0; ky < 2; ++ky)
#pragma unroll
            for (int kx = 0; kx < 2; ++kx)
                acc += (double)x[((size_t)(bn*4 + c)*32 + 2*y+ky)*32 + 2*xx+kx]
                     * (double)w[o*16 + c*4 + ky*2 + kx];
    xt[idx] = acc;
}

__global__ void k_unpatch(const double* __restrict__ flo, float* __restrict__ out)
{
    int idx = blockIdx.x*256 + threadIdx.x;            // 65536 exact
    int xx = idx & 31, y = (idx>>5)&31, ch = (idx>>10)&7, b = idx>>13;
    int hp = y>>1, py = y&1, wp = xx>>1, px = xx&1;
    out[idx] = (float)flo[((size_t)(b*256 + hp*16 + wp))*32 + (py*2+px)*8 + ch];
}

// ---------------- f64 GEMM: probed MFMA path + proven SIMT fallback --------
template<int AMODE>
DEV void load_a4d(const void* __restrict__ A, int row, int k, int M, double o[4])
{
    if (row >= M) { o[0]=o[1]=o[2]=o[3]=0.0; return; }
    if constexpr (AMODE == 1) {
        const float* Af = (const float*)A;
        int b = row>>10, p = row&1023, oy = p>>5, ox = p&31;
        int c = k>>8, ky = (k>>4)&15, kx = k&15;
        float4 v = *reinterpret_cast<const float4*>(
            Af + (((size_t)(b*6+c)*512 + (size_t)(oy*16+ky))*512 + (size_t)(ox*16+kx)));
        o[0]=v.x; o[1]=v.y; o[2]=v.z; o[3]=v.w;
    } else {
        const double* Ad = (const double*)A;
        int b = row>>8, y = (row>>4)&15, x = row&15;
        int q = k/1152, c = k - q*1152, ky = q>>1, kx = q&1;
        const double* p = Ad + (size_t)(b*1024 + (2*y+ky)*32 + 2*x+kx)*1152 + c;
        o[0]=p[0]; o[1]=p[1]; o[2]=p[2]; o[3]=p[3];
    }
}

template<int WMODE>
DEV void load_w4d(const float* __restrict__ W, int row, int k, int Nb, int K, double o[4])
{
    if (row >= Nb) { o[0]=o[1]=o[2]=o[3]=0.0; return; }
    if constexpr (WMODE == 0) {
        float4 v = *reinterpret_cast<const float4*>(W + (size_t)row*K + k);
        o[0]=v.x; o[1]=v.y; o[2]=v.z; o[3]=v.w;
    } else {
        int q = k/1152, c = k - q*1152;
        const float* p = W + (size_t)row*4608 + (size_t)c*4 + q;
        o[0]=p[0]; o[1]=p[4]; o[2]=p[8]; o[3]=p[12];
    }
}

template<int AMODE, int WMODE>
__global__ __launch_bounds__(256)
void k_dgemm(const void* __restrict__ A, const float* __restrict__ W,
             const float* __restrict__ bias, double* __restrict__ C,
             int M, int N, int K, int gridx, const int* __restrict__ mfma_flag)
{
    __shared__ double As[64][17];                  // [m][k], +1 pad
    __shared__ double Ws[64][17];                  // [n][k]
    const int tid = threadIdx.x;
    const int2 bxy = xcd_swz(gridx);
    const int m0 = bxy.y*64, n0 = bxy.x*64;
    const int lr = tid >> 2;                       // staging row 0..63
    const int lc = (tid & 3) * 4;                  // staging k {0,4,8,12}
    const int flag = *mfma_flag;                   // uniform

    if (flag) {
        // ---- f64 MFMA path (layout HW-verified this launch) ----
        const int lane = tid & 63, wid = tid >> 6;
        const int wm = wid >> 1, wn = wid & 1;     // 2x2 waves of 32x32
        const int lm = lane & 15, lk = lane >> 4;
        f64x4 fa[2][2];
#pragma unroll
        for (int i = 0; i < 2; ++i)
#pragma unroll
            for (int j = 0; j < 2; ++j) fa[i][j] = f64x4{0.0,0.0,0.0,0.0};

        for (int kt = 0; kt < K; kt += 16) {
            {
                double v[4];
                load_a4d<AMODE>(A, m0+lr, kt+lc, M, v);
                As[lr][lc+0]=v[0]; As[lr][lc+1]=v[1]; As[lr][lc+2]=v[2]; As[lr][lc+3]=v[3];
            }
            {
                double wv[4];
                load_w4d<WMODE>(W, n0+lr, kt+lc, N, K, wv);
                Ws[lr][lc+0]=wv[0]; Ws[lr][lc+1]=wv[1]; Ws[lr][lc+2]=wv[2]; Ws[lr][lc+3]=wv[3];
            }
            __syncthreads();
#pragma unroll
            for (int k4 = 0; k4 < 4; ++k4) {
                const int kk = k4*4 + lk;
                double a0 = As[wm*32 + lm][kk];
                double a1 = As[wm*32 + 16 + lm][kk];
                double b0 = Ws[wn*32 + lm][kk];
                double b1 = Ws[wn*32 + 16 + lm][kk];
                fa[0][0] = __builtin_amdgcn_mfma_f64_16x16x4f64(a0, b0, fa[0][0], 0, 0, 0);
                fa[0][1] = __builtin_amdgcn_mfma_f64_16x16x4f64(a0, b1, fa[0][1], 0, 0, 0);
                fa[1][0] = __builtin_amdgcn_mfma_f64_16x16x4f64(a1, b0, fa[1][0], 0, 0, 0);
                fa[1][1] = __builtin_amdgcn_mfma_f64_16x16x4f64(a1, b1, fa[1][1], 0, 0, 0);
            }
            __syncthreads();
        }
#pragma unroll
        for (int i = 0; i < 2; ++i)
#pragma unroll
            for (int j = 0; j < 2; ++j)
#pragma unroll
                for (int r = 0; r < 4; ++r) {
                    int ir = (flag == 1) ? (lk*4 + r) : lm;   // intra-frag row
                    int ic = (flag == 1) ? lm : (lk*4 + r);   // intra-frag col
                    int row = m0 + wm*32 + i*16 + ir;
                    int col = n0 + wn*32 + j*16 + ic;
                    if (row < M && col < N)
                        C[(size_t)row*N + col] = fa[i][j][r] + (bias ? (double)bias[col] : 0.0);
                }
        return;
    }

    // ---- SIMT fallback (proven rounds 3-9) ----
    const int tx = tid & 15, ty = tid >> 4;
    double acc[4][4] = {};
    for (int kt = 0; kt < K; kt += 16) {
        {
            double v[4];
            load_a4d<AMODE>(A, m0+lr, kt+lc, M, v);
            As[lr][lc+0]=v[0]; As[lr][lc+1]=v[1]; As[lr][lc+2]=v[2]; As[lr][lc+3]=v[3];
        }
        {
            double wv[4];
            load_w4d<WMODE>(W, n0+lr, kt+lc, N, K, wv);
            Ws[lr][lc+0]=wv[0]; Ws[lr][lc+1]=wv[1]; Ws[lr][lc+2]=wv[2]; Ws[lr][lc+3]=wv[3];
        }
        __syncthreads();
#pragma unroll
        for (int k = 0; k < 16; ++k) {
            double a[4], b[4];
#pragma unroll
            for (int e = 0; e < 4; ++e) { a[e] = As[ty + 16*e][k]; b[e] = Ws[tx + 16*e][k]; }
#pragma unroll
            for (int i = 0; i < 4; ++i)
#pragma unroll
                for (int j = 0; j < 4; ++j) acc[i][j] += a[i]*b[j];
        }
        __syncthreads();
    }
#pragma unroll
    for (int i = 0; i < 4; ++i) {
        int row = m0 + ty + 16*i;
        if (row >= M) continue;
#pragma unroll
        for (int j = 0; j < 4; ++j) {
            int col = n0 + tx + 16*j;
            if (col >= N) continue;
            C[(size_t)row*N + col] = acc[i][j] + (bias ? (double)bias[col] : 0.0);
        }
    }
}

// ---------------- int8 MFMA GEMM (exact), 256 thr + XCD swizzle ------------
template<int GATE, int PRE>
__global__ __launch_bounds__(256)
void k_qgemm(const signed char* __restrict__ A8, const double* __restrict__ ascale,
             const float* __restrict__ Wf, const signed char* __restrict__ W8,
             const double* __restrict__ wsum, long long wcount,
             const float* __restrict__ bias, double* __restrict__ C,
             int M, int N, int K, int accum, int gridM)
{
    __shared__ __align__(16) signed char Als[4][128][16];
    __shared__ __align__(16) signed char Bls[4][128][16];
    __shared__ __align__(16) signed char B2ls[GATE?4:1][GATE?128:1][16];
    const int tid = threadIdx.x;
    const int lane = tid & 63, wid = tid >> 6;
    const int wr = wid >> 1, wc = wid & 1;             // 2x2 waves, 64x64 each
    const int2 bxy = xcd_swz(gridM);
    const int m0 = bxy.x*128, n0 = bxy.y*128;
    const int ks = lane >> 4, fr = lane & 15;

    const double dqw = fmax(*wsum / (double)wcount, 1e-5);
    const double thr = 0.5 * dqw;

    i32x4 acc[4][4];
    i32x4 acc2[GATE?4:1][4];
#pragma unroll
    for (int i = 0; i < 4; ++i)
#pragma unroll
        for (int j = 0; j < 4; ++j) {
            acc[i][j] = i32x4{0,0,0,0};
            if constexpr (GATE) acc2[i][j] = i32x4{0,0,0,0};
        }

    for (int kt = 0; kt < K; kt += 64) {
#pragma unroll
        for (int c = 0; c < 2; ++c) {
            int idx = tid + c*256;
            int row = idx & 127, kslot = idx >> 7;
            i32x4 v = {0,0,0,0};
            if (m0 + row < M)
                v = *reinterpret_cast<const i32x4*>(A8 + (size_t)(m0+row)*K + kt + kslot*16);
            *reinterpret_cast<i32x4*>(&Als[kslot][row][0]) = v;
        }
#pragma unroll
        for (int c = 0; c < 2; ++c) {
            int idx = tid + c*256;
            int row = idx & 127, kslot = idx >> 7;
            i32x4 pv = {0,0,0,0};
            if (n0 + row < N) {
                if constexpr (PRE) {
                    pv = *reinterpret_cast<const i32x4*>(W8 + (size_t)(n0+row)*K + kt + kslot*16);
                } else {
                    const float* wp = Wf + (size_t)(n0+row)*K + kt + kslot*16;
#pragma unroll
                    for (int d = 0; d < 4; ++d) {
                        float4 wv = *reinterpret_cast<const float4*>(wp + d*4);
                        float we[4] = {wv.x, wv.y, wv.z, wv.w};
                        unsigned p = 0;
#pragma unroll
                        for (int e = 0; e < 4; ++e) {
                            double wd = (double)we[e];
                            int q = (wd > thr) - (wd < -thr);
                            p |= ((unsigned)(q & 255)) << (8*e);
                        }
                        pv[d] = (int)p;
                    }
                }
            }
            *reinterpret_cast<i32x4*>(&Bls[kslot][row][0]) = pv;
        }
        if constexpr (GATE) {
#pragma unroll
            for (int c = 0; c < 2; ++c) {
                int idx = tid + c*256;
                int row = idx & 127, kslot = idx >> 7;
                i32x4 pv = {0,0,0,0};
                if (n0 + row < N) {
                    if constexpr (PRE) {
                        pv = *reinterpret_cast<const i32x4*>(W8 + (size_t)(n0+row+N)*K + kt + kslot*16);
                    } else {
                        const float* wp = Wf + (size_t)(n0+row+N)*K + kt + kslot*16;
#pragma unroll
                        for (int d = 0; d < 4; ++d) {
                            float4 wv = *reinterpret_cast<const float4*>(wp + d*4);
                            float we[4] = {wv.x, wv.y, wv.z, wv.w};
                            unsigned p = 0;
#pragma unroll
                            for (int e = 0; e < 4; ++e) {
                                double wd = (double)we[e];
                                int q = (wd > thr) - (wd < -thr);
                                p |= ((unsigned)(q & 255)) << (8*e);
                            }
                            pv[d] = (int)p;
                        }
                    }
                }
                *reinterpret_cast<i32x4*>(&B2ls[kslot][row][0]) = pv;
            }
        }
        __syncthreads();
        i32x4 a[4];
#pragma unroll
        for (int i = 0; i < 4; ++i)
            a[i] = *reinterpret_cast<const i32x4*>(&Als[ks][wr*64 + i*16 + fr][0]);
#pragma unroll
        for (int j = 0; j < 4; ++j) {
            i32x4 b = *reinterpret_cast<const i32x4*>(&Bls[ks][wc*64 + j*16 + fr][0]);
#pragma unroll
            for (int i = 0; i < 4; ++i)
                acc[i][j] = __builtin_amdgcn_mfma_i32_16x16x64_i8(a[i], b, acc[i][j], 0, 0, 0);
            if constexpr (GATE) {
                i32x4 b2 = *reinterpret_cast<const i32x4*>(&B2ls[ks][wc*64 + j*16 + fr][0]);
#pragma unroll
                for (int i = 0; i < 4; ++i)
                    acc2[i][j] = __builtin_amdgcn_mfma_i32_16x16x64_i8(a[i], b2, acc2[i][j], 0, 0, 0);
            }
        }
        __syncthreads();
    }

#pragma unroll
    for (int i = 0; i < 4; ++i) {
#pragma unroll
        for (int r = 0; r < 4; ++r) {
            int row = m0 + wr*64 + i*16 + (lane>>4)*4 + r;
            if (row >= M) continue;
            double mul = dqw / ascale[row];
#pragma unroll
            for (int j = 0; j < 4; ++j) {
                int col = n0 + wc*64 + j*16 + (lane & 15);
                if (col >= N) continue;
                size_t o = (size_t)row*N + col;
                if constexpr (GATE) {
                    double g = (double)acc[i][j][r] * mul;
                    double y = (double)acc2[i][j][r] * mul;
                    C[o] = g/(1.0+exp(-g)) * y;
                } else {
                    double v = (double)acc[i][j][r] * mul;
                    if (bias) v += (double)bias[col];
                    C[o] = accum ? C[o] + v : v;
                }
            }
        }
    }
}

// ---------------------------------------------------------------------------
extern "C" void kernel_launch(void* const* d_in, const int* in_sizes, int n_in,
                              void* d_out, int out_size, void* d_ws, size_t ws_size,
                              hipStream_t stream)
{
    (void)in_sizes; (void)n_in; (void)out_size;
    auto in = [&](int i){ return (const float*)d_in[i]; };

    const float *X = in(0), *T = in(1), *Y = in(2), *XC = in(3), *REF = in(4);
    const float *xe_w = in(6), *xe_b = in(7), *pos = in(8);
    const float *te_w1 = in(9), *te_b1 = in(10), *te_w2 = in(11), *te_b2 = in(12);
    const float *pp_w = in(13), *pp_b = in(14);
    const float *sa_pe_w = in(15), *sa_pe_b = in(16);
    const float *sa_ln_g = in(17), *sa_ln_b = in(18);
    const float *sa_gate_w = in(19), *sa_down_w = in(20);
    const float *sa_dc_w = in(21), *sa_dc_b = in(22);
    const float *ada_w = in(23), *ada_b = in(24);
    const float *sa_wi = in(25), *sa_wf = in(26), *sa_wg = in(27), *sa_wo = in(28);
    const float *mv_wi = in(29), *mv_wf = in(30), *mv_wg = in(31), *mv_wo = in(32);
    const float *rf_wi = in(33), *rf_wf = in(34), *rf_wg = in(35), *rf_wo = in(36);
    const float *gate_w = in(37), *down_w = in(38);
    const float *fl_w = in(39), *fl_b = in(40), *fl_ada_w = in(41), *fl_ada_b = in(42);
    float* OUT = (float*)d_out;

    // ---------- workspace layout ----------
    size_t off = 0;
    auto AL = [&](size_t bytes){ off = (off+255)&~(size_t)255; size_t r = off; off += bytes; return r; };
    const size_t oScale = AL(37*8);
    const size_t oPart  = AL(37*32*8);
    const size_t oProbe = AL(64*4*8);
    const size_t oFlag  = AL(256);
    const size_t oSM1 = AL(8*1152*8), oSM2 = AL(8*1152*8), oSM3 = AL(8*1152*8);
    const size_t oCB  = AL(8*1152*8);
    const size_t oMOD = AL(8*6912*8);
    const size_t oH   = AL((size_t)8192*1152*8);    // 75.5 MB; reused as OB later
    const size_t oINT = AL((size_t)1024*4608*8);
    const size_t oF0  = AL((size_t)2048*1152*8);    // also ACC
    const size_t oXT  = AL((size_t)2048*1152*8);
    const size_t oFB  = AL((size_t)2048*1152*8);
    const size_t oIB  = AL((size_t)2048*1152*8);
    const size_t oGB  = AL((size_t)2048*1152*8);
    const size_t oRO  = AL((size_t)512*1152*8);
    const size_t oQ8X = AL((size_t)2048*1152);
    const size_t oQ8I = AL((size_t)1024*4608);
    const size_t oQ8O = AL((size_t)2048*1152);
    const size_t oQ8R = AL((size_t)512*1152);
    const size_t oQ8T = AL((size_t)8*1152);
    const size_t oQ8C = AL((size_t)8*1152);
    const size_t oDSX = AL(2048*8), oDSI = AL(1024*8), oDSO = AL(2048*8);
    const size_t oDSR = AL(512*8),  oDST = AL(8*8),    oDSC = AL(8*8);
    if (off > ws_size) return;

    // ---------- weight list + optional pre-ternarized region ----------
    WList wl{}; WOffs wo{};
    long long wn[37];
    int nw = 0;
    auto addw = [&](const float* w, long long n){ wl.p[nw]=w; wl.n[nw]=n; wn[nw]=n; nw++; };
    addw(te_w1, 294912); addw(te_w2, 1327104); addw(pp_w, 884736);
    addw(sa_gate_w, 10616832); addw(sa_down_w, 5308416);
    for (int l = 0; l < 2; ++l) {
        addw(ada_w + (size_t)l*7962624, 7962624);
        addw(sa_wi + (size_t)l*1327104, 1327104);
        addw(sa_wf + (size_t)l*1327104, 1327104);
        addw(sa_wg + (size_t)l*1327104, 1327104);
        addw(sa_wo + (size_t)l*1327104, 1327104);
        addw(mv_wi + (size_t)l*1327104, 1327104);
        addw(mv_wf + (size_t)l*1327104, 1327104);
        addw(mv_wg + (size_t)l*1327104, 1327104);
        addw(mv_wo + (size_t)l*1327104, 1327104);
        addw(rf_wi + (size_t)l*1327104, 1327104);
        addw(rf_wf + (size_t)l*1327104, 1327104);
        addw(rf_wg + (size_t)l*1327104, 1327104);
        addw(rf_wo + (size_t)l*1327104, 1327104);
        addw(gate_w + (size_t)l*10616832, 10616832);
        addw(down_w + (size_t)l*5308416, 5308416);
    }
    addw(fl_ada_w, 2654208); addw(fl_w, 36864);

    size_t off_saved = off;
    long long wtot = 0;
    for (int i = 0; i < 37; ++i) { wo.o[i] = wtot; wtot += (wn[i] + 255) & ~255LL; }
    const size_t oW8 = AL((size_t)wtot);
    const bool useW8 = (off <= ws_size);
    if (!useW8) off = off_saved;

    // ---------- tiered SA/MLP chunk enlargement (row-independent) ----------
    int schunk = 1024;
    size_t oINTb = 0, oQ8Ib = 0, oQ8Xb = 0, oDSXb = 0, oDSIb = 0;
    if (useW8) {
        size_t off_w8 = off;
        oINTb = AL((size_t)4096*4608*8); oQ8Ib = AL((size_t)4096*4608);
        oQ8Xb = AL((size_t)4096*1152);   oDSXb = AL(4096*8); oDSIb = AL(4096*8);
        if (off <= ws_size) schunk = 4096;
        else {
            off = off_w8;
            oINTb = AL((size_t)2048*4608*8); oQ8Ib = AL((size_t)2048*4608); oDSIb = AL(2048*8);
            if (off <= ws_size) schunk = 2048;
            else off = off_w8;
        }
    }

    char* w8p = (char*)d_ws;
    double* scales = (double*)(w8p + oScale);
    double* parts  = (double*)(w8p + oPart);
    double* probeD = (double*)(w8p + oProbe);
    int*    mflag  = (int*)(w8p + oFlag);
    double *SM1=(double*)(w8p+oSM1), *SM2=(double*)(w8p+oSM2), *SM3=(double*)(w8p+oSM3);
    double *CB=(double*)(w8p+oCB), *MOD=(double*)(w8p+oMOD);
    double *H=(double*)(w8p+oH), *INT=(double*)(w8p+oINT);
    double *F0=(double*)(w8p+oF0), *XT=(double*)(w8p+oXT);
    double *FB=(double*)(w8p+oFB), *IB=(double*)(w8p+oIB), *GB=(double*)(w8p+oGB);
    double *ACC=F0, *OB=H, *RO=(double*)(w8p+oRO);
    signed char *Q8X=(signed char*)(w8p+oQ8X), *Q8I=(signed char*)(w8p+oQ8I);
    signed char *Q8O=(signed char*)(w8p+oQ8O), *Q8R=(signed char*)(w8p+oQ8R);
    signed char *Q8T=(signed char*)(w8p+oQ8T), *Q8C=(signed char*)(w8p+oQ8C);
    double *DSX=(double*)(w8p+oDSX), *DSI=(double*)(w8p+oDSI), *DSO=(double*)(w8p+oDSO);
    double *DSR=(double*)(w8p+oDSR), *DST=(double*)(w8p+oDST), *DSC=(double*)(w8p+oDSC);
    signed char* W8 = (signed char*)(w8p + oW8);

    // SA-chunk buffer selection
    double*      INTs = (schunk > 1024) ? (double*)(w8p + oINTb) : INT;
    signed char* Q8Is = (schunk > 1024) ? (signed char*)(w8p + oQ8Ib) : Q8I;
    double*      DSIs = (schunk > 1024) ? (double*)(w8p + oDSIb) : DSI;
    signed char* Q8Xs = (schunk == 4096) ? (signed char*)(w8p + oQ8Xb) : Q8X;
    double*      DSXs = (schunk == 4096) ? (double*)(w8p + oDSXb) : DSX;

    // ---------- probe f64 MFMA layout + weight scales + ternarize ----------
    k_mfma64_probe<<<1, 64, 0, stream>>>(probeD);
    k_mfma64_check<<<1, 64, 0, stream>>>(probeD, mflag);
    k_abssum_all<<<dim3(32,37), 256, 0, stream>>>(wl, parts);
    k_abssum_fin<<<37, 64, 0, stream>>>(parts, scales);
    if (useW8)
        k_ternarize<<<dim3(64,37), 256, 0, stream>>>(wl, wo, scales, W8);

    // ---------- launch helpers ----------
    auto qgemm = [&](const signed char* A8, const double* as, const float* Win, int slot,
                     const float* b, double* Cout, int M, int N, int K, int accum){
        int gm = (M+127)/128, gn = (N+127)/128;
        if (useW8)
            k_qgemm<0,1><<<gm*gn, 256, 0, stream>>>(A8, as, Win, W8 + wo.o[slot],
                                                    scales+slot, wn[slot], b, Cout, M, N, K, accum, gm);
        else
            k_qgemm<0,0><<<gm*gn, 256, 0, stream>>>(A8, as, Win, nullptr,
                                                    scales+slot, wn[slot], b, Cout, M, N, K, accum, gm);
    };
    auto qgemmGate = [&](const signed char* A8, const double* as, const float* Win, int slot,
                         double* Cout, int M){
        int gm = (M+127)/128;
        if (useW8)
            k_qgemm<1,1><<<gm*36, 256, 0, stream>>>(A8, as, Win, W8 + wo.o[slot],
                                                    scales+slot, wn[slot], nullptr, Cout, M, 4608, 1152, 0, gm);
        else
            k_qgemm<1,0><<<gm*36, 256, 0, stream>>>(A8, as, Win, nullptr,
                                                    scales+slot, wn[slot], nullptr, Cout, M, 4608, 1152, 0, gm);
    };

    // ---------- conditioning vector c ----------
    k_temb<<<8, 128, 0, stream>>>(T, SM1);
    k_rsq8<double><<<8, 256, 0, stream>>>(SM1, Q8T, DST, 256, 0);
    qgemm(Q8T, DST, te_w1, 0, te_b1, SM3, 8, 1152, 256, 0);
    k_rsq8<double><<<8, 256, 0, stream>>>(SM3, Q8T, DST, 1152, 1);
    qgemm(Q8T, DST, te_w2, 1, te_b2, SM2, 8, 1152, 1152, 0);
    k_rsq8<float><<<8, 256, 0, stream>>>(Y, Q8T, DST, 768, 0);
    qgemm(Q8T, DST, pp_w, 2, pp_b, SM3, 8, 1152, 768, 0);
    k_add<<<36, 256, 0, stream>>>(SM2, SM3, CB, 9216);
    k_rsq8<double><<<8, 256, 0, stream>>>(CB, Q8C, DSC, 1152, 1);

    // ---------- spatial adapter: patch embed + block 0 only ----------
    k_dgemm<1,0><<<18*128, 256, 0, stream>>>(XC, sa_pe_w, sa_pe_b, H, 8192, 1152, 1536, 18, mflag);
    {
        const int nch = 8192 / schunk;
        for (int ch = 0; ch < nch; ++ch) {
            double* Hrow = H + (size_t)ch*schunk*1152;
            k_lnq8<<<schunk, 256, 1152*8, stream>>>(Hrow, Q8Xs, DSXs, 1152, sa_ln_g, sa_ln_b,
                                                    nullptr, nullptr, 0, 1e-5);
            qgemmGate(Q8Xs, DSXs, sa_gate_w, 3, INTs, schunk);
            k_rsq8<double><<<schunk, 256, 0, stream>>>(INTs, Q8Is, DSIs, 4608, 0);
            qgemm(Q8Is, DSIs, sa_down_w, 4, nullptr, Hrow, schunk, 1152, 4608, 0);
        }
    }
    k_dgemm<2,1><<<18*32, 256, 0, stream>>>(H, sa_dc_w, sa_dc_b, F0, 2048, 1152, 4608, 18, mflag);

    // ---------- patchify latents + pos + feats0 ----------
    k_patchify<<<9216, 256, 0, stream>>>(X, xe_w, xe_b, pos, F0, XT);
    k_rsq8<float><<<512, 256, 0, stream>>>(REF, Q8R, DSR, 1152, 0);

    // ---------- transformer blocks (OB aliases dead H) ----------
    for (int l = 0; l < 2; ++l) {
        int sb = 5 + l*15;
        const float *wada = ada_w + (size_t)l*7962624, *bada = ada_b + (size_t)l*6912;
        const float *swi = sa_wi + (size_t)l*1327104, *swf = sa_wf + (size_t)l*1327104;
        const float *swg = sa_wg + (size_t)l*1327104, *swo = sa_wo + (size_t)l*1327104;
        const float *mwi = mv_wi + (size_t)l*1327104, *mwf = mv_wf + (size_t)l*1327104;
        const float *mwg = mv_wg + (size_t)l*1327104, *mwo = mv_wo + (size_t)l*1327104;
        const float *rwi = rf_wi + (size_t)l*1327104, *rwf = rf_wf + (size_t)l*1327104;
        const float *rwg = rf_wg + (size_t)l*1327104, *rwo = rf_wo + (size_t)l*1327104;
        const float *wgt = gate_w + (size_t)l*10616832, *wdn = down_w + (size_t)l*5308416;

        qgemm(Q8C, DSC, wada, sb+0, bada, MOD, 8, 6912, 1152, 0);

        k_lnq8<<<2048, 256, 1152*8, stream>>>(XT, Q8X, DSX, 1152, nullptr, nullptr,
                                              MOD+0, MOD+1152, 6912, 1e-6);

        // self attention (seq = 256 tokens)
        qgemm(Q8X, DSX, swf, sb+2, nullptr, FB, 2048, 1152, 1152, 0);
        qgemm(Q8X, DSX, swi, sb+1, nullptr, IB, 2048, 1152, 1152, 0);
        qgemm(Q8X, DSX, swg, sb+3, nullptr, GB, 2048, 1152, 1152, 0);
        k_gatepre<<<9216, 256, 0, stream>>>(FB, IB, 2359296LL);
        k_scan2<<<36, 256, 0, stream>>>(FB, IB, OB, 8, 294912LL, 1152, 1152LL, 256);
        k_ogateq8<<<2048, 256, 1152*8, stream>>>(OB, GB, Q8O, DSO, 1152);
        qgemm(Q8O, DSO, swo, sb+4, nullptr, ACC, 2048, 1152, 1152, 0);

        // multi-view attention (seq = 4 views; token layout unchanged)
        qgemm(Q8X, DSX, mwf, sb+6, nullptr, FB, 2048, 1152, 1152, 0);
        qgemm(Q8X, DSX, mwi, sb+5, nullptr, IB, 2048, 1152, 1152, 0);
        qgemm(Q8X, DSX, mwg, sb+7, nullptr, GB, 2048, 1152, 1152, 0);
        k_gatepre<<<9216, 256, 0, stream>>>(FB, IB, 2359296LL);
        k_scan2<<<2304, 256, 0, stream>>>(FB, IB, OB, 2, 1179648LL, 294912, 294912LL, 4);
        k_ogateq8<<<2048, 256, 1152*8, stream>>>(OB, GB, Q8O, DSO, 1152);
        qgemm(Q8O, DSO, mwo, sb+8, nullptr, ACC, 2048, 1152, 1152, 1);   // +=

        // ref attention on 2 unique batches
        qgemm(Q8R, DSR, rwf, sb+10, nullptr, FB, 512, 1152, 1152, 0);
        qgemm(Q8R, DSR, rwi, sb+9,  nullptr, IB, 512, 1152, 1152, 0);
        qgemm(Q8R, DSR, rwg, sb+11, nullptr, GB, 512, 1152, 1152, 0);
        k_gatepre<<<2304, 256, 0, stream>>>(FB, IB, 589824LL);
        k_scan2<<<9, 256, 0, stream>>>(FB, IB, OB, 2, 294912LL, 1152, 1152LL, 256);
        k_ogateq8<<<512, 256, 1152*8, stream>>>(OB, GB, Q8O, DSO, 1152);
        qgemm(Q8O, DSO, rwo, sb+12, nullptr, RO, 512, 1152, 1152, 0);

        k_resid_attn<<<9216, 256, 0, stream>>>(XT, ACC, RO, MOD);

        // MLP
        k_lnq8<<<2048, 256, 1152*8, stream>>>(XT, Q8X, DSX, 1152, nullptr, nullptr,
                                              MOD+3*1152, MOD+4*1152, 6912, 1e-6);
        if (schunk >= 2048) {
            qgemmGate(Q8X, DSX, wgt, sb+13, INTs, 2048);
            k_rsq8<double><<<2048, 256, 0, stream>>>(INTs, Q8Is, DSIs, 4608, 0);
            qgemm(Q8Is, DSIs, wdn, sb+14, nullptr, OB, 2048, 1152, 4608, 0);
        } else {
            for (int ch = 0; ch < 2; ++ch) {
                qgemmGate(Q8X + (size_t)ch*1024*1152, DSX + ch*1024, wgt, sb+13, INT, 1024);
                k_rsq8<double><<<1024, 256, 0, stream>>>(INT, Q8I, DSI, 4608, 0);
                qgemm(Q8I, DSI, wdn, sb+14, nullptr, OB + (size_t)ch*1024*1152, 1024, 1152, 4608, 0);
            }
        }
        k_resid_mlp<<<9216, 256, 0, stream>>>(XT, OB, MOD);
    }

    // ---------- final layer + unpatchify ----------
    qgemm(Q8C, DSC, fl_ada_w, 35, fl_ada_b, MOD, 8, 2304, 1152, 0);
    k_lnq8<<<2048, 256, 1152*8, stream>>>(XT, Q8X, DSX, 1152, nullptr, nullptr,
                                          MOD+0, MOD+1152, 2304, 1e-6);
    qgemm(Q8X, DSX, fl_w, 36, fl_b, FB, 2048, 32, 1152, 0);
    k_unpatch<<<256, 256, 0, stream>>>(FB, OUT);
}

// Round 11
// 5163.140 us; speedup vs baseline: 1.2704x; 1.0839x over previous
//
#include <hip/hip_runtime.h>

#define DEV __device__ __forceinline__

typedef __attribute__((ext_vector_type(4))) int i32x4;
typedef __attribute__((ext_vector_type(4))) double f64x4;

// ---------------------------------------------------------------------------
// TernaryMVAdapter forward on MI355X. Round 11: round-10 pipeline (f64-exact,
// absmax floor ~0.035, replay-safe, 5596us) with the f64-MFMA probe widened:
// round-10's probe REJECTED both candidate D layouts (flag=0 -> SIMT ran,
// MfmaUtil=0, dgemm unchanged). The checker now brute-forces 16 combos:
// {A lane-map: (i,k)=(l&15,l>>4) | (l>>2,l&3)} x {B likewise} x
// {D: row=4*(l>>4)+r | row=4r+(l>>4), each +transpose}. Exact-integer match
// -> flag=1+combo; k_dgemm decodes combo into uniform index math. SIMT
// fallback if still no match (bitwise round-10 behavior).
// ---------------------------------------------------------------------------

struct WList { const float* p[37]; long long n[37]; };
struct WOffs { long long o[37]; };

DEV int2 xcd_swz(int gridx)
{
    const int nwg = (int)gridDim.x, b = (int)blockIdx.x;
    const int q = nwg >> 3, r = nwg & 7, xcd = b & 7, idx = b >> 3;
    const int lb = (xcd < r ? xcd*(q+1) : r*(q+1) + (xcd-r)*q) + idx;
    return make_int2(lb % gridx, lb / gridx);
}

// ---------------- f64 MFMA layout probe (exact-integer classification) -----
__global__ void k_mfma64_probe(double* __restrict__ out)
{
    const int lane = threadIdx.x;                      // 64 threads
    double a = (double)(1 + lane);                     // injective per-lane
    double b = (double)(101 + 3*lane);
    f64x4 acc = {0.0, 0.0, 0.0, 0.0};
    acc = __builtin_amdgcn_mfma_f64_16x16x4f64(a, b, acc, 0, 0, 0);
#pragma unroll
    for (int r = 0; r < 4; ++r) out[lane*4 + r] = acc[r];
}

__global__ void k_mfma64_check(const double* __restrict__ probe, int* __restrict__ flag)
{
    if (threadIdx.x != 0) return;
    int best = 0;
    for (int c = 0; c < 16 && !best; ++c) {
        const int a_alt = c & 1, b_alt = (c >> 1) & 1, dv = (c >> 2) & 3;
        double Amat[16][4], Bmat[4][16];
        for (int l = 0; l < 64; ++l) {
            int ai = a_alt ? (l >> 2) : (l & 15);
            int ak = a_alt ? (l & 3)  : (l >> 4);
            Amat[ai][ak] = (double)(1 + l);
            int bj = b_alt ? (l >> 2) : (l & 15);
            int bk = b_alt ? (l & 3)  : (l >> 4);
            Bmat[bk][bj] = (double)(101 + 3*l);
        }
        double C[16][16];
        for (int i = 0; i < 16; ++i)
            for (int j = 0; j < 16; ++j) {
                double s = 0.0;
                for (int k = 0; k < 4; ++k) s += Amat[i][k] * Bmat[k][j];
                C[i][j] = s;                           // exact integers in f64
            }
        bool ok = true;
        for (int l = 0; l < 64 && ok; ++l)
            for (int r = 0; r < 4 && ok; ++r) {
                int ir = (dv & 2) ? (4*r + (l >> 4)) : (4*(l >> 4) + r);
                int ic = l & 15;
                if (dv & 1) { int t = ir; ir = ic; ic = t; }
                if (probe[l*4 + r] != C[ir][ic]) ok = false;
            }
        if (ok) best = 1 + c;
    }
    *flag = best;
}

// ---------------- fused deterministic |w| sums (37 slots) ------------------
__global__ void k_abssum_all(WList wl, double* __restrict__ partials)
{
    const int slot = blockIdx.y;
    const float* w = wl.p[slot];
    const long long n = wl.n[slot];
    __shared__ double sm[256];
    double s = 0.0;
    for (long long i = (long long)blockIdx.x*256 + threadIdx.x; i < n; i += 32LL*256)
        s += (double)fabsf(w[i]);
    sm[threadIdx.x] = s;
    __syncthreads();
    for (int k = 128; k > 0; k >>= 1) {
        if ((int)threadIdx.x < k) sm[threadIdx.x] += sm[threadIdx.x + k];
        __syncthreads();
    }
    if (threadIdx.x == 0) partials[slot*32 + blockIdx.x] = sm[0];
}

__global__ void k_abssum_fin(const double* __restrict__ partials, double* __restrict__ out)
{
    const int slot = blockIdx.x;
    if (threadIdx.x == 0) {
        double s = 0.0;
        for (int i = 0; i < 32; ++i) s += partials[slot*32 + i];
        out[slot] = s;
    }
}

// ---------------- one-time weight ternarization (f64-exact decision) -------
__global__ void k_ternarize(WList wl, WOffs wo, const double* __restrict__ scales,
                            signed char* __restrict__ W8)
{
    const int slot = blockIdx.y;
    const float* w = wl.p[slot];
    const long long n4 = wl.n[slot] >> 2;
    const double dqw = fmax(scales[slot] / (double)wl.n[slot], 1e-5);
    const double thr = 0.5 * dqw;
    signed char* o = W8 + wo.o[slot];
    for (long long i = (long long)blockIdx.x*256 + threadIdx.x; i < n4; i += 64LL*256) {
        float4 v = *reinterpret_cast<const float4*>(w + i*4);
        float we[4] = {v.x, v.y, v.z, v.w};
        char r[4];
#pragma unroll
        for (int e = 0; e < 4; ++e) {
            double wd = (double)we[e];
            r[e] = (char)((wd > thr) - (wd < -thr));
        }
        *reinterpret_cast<char4*>(o + i*4) = make_char4(r[0], r[1], r[2], r[3]);
    }
}

// ---------------- timestep frequency embedding (f64) -----------------------
__global__ void k_temb(const float* __restrict__ t, double* __restrict__ out)
{
    int b = blockIdx.x, j = threadIdx.x;               // 8 x 128
    double fr  = exp(-9.210340371976184 * (double)j / 128.0);
    double ang = (double)t[b] * fr;
    out[b*256 + j]       = cos(ang);
    out[b*256 + 128 + j] = sin(ang);
}

// ---------------- rmsnorm + int8 absmax quant (f64, LDS-free) --------------
template<typename TI>
__global__ void k_rsq8(const TI* __restrict__ x, signed char* __restrict__ q8,
                       double* __restrict__ dscale, int K, int pre_silu)
{
    __shared__ double red[256], red2[256];
    const int row = blockIdx.x, tid = threadIdx.x;
    const TI* xr = x + (size_t)row*K;
    double ss = 0.0, am = 0.0;
    for (int i = tid; i < K; i += 256) {
        double v = (double)xr[i];
        if (pre_silu) v = v / (1.0 + exp(-v));
        ss += v*v; am = fmax(am, fabs(v));
    }
    red[tid] = ss; red2[tid] = am;
    __syncthreads();
    for (int s = 128; s > 0; s >>= 1) {
        if (tid < s) { red[tid] += red[tid+s]; red2[tid] = fmax(red2[tid], red2[tid+s]); }
        __syncthreads();
    }
    double rms = 1.0 / sqrt(red[0]/(double)K + 1e-8);
    double s   = 127.0 / fmax(red2[0]*rms, 1e-5);
    signed char* orow = q8 + (size_t)row*K;
    for (int i = tid; i < K; i += 256) {
        double v = (double)xr[i];
        if (pre_silu) v = v / (1.0 + exp(-v));
        orow[i] = (signed char)(int)fmin(fmax(rint(v*rms*s), -128.0), 127.0);
    }
    if (tid == 0) dscale[row] = s;
}

// ---------------- layernorm(+gb/+mod) + rmsnorm + int8 quant (f64) ---------
__global__ void k_lnq8(const double* __restrict__ x, signed char* __restrict__ q8,
                       double* __restrict__ dscale, int K,
                       const float* __restrict__ gamma, const float* __restrict__ beta,
                       const double* __restrict__ sh, const double* __restrict__ sc,
                       int modstride, double eps)
{
    extern __shared__ double rb[];
    __shared__ double red[256], red2[256];
    const int row = blockIdx.x, tid = threadIdx.x;
    const double* xr = x + (size_t)row*K;
    double s1 = 0.0;
    for (int i = tid; i < K; i += 256) { double v = xr[i]; rb[i] = v; s1 += v; }
    red[tid] = s1; __syncthreads();
    for (int s = 128; s > 0; s >>= 1) { if (tid < s) red[tid] += red[tid+s]; __syncthreads(); }
    double mu = red[0]/(double)K;
    __syncthreads();
    double s2 = 0.0;
    for (int i = tid; i < K; i += 256) { double d = rb[i]-mu; s2 += d*d; }
    red[tid] = s2; __syncthreads();
    for (int s = 128; s > 0; s >>= 1) { if (tid < s) red[tid] += red[tid+s]; __syncthreads(); }
    double r = 1.0 / sqrt(red[0]/(double)K + eps);
    const int bn = row >> 8;
    __syncthreads();
    double ss = 0.0, am = 0.0;
    for (int i = tid; i < K; i += 256) {
        double y = (rb[i]-mu)*r;
        if (gamma) y = y*(double)gamma[i] + (double)beta[i];
        if (sh)    y = y*(1.0 + sc[(size_t)bn*modstride + i]) + sh[(size_t)bn*modstride + i];
        rb[i] = y; ss += y*y; am = fmax(am, fabs(y));
    }
    red[tid] = ss; red2[tid] = am;
    __syncthreads();
    for (int s = 128; s > 0; s >>= 1) {
        if (tid < s) { red[tid] += red[tid+s]; red2[tid] = fmax(red2[tid], red2[tid+s]); }
        __syncthreads();
    }
    double rms = 1.0 / sqrt(red[0]/(double)K + 1e-8);
    double s   = 127.0 / fmax(red2[0]*rms, 1e-5);
    signed char* orow = q8 + (size_t)row*K;
    for (int i = tid; i < K; i += 256)
        orow[i] = (signed char)(int)fmin(fmax(rint(rb[i]*rms*s), -128.0), 127.0);
    if (tid == 0) dscale[row] = s;
}

// ---------------- ogate (rmsnorm*g*sig(g)) + rmsnorm + quant (f64) ---------
__global__ void k_ogateq8(const double* __restrict__ O, const double* __restrict__ G,
                          signed char* __restrict__ q8, double* __restrict__ dscale, int K)
{
    extern __shared__ double rb[];
    __shared__ double red[256], red2[256];
    const int row = blockIdx.x, tid = threadIdx.x;
    const double* orow = O + (size_t)row*K;
    const double* grow = G + (size_t)row*K;
    double ss = 0.0;
    for (int i = tid; i < K; i += 256) { double v = orow[i]; rb[i] = v; ss += v*v; }
    red[tid] = ss; __syncthreads();
    for (int s = 128; s > 0; s >>= 1) { if (tid < s) red[tid] += red[tid+s]; __syncthreads(); }
    double rmso = 1.0 / sqrt(red[0]/(double)K + 1e-8);
    __syncthreads();
    double ss2 = 0.0, am = 0.0;
    for (int i = tid; i < K; i += 256) {
        double g = grow[i];
        double y = rb[i]*rmso * g / (1.0 + exp(-g));
        rb[i] = y; ss2 += y*y; am = fmax(am, fabs(y));
    }
    red[tid] = ss2; red2[tid] = am;
    __syncthreads();
    for (int s = 128; s > 0; s >>= 1) {
        if (tid < s) { red[tid] += red[tid+s]; red2[tid] = fmax(red2[tid], red2[tid+s]); }
        __syncthreads();
    }
    double rms = 1.0 / sqrt(red[0]/(double)K + 1e-8);
    double s   = 127.0 / fmax(red2[0]*rms, 1e-5);
    signed char* qrow = q8 + (size_t)row*K;
    for (int i = tid; i < K; i += 256)
        qrow[i] = (signed char)(int)fmin(fmax(rint(rb[i]*rms*s), -128.0), 127.0);
    if (tid == 0) dscale[row] = s;
}

// ---------------- HGRN gate precompute + lean serial scan ------------------
__global__ void k_gatepre(double* __restrict__ F, double* __restrict__ I, long long n)
{
    long long i = (long long)blockIdx.x*256 + threadIdx.x;
    if (i >= n) return;
    double fp = F[i], ip = I[i];
    double f = 1.0/(1.0+exp(-fp));
    double v = (ip/(1.0+exp(-ip)))*(1.0-f);
    F[i] = f; I[i] = v;
}

__global__ void k_scan2(const double* __restrict__ F, const double* __restrict__ V,
                        double* __restrict__ O, int n_outer, long long outer_stride,
                        int n_inner, long long t_stride, int T)
{
    long long chain = (long long)blockIdx.x*blockDim.x + threadIdx.x;
    if (chain >= (long long)n_outer*n_inner) return;
    long long base = (chain / n_inner)*outer_stride + (chain % n_inner);
    double h = 0.0;
    for (int t = 0; t < T; ++t) {
        long long idx = base + (long long)t*t_stride;
        h = F[idx]*h + V[idx];
        O[idx] = h;
    }
}

// ---------------- misc elementwise (f64) -----------------------------------
__global__ void k_add(const double* __restrict__ a, const double* __restrict__ b,
                      double* __restrict__ o, int n)
{
    int i = blockIdx.x*256 + threadIdx.x;
    if (i < n) o[i] = a[i] + b[i];
}

__global__ void k_resid_attn(double* __restrict__ xt, const double* __restrict__ acc,
                             const double* __restrict__ refo, const double* __restrict__ mod)
{
    int idx = blockIdx.x*256 + threadIdx.x;            // 2048*1152 exact
    int r = idx / 1152, d = idx - r*1152;
    int bn = r >> 8, l = r & 255;
    double ga = mod[(size_t)bn*6912 + 2*1152 + d];
    double rv = refo[((size_t)((bn>>2)*256 + l))*1152 + d];
    xt[idx] += ga*(acc[idx] + rv);
}

__global__ void k_resid_mlp(double* __restrict__ xt, const double* __restrict__ t2,
                            const double* __restrict__ mod)
{
    int idx = blockIdx.x*256 + threadIdx.x;
    int r = idx / 1152, d = idx - r*1152;
    int bn = r >> 8;
    xt[idx] += mod[(size_t)bn*6912 + 5*1152 + d] * t2[idx];
}

__global__ void k_patchify(const float* __restrict__ x, const float* __restrict__ w,
                           const float* __restrict__ bias, const float* __restrict__ pos,
                           const double* __restrict__ f0, double* __restrict__ xt)
{
    int idx = blockIdx.x*256 + threadIdx.x;            // 2048*1152 exact
    int r = idx / 1152, o = idx - r*1152;
    int bn = r >> 8, p = r & 255;
    int y = p >> 4, xx = p & 15;
    double acc = (double)bias[o] + (double)pos[(size_t)p*1152 + o] + f0[idx];
#pragma unroll
    for (int c = 0; c < 4; ++c)
#pragma unroll
        for (int ky = 0; ky < 2; ++ky)
#pragma unroll
            for (int kx = 0; kx < 2; ++kx)
                acc += (double)x[((size_t)(bn*4 + c)*32 + 2*y+ky)*32 + 2*xx+kx]
                     * (double)w[o*16 + c*4 + ky*2 + kx];
    xt[idx] = acc;
}

__global__ void k_unpatch(const double* __restrict__ flo, float* __restrict__ out)
{
    int idx = blockIdx.x*256 + threadIdx.x;            // 65536 exact
    int xx = idx & 31, y = (idx>>5)&31, ch = (idx>>10)&7, b = idx>>13;
    int hp = y>>1, py = y&1, wp = xx>>1, px = xx&1;
    out[idx] = (float)flo[((size_t)(b*256 + hp*16 + wp))*32 + (py*2+px)*8 + ch];
}

// ---------------- f64 GEMM: probed MFMA path + proven SIMT fallback --------
template<int AMODE>
DEV void load_a4d(const void* __restrict__ A, int row, int k, int M, double o[4])
{
    if (row >= M) { o[0]=o[1]=o[2]=o[3]=0.0; return; }
    if constexpr (AMODE == 1) {
        const float* Af = (const float*)A;
        int b = row>>10, p = row&1023, oy = p>>5, ox = p&31;
        int c = k>>8, ky = (k>>4)&15, kx = k&15;
        float4 v = *reinterpret_cast<const float4*>(
            Af + (((size_t)(b*6+c)*512 + (size_t)(oy*16+ky))*512 + (size_t)(ox*16+kx)));
        o[0]=v.x; o[1]=v.y; o[2]=v.z; o[3]=v.w;
    } else {
        const double* Ad = (const double*)A;
        int b = row>>8, y = (row>>4)&15, x = row&15;
        int q = k/1152, c = k - q*1152, ky = q>>1, kx = q&1;
        const double* p = Ad + (size_t)(b*1024 + (2*y+ky)*32 + 2*x+kx)*1152 + c;
        o[0]=p[0]; o[1]=p[1]; o[2]=p[2]; o[3]=p[3];
    }
}

template<int WMODE>
DEV void load_w4d(const float* __restrict__ W, int row, int k, int Nb, int K, double o[4])
{
    if (row >= Nb) { o[0]=o[1]=o[2]=o[3]=0.0; return; }
    if constexpr (WMODE == 0) {
        float4 v = *reinterpret_cast<const float4*>(W + (size_t)row*K + k);
        o[0]=v.x; o[1]=v.y; o[2]=v.z; o[3]=v.w;
    } else {
        int q = k/1152, c = k - q*1152;
        const float* p = W + (size_t)row*4608 + (size_t)c*4 + q;
        o[0]=p[0]; o[1]=p[4]; o[2]=p[8]; o[3]=p[12];
    }
}

template<int AMODE, int WMODE>
__global__ __launch_bounds__(256)
void k_dgemm(const void* __restrict__ A, const float* __restrict__ W,
             const float* __restrict__ bias, double* __restrict__ C,
             int M, int N, int K, int gridx, const int* __restrict__ mfma_flag)
{
    __shared__ double As[64][17];                  // [m][k], +1 pad
    __shared__ double Ws[64][17];                  // [n][k]
    const int tid = threadIdx.x;
    const int2 bxy = xcd_swz(gridx);
    const int m0 = bxy.y*64, n0 = bxy.x*64;
    const int lr = tid >> 2;                       // staging row 0..63
    const int lc = (tid & 3) * 4;                  // staging k {0,4,8,12}
    const int flag = *mfma_flag;                   // uniform

    if (flag) {
        // ---- f64 MFMA path (lane maps HW-verified this launch) ----
        const int cmb = flag - 1;
        const int a_alt = cmb & 1, b_alt = (cmb >> 1) & 1, dv = (cmb >> 2) & 3;
        const int lane = tid & 63, wid = tid >> 6;
        const int wm = wid >> 1, wn = wid & 1;     // 2x2 waves of 32x32
        const int ai = a_alt ? (lane >> 2) : (lane & 15);
        const int ak = a_alt ? (lane & 3)  : (lane >> 4);
        const int bj = b_alt ? (lane >> 2) : (lane & 15);
        const int bk = b_alt ? (lane & 3)  : (lane >> 4);
        f64x4 fa[2][2];
#pragma unroll
        for (int i = 0; i < 2; ++i)
#pragma unroll
            for (int j = 0; j < 2; ++j) fa[i][j] = f64x4{0.0,0.0,0.0,0.0};

        for (int kt = 0; kt < K; kt += 16) {
            {
                double v[4];
                load_a4d<AMODE>(A, m0+lr, kt+lc, M, v);
                As[lr][lc+0]=v[0]; As[lr][lc+1]=v[1]; As[lr][lc+2]=v[2]; As[lr][lc+3]=v[3];
            }
            {
                double wv[4];
                load_w4d<WMODE>(W, n0+lr, kt+lc, N, K, wv);
                Ws[lr][lc+0]=wv[0]; Ws[lr][lc+1]=wv[1]; Ws[lr][lc+2]=wv[2]; Ws[lr][lc+3]=wv[3];
            }
            __syncthreads();
#pragma unroll
            for (int k4 = 0; k4 < 4; ++k4) {
                double a0 = As[wm*32 + ai][k4*4 + ak];
                double a1 = As[wm*32 + 16 + ai][k4*4 + ak];
                double b0 = Ws[wn*32 + bj][k4*4 + bk];
                double b1 = Ws[wn*32 + 16 + bj][k4*4 + bk];
                fa[0][0] = __builtin_amdgcn_mfma_f64_16x16x4f64(a0, b0, fa[0][0], 0, 0, 0);
                fa[0][1] = __builtin_amdgcn_mfma_f64_16x16x4f64(a0, b1, fa[0][1], 0, 0, 0);
                fa[1][0] = __builtin_amdgcn_mfma_f64_16x16x4f64(a1, b0, fa[1][0], 0, 0, 0);
                fa[1][1] = __builtin_amdgcn_mfma_f64_16x16x4f64(a1, b1, fa[1][1], 0, 0, 0);
            }
            __syncthreads();
        }
#pragma unroll
        for (int i = 0; i < 2; ++i)
#pragma unroll
            for (int j = 0; j < 2; ++j)
#pragma unroll
                for (int r = 0; r < 4; ++r) {
                    int ir = (dv & 2) ? (4*r + (lane >> 4)) : (4*(lane >> 4) + r);
                    int ic = lane & 15;
                    if (dv & 1) { int t = ir; ir = ic; ic = t; }
                    int row = m0 + wm*32 + i*16 + ir;
                    int col = n0 + wn*32 + j*16 + ic;
                    if (row < M && col < N)
                        C[(size_t)row*N + col] = fa[i][j][r] + (bias ? (double)bias[col] : 0.0);
                }
        return;
    }

    // ---- SIMT fallback (proven rounds 3-10) ----
    const int tx = tid & 15, ty = tid >> 4;
    double acc[4][4] = {};
    for (int kt = 0; kt < K; kt += 16) {
        {
            double v[4];
            load_a4d<AMODE>(A, m0+lr, kt+lc, M, v);
            As[lr][lc+0]=v[0]; As[lr][lc+1]=v[1]; As[lr][lc+2]=v[2]; As[lr][lc+3]=v[3];
        }
        {
            double wv[4];
            load_w4d<WMODE>(W, n0+lr, kt+lc, N, K, wv);
            Ws[lr][lc+0]=wv[0]; Ws[lr][lc+1]=wv[1]; Ws[lr][lc+2]=wv[2]; Ws[lr][lc+3]=wv[3];
        }
        __syncthreads();
#pragma unroll
        for (int k = 0; k < 16; ++k) {
            double a[4], b[4];
#pragma unroll
            for (int e = 0; e < 4; ++e) { a[e] = As[ty + 16*e][k]; b[e] = Ws[tx + 16*e][k]; }
#pragma unroll
            for (int i = 0; i < 4; ++i)
#pragma unroll
                for (int j = 0; j < 4; ++j) acc[i][j] += a[i]*b[j];
        }
        __syncthreads();
    }
#pragma unroll
    for (int i = 0; i < 4; ++i) {
        int row = m0 + ty + 16*i;
        if (row >= M) continue;
#pragma unroll
        for (int j = 0; j < 4; ++j) {
            int col = n0 + tx + 16*j;
            if (col >= N) continue;
            C[(size_t)row*N + col] = acc[i][j] + (bias ? (double)bias[col] : 0.0);
        }
    }
}

// ---------------- int8 MFMA GEMM (exact), 256 thr + XCD swizzle ------------
template<int GATE, int PRE>
__global__ __launch_bounds__(256)
void k_qgemm(const signed char* __restrict__ A8, const double* __restrict__ ascale,
             const float* __restrict__ Wf, const signed char* __restrict__ W8,
             const double* __restrict__ wsum, long long wcount,
             const float* __restrict__ bias, double* __restrict__ C,
             int M, int N, int K, int accum, int gridM)
{
    __shared__ __align__(16) signed char Als[4][128][16];
    __shared__ __align__(16) signed char Bls[4][128][16];
    __shared__ __align__(16) signed char B2ls[GATE?4:1][GATE?128:1][16];
    const int tid = threadIdx.x;
    const int lane = tid & 63, wid = tid >> 6;
    const int wr = wid >> 1, wc = wid & 1;             // 2x2 waves, 64x64 each
    const int2 bxy = xcd_swz(gridM);
    const int m0 = bxy.x*128, n0 = bxy.y*128;
    const int ks = lane >> 4, fr = lane & 15;

    const double dqw = fmax(*wsum / (double)wcount, 1e-5);
    const double thr = 0.5 * dqw;

    i32x4 acc[4][4];
    i32x4 acc2[GATE?4:1][4];
#pragma unroll
    for (int i = 0; i < 4; ++i)
#pragma unroll
        for (int j = 0; j < 4; ++j) {
            acc[i][j] = i32x4{0,0,0,0};
            if constexpr (GATE) acc2[i][j] = i32x4{0,0,0,0};
        }

    for (int kt = 0; kt < K; kt += 64) {
#pragma unroll
        for (int c = 0; c < 2; ++c) {
            int idx = tid + c*256;
            int row = idx & 127, kslot = idx >> 7;
            i32x4 v = {0,0,0,0};
            if (m0 + row < M)
                v = *reinterpret_cast<const i32x4*>(A8 + (size_t)(m0+row)*K + kt + kslot*16);
            *reinterpret_cast<i32x4*>(&Als[kslot][row][0]) = v;
        }
#pragma unroll
        for (int c = 0; c < 2; ++c) {
            int idx = tid + c*256;
            int row = idx & 127, kslot = idx >> 7;
            i32x4 pv = {0,0,0,0};
            if (n0 + row < N) {
                if constexpr (PRE) {
                    pv = *reinterpret_cast<const i32x4*>(W8 + (size_t)(n0+row)*K + kt + kslot*16);
                } else {
                    const float* wp = Wf + (size_t)(n0+row)*K + kt + kslot*16;
#pragma unroll
                    for (int d = 0; d < 4; ++d) {
                        float4 wv = *reinterpret_cast<const float4*>(wp + d*4);
                        float we[4] = {wv.x, wv.y, wv.z, wv.w};
                        unsigned p = 0;
#pragma unroll
                        for (int e = 0; e < 4; ++e) {
                            double wd = (double)we[e];
                            int q = (wd > thr) - (wd < -thr);
                            p |= ((unsigned)(q & 255)) << (8*e);
                        }
                        pv[d] = (int)p;
                    }
                }
            }
            *reinterpret_cast<i32x4*>(&Bls[kslot][row][0]) = pv;
        }
        if constexpr (GATE) {
#pragma unroll
            for (int c = 0; c < 2; ++c) {
                int idx = tid + c*256;
                int row = idx & 127, kslot = idx >> 7;
                i32x4 pv = {0,0,0,0};
                if (n0 + row < N) {
                    if constexpr (PRE) {
                        pv = *reinterpret_cast<const i32x4*>(W8 + (size_t)(n0+row+N)*K + kt + kslot*16);
                    } else {
                        const float* wp = Wf + (size_t)(n0+row+N)*K + kt + kslot*16;
#pragma unroll
                        for (int d = 0; d < 4; ++d) {
                            float4 wv = *reinterpret_cast<const float4*>(wp + d*4);
                            float we[4] = {wv.x, wv.y, wv.z, wv.w};
                            unsigned p = 0;
#pragma unroll
                            for (int e = 0; e < 4; ++e) {
                                double wd = (double)we[e];
                                int q = (wd > thr) - (wd < -thr);
                                p |= ((unsigned)(q & 255)) << (8*e);
                            }
                            pv[d] = (int)p;
                        }
                    }
                }
                *reinterpret_cast<i32x4*>(&B2ls[kslot][row][0]) = pv;
            }
        }
        __syncthreads();
        i32x4 a[4];
#pragma unroll
        for (int i = 0; i < 4; ++i)
            a[i] = *reinterpret_cast<const i32x4*>(&Als[ks][wr*64 + i*16 + fr][0]);
#pragma unroll
        for (int j = 0; j < 4; ++j) {
            i32x4 b = *reinterpret_cast<const i32x4*>(&Bls[ks][wc*64 + j*16 + fr][0]);
#pragma unroll
            for (int i = 0; i < 4; ++i)
                acc[i][j] = __builtin_amdgcn_mfma_i32_16x16x64_i8(a[i], b, acc[i][j], 0, 0, 0);
            if constexpr (GATE) {
                i32x4 b2 = *reinterpret_cast<const i32x4*>(&B2ls[ks][wc*64 + j*16 + fr][0]);
#pragma unroll
                for (int i = 0; i < 4; ++i)
                    acc2[i][j] = __builtin_amdgcn_mfma_i32_16x16x64_i8(a[i], b2, acc2[i][j], 0, 0, 0);
            }
        }
        __syncthreads();
    }

#pragma unroll
    for (int i = 0; i < 4; ++i) {
#pragma unroll
        for (int r = 0; r < 4; ++r) {
            int row = m0 + wr*64 + i*16 + (lane>>4)*4 + r;
            if (row >= M) continue;
            double mul = dqw / ascale[row];
#pragma unroll
            for (int j = 0; j < 4; ++j) {
                int col = n0 + wc*64 + j*16 + (lane & 15);
                if (col >= N) continue;
                size_t o = (size_t)row*N + col;
                if constexpr (GATE) {
                    double g = (double)acc[i][j][r] * mul;
                    double y = (double)acc2[i][j][r] * mul;
                    C[o] = g/(1.0+exp(-g)) * y;
                } else {
                    double v = (double)acc[i][j][r] * mul;
                    if (bias) v += (double)bias[col];
                    C[o] = accum ? C[o] + v : v;
                }
            }
        }
    }
}

// ---------------------------------------------------------------------------
extern "C" void kernel_launch(void* const* d_in, const int* in_sizes, int n_in,
                              void* d_out, int out_size, void* d_ws, size_t ws_size,
                              hipStream_t stream)
{
    (void)in_sizes; (void)n_in; (void)out_size;
    auto in = [&](int i){ return (const float*)d_in[i]; };

    const float *X = in(0), *T = in(1), *Y = in(2), *XC = in(3), *REF = in(4);
    const float *xe_w = in(6), *xe_b = in(7), *pos = in(8);
    const float *te_w1 = in(9), *te_b1 = in(10), *te_w2 = in(11), *te_b2 = in(12);
    const float *pp_w = in(13), *pp_b = in(14);
    const float *sa_pe_w = in(15), *sa_pe_b = in(16);
    const float *sa_ln_g = in(17), *sa_ln_b = in(18);
    const float *sa_gate_w = in(19), *sa_down_w = in(20);
    const float *sa_dc_w = in(21), *sa_dc_b = in(22);
    const float *ada_w = in(23), *ada_b = in(24);
    const float *sa_wi = in(25), *sa_wf = in(26), *sa_wg = in(27), *sa_wo = in(28);
    const float *mv_wi = in(29), *mv_wf = in(30), *mv_wg = in(31), *mv_wo = in(32);
    const float *rf_wi = in(33), *rf_wf = in(34), *rf_wg = in(35), *rf_wo = in(36);
    const float *gate_w = in(37), *down_w = in(38);
    const float *fl_w = in(39), *fl_b = in(40), *fl_ada_w = in(41), *fl_ada_b = in(42);
    float* OUT = (float*)d_out;

    // ---------- workspace layout ----------
    size_t off = 0;
    auto AL = [&](size_t bytes){ off = (off+255)&~(size_t)255; size_t r = off; off += bytes; return r; };
    const size_t oScale = AL(37*8);
    const size_t oPart  = AL(37*32*8);
    const size_t oProbe = AL(64*4*8);
    const size_t oFlag  = AL(256);
    const size_t oSM1 = AL(8*1152*8), oSM2 = AL(8*1152*8), oSM3 = AL(8*1152*8);
    const size_t oCB  = AL(8*1152*8);
    const size_t oMOD = AL(8*6912*8);
    const size_t oH   = AL((size_t)8192*1152*8);    // 75.5 MB; reused as OB later
    const size_t oINT = AL((size_t)1024*4608*8);
    const size_t oF0  = AL((size_t)2048*1152*8);    // also ACC
    const size_t oXT  = AL((size_t)2048*1152*8);
    const size_t oFB  = AL((size_t)2048*1152*8);
    const size_t oIB  = AL((size_t)2048*1152*8);
    const size_t oGB  = AL((size_t)2048*1152*8);
    const size_t oRO  = AL((size_t)512*1152*8);
    const size_t oQ8X = AL((size_t)2048*1152);
    const size_t oQ8I = AL((size_t)1024*4608);
    const size_t oQ8O = AL((size_t)2048*1152);
    const size_t oQ8R = AL((size_t)512*1152);
    const size_t oQ8T = AL((size_t)8*1152);
    const size_t oQ8C = AL((size_t)8*1152);
    const size_t oDSX = AL(2048*8), oDSI = AL(1024*8), oDSO = AL(2048*8);
    const size_t oDSR = AL(512*8),  oDST = AL(8*8),    oDSC = AL(8*8);
    if (off > ws_size) return;

    // ---------- weight list + optional pre-ternarized region ----------
    WList wl{}; WOffs wo{};
    long long wn[37];
    int nw = 0;
    auto addw = [&](const float* w, long long n){ wl.p[nw]=w; wl.n[nw]=n; wn[nw]=n; nw++; };
    addw(te_w1, 294912); addw(te_w2, 1327104); addw(pp_w, 884736);
    addw(sa_gate_w, 10616832); addw(sa_down_w, 5308416);
    for (int l = 0; l < 2; ++l) {
        addw(ada_w + (size_t)l*7962624, 7962624);
        addw(sa_wi + (size_t)l*1327104, 1327104);
        addw(sa_wf + (size_t)l*1327104, 1327104);
        addw(sa_wg + (size_t)l*1327104, 1327104);
        addw(sa_wo + (size_t)l*1327104, 1327104);
        addw(mv_wi + (size_t)l*1327104, 1327104);
        addw(mv_wf + (size_t)l*1327104, 1327104);
        addw(mv_wg + (size_t)l*1327104, 1327104);
        addw(mv_wo + (size_t)l*1327104, 1327104);
        addw(rf_wi + (size_t)l*1327104, 1327104);
        addw(rf_wf + (size_t)l*1327104, 1327104);
        addw(rf_wg + (size_t)l*1327104, 1327104);
        addw(rf_wo + (size_t)l*1327104, 1327104);
        addw(gate_w + (size_t)l*10616832, 10616832);
        addw(down_w + (size_t)l*5308416, 5308416);
    }
    addw(fl_ada_w, 2654208); addw(fl_w, 36864);

    size_t off_saved = off;
    long long wtot = 0;
    for (int i = 0; i < 37; ++i) { wo.o[i] = wtot; wtot += (wn[i] + 255) & ~255LL; }
    const size_t oW8 = AL((size_t)wtot);
    const bool useW8 = (off <= ws_size);
    if (!useW8) off = off_saved;

    // ---------- tiered SA/MLP chunk enlargement (row-independent) ----------
    int schunk = 1024;
    size_t oINTb = 0, oQ8Ib = 0, oQ8Xb = 0, oDSXb = 0, oDSIb = 0;
    if (useW8) {
        size_t off_w8 = off;
        oINTb = AL((size_t)4096*4608*8); oQ8Ib = AL((size_t)4096*4608);
        oQ8Xb = AL((size_t)4096*1152);   oDSXb = AL(4096*8); oDSIb = AL(4096*8);
        if (off <= ws_size) schunk = 4096;
        else {
            off = off_w8;
            oINTb = AL((size_t)2048*4608*8); oQ8Ib = AL((size_t)2048*4608); oDSIb = AL(2048*8);
            if (off <= ws_size) schunk = 2048;
            else off = off_w8;
        }
    }

    char* w8p = (char*)d_ws;
    double* scales = (double*)(w8p + oScale);
    double* parts  = (double*)(w8p + oPart);
    double* probeD = (double*)(w8p + oProbe);
    int*    mflag  = (int*)(w8p + oFlag);
    double *SM1=(double*)(w8p+oSM1), *SM2=(double*)(w8p+oSM2), *SM3=(double*)(w8p+oSM3);
    double *CB=(double*)(w8p+oCB), *MOD=(double*)(w8p+oMOD);
    double *H=(double*)(w8p+oH), *INT=(double*)(w8p+oINT);
    double *F0=(double*)(w8p+oF0), *XT=(double*)(w8p+oXT);
    double *FB=(double*)(w8p+oFB), *IB=(double*)(w8p+oIB), *GB=(double*)(w8p+oGB);
    double *ACC=F0, *OB=H, *RO=(double*)(w8p+oRO);
    signed char *Q8X=(signed char*)(w8p+oQ8X), *Q8I=(signed char*)(w8p+oQ8I);
    signed char *Q8O=(signed char*)(w8p+oQ8O), *Q8R=(signed char*)(w8p+oQ8R);
    signed char *Q8T=(signed char*)(w8p+oQ8T), *Q8C=(signed char*)(w8p+oQ8C);
    double *DSX=(double*)(w8p+oDSX), *DSI=(double*)(w8p+oDSI), *DSO=(double*)(w8p+oDSO);
    double *DSR=(double*)(w8p+oDSR), *DST=(double*)(w8p+oDST), *DSC=(double*)(w8p+oDSC);
    signed char* W8 = (signed char*)(w8p + oW8);

    double*      INTs = (schunk > 1024) ? (double*)(w8p + oINTb) : INT;
    signed char* Q8Is = (schunk > 1024) ? (signed char*)(w8p + oQ8Ib) : Q8I;
    double*      DSIs = (schunk > 1024) ? (double*)(w8p + oDSIb) : DSI;
    signed char* Q8Xs = (schunk == 4096) ? (signed char*)(w8p + oQ8Xb) : Q8X;
    double*      DSXs = (schunk == 4096) ? (double*)(w8p + oDSXb) : DSX;

    // ---------- probe f64 MFMA layout + weight scales + ternarize ----------
    k_mfma64_probe<<<1, 64, 0, stream>>>(probeD);
    k_mfma64_check<<<1, 64, 0, stream>>>(probeD, mflag);
    k_abssum_all<<<dim3(32,37), 256, 0, stream>>>(wl, parts);
    k_abssum_fin<<<37, 64, 0, stream>>>(parts, scales);
    if (useW8)
        k_ternarize<<<dim3(64,37), 256, 0, stream>>>(wl, wo, scales, W8);

    // ---------- launch helpers ----------
    auto qgemm = [&](const signed char* A8, const double* as, const float* Win, int slot,
                     const float* b, double* Cout, int M, int N, int K, int accum){
        int gm = (M+127)/128, gn = (N+127)/128;
        if (useW8)
            k_qgemm<0,1><<<gm*gn, 256, 0, stream>>>(A8, as, Win, W8 + wo.o[slot],
                                                    scales+slot, wn[slot], b, Cout, M, N, K, accum, gm);
        else
            k_qgemm<0,0><<<gm*gn, 256, 0, stream>>>(A8, as, Win, nullptr,
                                                    scales+slot, wn[slot], b, Cout, M, N, K, accum, gm);
    };
    auto qgemmGate = [&](const signed char* A8, const double* as, const float* Win, int slot,
                         double* Cout, int M){
        int gm = (M+127)/128;
        if (useW8)
            k_qgemm<1,1><<<gm*36, 256, 0, stream>>>(A8, as, Win, W8 + wo.o[slot],
                                                    scales+slot, wn[slot], nullptr, Cout, M, 4608, 1152, 0, gm);
        else
            k_qgemm<1,0><<<gm*36, 256, 0, stream>>>(A8, as, Win, nullptr,
                                                    scales+slot, wn[slot], nullptr, Cout, M, 4608, 1152, 0, gm);
    };

    // ---------- conditioning vector c ----------
    k_temb<<<8, 128, 0, stream>>>(T, SM1);
    k_rsq8<double><<<8, 256, 0, stream>>>(SM1, Q8T, DST, 256, 0);
    qgemm(Q8T, DST, te_w1, 0, te_b1, SM3, 8, 1152, 256, 0);
    k_rsq8<double><<<8, 256, 0, stream>>>(SM3, Q8T, DST, 1152, 1);
    qgemm(Q8T, DST, te_w2, 1, te_b2, SM2, 8, 1152, 1152, 0);
    k_rsq8<float><<<8, 256, 0, stream>>>(Y, Q8T, DST, 768, 0);
    qgemm(Q8T, DST, pp_w, 2, pp_b, SM3, 8, 1152, 768, 0);
    k_add<<<36, 256, 0, stream>>>(SM2, SM3, CB, 9216);
    k_rsq8<double><<<8, 256, 0, stream>>>(CB, Q8C, DSC, 1152, 1);

    // ---------- spatial adapter: patch embed + block 0 only ----------
    k_dgemm<1,0><<<18*128, 256, 0, stream>>>(XC, sa_pe_w, sa_pe_b, H, 8192, 1152, 1536, 18, mflag);
    {
        const int nch = 8192 / schunk;
        for (int ch = 0; ch < nch; ++ch) {
            double* Hrow = H + (size_t)ch*schunk*1152;
            k_lnq8<<<schunk, 256, 1152*8, stream>>>(Hrow, Q8Xs, DSXs, 1152, sa_ln_g, sa_ln_b,
                                                    nullptr, nullptr, 0, 1e-5);
            qgemmGate(Q8Xs, DSXs, sa_gate_w, 3, INTs, schunk);
            k_rsq8<double><<<schunk, 256, 0, stream>>>(INTs, Q8Is, DSIs, 4608, 0);
            qgemm(Q8Is, DSIs, sa_down_w, 4, nullptr, Hrow, schunk, 1152, 4608, 0);
        }
    }
    k_dgemm<2,1><<<18*32, 256, 0, stream>>>(H, sa_dc_w, sa_dc_b, F0, 2048, 1152, 4608, 18, mflag);

    // ---------- patchify latents + pos + feats0 ----------
    k_patchify<<<9216, 256, 0, stream>>>(X, xe_w, xe_b, pos, F0, XT);
    k_rsq8<float><<<512, 256, 0, stream>>>(REF, Q8R, DSR, 1152, 0);

    // ---------- transformer blocks (OB aliases dead H) ----------
    for (int l = 0; l < 2; ++l) {
        int sb = 5 + l*15;
        const float *wada = ada_w + (size_t)l*7962624, *bada = ada_b + (size_t)l*6912;
        const float *swi = sa_wi + (size_t)l*1327104, *swf = sa_wf + (size_t)l*1327104;
        const float *swg = sa_wg + (size_t)l*1327104, *swo = sa_wo + (size_t)l*1327104;
        const float *mwi = mv_wi + (size_t)l*1327104, *mwf = mv_wf + (size_t)l*1327104;
        const float *mwg = mv_wg + (size_t)l*1327104, *mwo = mv_wo + (size_t)l*1327104;
        const float *rwi = rf_wi + (size_t)l*1327104, *rwf = rf_wf + (size_t)l*1327104;
        const float *rwg = rf_wg + (size_t)l*1327104, *rwo = rf_wo + (size_t)l*1327104;
        const float *wgt = gate_w + (size_t)l*10616832, *wdn = down_w + (size_t)l*5308416;

        qgemm(Q8C, DSC, wada, sb+0, bada, MOD, 8, 6912, 1152, 0);

        k_lnq8<<<2048, 256, 1152*8, stream>>>(XT, Q8X, DSX, 1152, nullptr, nullptr,
                                              MOD+0, MOD+1152, 6912, 1e-6);

        // self attention (seq = 256 tokens)
        qgemm(Q8X, DSX, swf, sb+2, nullptr, FB, 2048, 1152, 1152, 0);
        qgemm(Q8X, DSX, swi, sb+1, nullptr, IB, 2048, 1152, 1152, 0);
        qgemm(Q8X, DSX, swg, sb+3, nullptr, GB, 2048, 1152, 1152, 0);
        k_gatepre<<<9216, 256, 0, stream>>>(FB, IB, 2359296LL);
        k_scan2<<<36, 256, 0, stream>>>(FB, IB, OB, 8, 294912LL, 1152, 1152LL, 256);
        k_ogateq8<<<2048, 256, 1152*8, stream>>>(OB, GB, Q8O, DSO, 1152);
        qgemm(Q8O, DSO, swo, sb+4, nullptr, ACC, 2048, 1152, 1152, 0);

        // multi-view attention (seq = 4 views; token layout unchanged)
        qgemm(Q8X, DSX, mwf, sb+6, nullptr, FB, 2048, 1152, 1152, 0);
        qgemm(Q8X, DSX, mwi, sb+5, nullptr, IB, 2048, 1152, 1152, 0);
        qgemm(Q8X, DSX, mwg, sb+7, nullptr, GB, 2048, 1152, 1152, 0);
        k_gatepre<<<9216, 256, 0, stream>>>(FB, IB, 2359296LL);
        k_scan2<<<2304, 256, 0, stream>>>(FB, IB, OB, 2, 1179648LL, 294912, 294912LL, 4);
        k_ogateq8<<<2048, 256, 1152*8, stream>>>(OB, GB, Q8O, DSO, 1152);
        qgemm(Q8O, DSO, mwo, sb+8, nullptr, ACC, 2048, 1152, 1152, 1);   // +=

        // ref attention on 2 unique batches
        qgemm(Q8R, DSR, rwf, sb+10, nullptr, FB, 512, 1152, 1152, 0);
        qgemm(Q8R, DSR, rwi, sb+9,  nullptr, IB, 512, 1152, 1152, 0);
        qgemm(Q8R, DSR, rwg, sb+11, nullptr, GB, 512, 1152, 1152, 0);
        k_gatepre<<<2304, 256, 0, stream>>>(FB, IB, 589824LL);
        k_scan2<<<9, 256, 0, stream>>>(FB, IB, OB, 2, 294912LL, 1152, 1152LL, 256);
        k_ogateq8<<<512, 256, 1152*8, stream>>>(OB, GB, Q8O, DSO, 1152);
        qgemm(Q8O, DSO, rwo, sb+12, nullptr, RO, 512, 1152, 1152, 0);

        k_resid_attn<<<9216, 256, 0, stream>>>(XT, ACC, RO, MOD);

        // MLP
        k_lnq8<<<2048, 256, 1152*8, stream>>>(XT, Q8X, DSX, 1152, nullptr, nullptr,
                                              MOD+3*1152, MOD+4*1152, 6912, 1e-6);
        if (schunk >= 2048) {
            qgemmGate(Q8X, DSX, wgt, sb+13, INTs, 2048);
            k_rsq8<double><<<2048, 256, 0, stream>>>(INTs, Q8Is, DSIs, 4608, 0);
            qgemm(Q8Is, DSIs, wdn, sb+14, nullptr, OB, 2048, 1152, 4608, 0);
        } else {
            for (int ch = 0; ch < 2; ++ch) {
                qgemmGate(Q8X + (size_t)ch*1024*1152, DSX + ch*1024, wgt, sb+13, INT, 1024);
                k_rsq8<double><<<1024, 256, 0, stream>>>(INT, Q8I, DSI, 4608, 0);
                qgemm(Q8I, DSI, wdn, sb+14, nullptr, OB + (size_t)ch*1024*1152, 1024, 1152, 4608, 0);
            }
        }
        k_resid_mlp<<<9216, 256, 0, stream>>>(XT, OB, MOD);
    }

    // ---------- final layer + unpatchify ----------
    qgemm(Q8C, DSC, fl_ada_w, 35, fl_ada_b, MOD, 8, 2304, 1152, 0);
    k_lnq8<<<2048, 256, 1152*8, stream>>>(XT, Q8X, DSX, 1152, nullptr, nullptr,
                                          MOD+0, MOD+1152, 2304, 1e-6);
    qgemm(Q8X, DSX, fl_w, 36, fl_b, FB, 2048, 32, 1152, 0);
    k_unpatch<<<256, 256, 0, stream>>>(FB, OUT);
}

// Round 12
// 4849.022 us; speedup vs baseline: 1.3527x; 1.0648x over previous
//
#include <hip/hip_runtime.h>

#define DEV __device__ __forceinline__

typedef __attribute__((ext_vector_type(4))) int i32x4;
typedef __attribute__((ext_vector_type(4))) double f64x4;

// ---------------------------------------------------------------------------
// TernaryMVAdapter forward on MI355X. Round 12: round-11 pipeline (probed f64
// MFMA convs @60% util, 5163us) + dispatch-count/occupancy round:
//  * k_qgemm3: fused wf/wi/wg projection (3 GEMMs -> 1 dispatch, 3x blocks),
//    per-group epilogue = gatepre's exact f64 math (sigma / silu / raw)
//  * k_scan3: v = I_silu*(1-f) inline -> k_gatepre eliminated
//  * sa_dc_w pre-transposed to linear k' (coalesced W loads in down-conv)
// All transforms bitwise-identical; replay-safe (pure functions of inputs).
// ---------------------------------------------------------------------------

struct WList { const float* p[37]; long long n[37]; };
struct WOffs { long long o[37]; };
struct W3 { const signed char* w[3]; const double* sc[3]; double* c[3]; };

DEV int2 xcd_swz(int gridx)
{
    const int nwg = (int)gridDim.x, b = (int)blockIdx.x;
    const int q = nwg >> 3, r = nwg & 7, xcd = b & 7, idx = b >> 3;
    const int lb = (xcd < r ? xcd*(q+1) : r*(q+1) + (xcd-r)*q) + idx;
    return make_int2(lb % gridx, lb / gridx);
}

// ---------------- f64 MFMA layout probe (exact-integer classification) -----
__global__ void k_mfma64_probe(double* __restrict__ out)
{
    const int lane = threadIdx.x;                      // 64 threads
    double a = (double)(1 + lane);                     // injective per-lane
    double b = (double)(101 + 3*lane);
    f64x4 acc = {0.0, 0.0, 0.0, 0.0};
    acc = __builtin_amdgcn_mfma_f64_16x16x4f64(a, b, acc, 0, 0, 0);
#pragma unroll
    for (int r = 0; r < 4; ++r) out[lane*4 + r] = acc[r];
}

__global__ void k_mfma64_check(const double* __restrict__ probe, int* __restrict__ flag)
{
    if (threadIdx.x != 0) return;
    int best = 0;
    for (int c = 0; c < 16 && !best; ++c) {
        const int a_alt = c & 1, b_alt = (c >> 1) & 1, dv = (c >> 2) & 3;
        double Amat[16][4], Bmat[4][16];
        for (int l = 0; l < 64; ++l) {
            int ai = a_alt ? (l >> 2) : (l & 15);
            int ak = a_alt ? (l & 3)  : (l >> 4);
            Amat[ai][ak] = (double)(1 + l);
            int bj = b_alt ? (l >> 2) : (l & 15);
            int bk = b_alt ? (l & 3)  : (l >> 4);
            Bmat[bk][bj] = (double)(101 + 3*l);
        }
        double C[16][16];
        for (int i = 0; i < 16; ++i)
            for (int j = 0; j < 16; ++j) {
                double s = 0.0;
                for (int k = 0; k < 4; ++k) s += Amat[i][k] * Bmat[k][j];
                C[i][j] = s;
            }
        bool ok = true;
        for (int l = 0; l < 64 && ok; ++l)
            for (int r = 0; r < 4 && ok; ++r) {
                int ir = (dv & 2) ? (4*r + (l >> 4)) : (4*(l >> 4) + r);
                int ic = l & 15;
                if (dv & 1) { int t = ir; ir = ic; ic = t; }
                if (probe[l*4 + r] != C[ir][ic]) ok = false;
            }
        if (ok) best = 1 + c;
    }
    *flag = best;
}

// ---------------- fused deterministic |w| sums (37 slots) ------------------
__global__ void k_abssum_all(WList wl, double* __restrict__ partials)
{
    const int slot = blockIdx.y;
    const float* w = wl.p[slot];
    const long long n = wl.n[slot];
    __shared__ double sm[256];
    double s = 0.0;
    for (long long i = (long long)blockIdx.x*256 + threadIdx.x; i < n; i += 32LL*256)
        s += (double)fabsf(w[i]);
    sm[threadIdx.x] = s;
    __syncthreads();
    for (int k = 128; k > 0; k >>= 1) {
        if ((int)threadIdx.x < k) sm[threadIdx.x] += sm[threadIdx.x + k];
        __syncthreads();
    }
    if (threadIdx.x == 0) partials[slot*32 + blockIdx.x] = sm[0];
}

__global__ void k_abssum_fin(const double* __restrict__ partials, double* __restrict__ out)
{
    const int slot = blockIdx.x;
    if (threadIdx.x == 0) {
        double s = 0.0;
        for (int i = 0; i < 32; ++i) s += partials[slot*32 + i];
        out[slot] = s;
    }
}

// ---------------- one-time weight ternarization (f64-exact decision) -------
__global__ void k_ternarize(WList wl, WOffs wo, const double* __restrict__ scales,
                            signed char* __restrict__ W8)
{
    const int slot = blockIdx.y;
    const float* w = wl.p[slot];
    const long long n4 = wl.n[slot] >> 2;
    const double dqw = fmax(scales[slot] / (double)wl.n[slot], 1e-5);
    const double thr = 0.5 * dqw;
    signed char* o = W8 + wo.o[slot];
    for (long long i = (long long)blockIdx.x*256 + threadIdx.x; i < n4; i += 64LL*256) {
        float4 v = *reinterpret_cast<const float4*>(w + i*4);
        float we[4] = {v.x, v.y, v.z, v.w};
        char r[4];
#pragma unroll
        for (int e = 0; e < 4; ++e) {
            double wd = (double)we[e];
            r[e] = (char)((wd > thr) - (wd < -thr));
        }
        *reinterpret_cast<char4*>(o + i*4) = make_char4(r[0], r[1], r[2], r[3]);
    }
}

// ---------------- sa_dc_w pre-transpose to linear k' -----------------------
__global__ void k_dcw_prep(const float* __restrict__ w, float* __restrict__ wt)
{
    int row = blockIdx.x;                              // 1152
    for (int k = threadIdx.x; k < 4608; k += 256) {
        int q = k / 1152, c = k - q*1152;
        wt[(size_t)row*4608 + k] = w[(size_t)row*4608 + (size_t)c*4 + q];
    }
}

// ---------------- timestep frequency embedding (f64) -----------------------
__global__ void k_temb(const float* __restrict__ t, double* __restrict__ out)
{
    int b = blockIdx.x, j = threadIdx.x;               // 8 x 128
    double fr  = exp(-9.210340371976184 * (double)j / 128.0);
    double ang = (double)t[b] * fr;
    out[b*256 + j]       = cos(ang);
    out[b*256 + 128 + j] = sin(ang);
}

// ---------------- rmsnorm + int8 absmax quant (f64, LDS-free) --------------
template<typename TI>
__global__ void k_rsq8(const TI* __restrict__ x, signed char* __restrict__ q8,
                       double* __restrict__ dscale, int K, int pre_silu)
{
    __shared__ double red[256], red2[256];
    const int row = blockIdx.x, tid = threadIdx.x;
    const TI* xr = x + (size_t)row*K;
    double ss = 0.0, am = 0.0;
    for (int i = tid; i < K; i += 256) {
        double v = (double)xr[i];
        if (pre_silu) v = v / (1.0 + exp(-v));
        ss += v*v; am = fmax(am, fabs(v));
    }
    red[tid] = ss; red2[tid] = am;
    __syncthreads();
    for (int s = 128; s > 0; s >>= 1) {
        if (tid < s) { red[tid] += red[tid+s]; red2[tid] = fmax(red2[tid], red2[tid+s]); }
        __syncthreads();
    }
    double rms = 1.0 / sqrt(red[0]/(double)K + 1e-8);
    double s   = 127.0 / fmax(red2[0]*rms, 1e-5);
    signed char* orow = q8 + (size_t)row*K;
    for (int i = tid; i < K; i += 256) {
        double v = (double)xr[i];
        if (pre_silu) v = v / (1.0 + exp(-v));
        orow[i] = (signed char)(int)fmin(fmax(rint(v*rms*s), -128.0), 127.0);
    }
    if (tid == 0) dscale[row] = s;
}

// ---------------- layernorm(+gb/+mod) + rmsnorm + int8 quant (f64) ---------
__global__ void k_lnq8(const double* __restrict__ x, signed char* __restrict__ q8,
                       double* __restrict__ dscale, int K,
                       const float* __restrict__ gamma, const float* __restrict__ beta,
                       const double* __restrict__ sh, const double* __restrict__ sc,
                       int modstride, double eps)
{
    extern __shared__ double rb[];
    __shared__ double red[256], red2[256];
    const int row = blockIdx.x, tid = threadIdx.x;
    const double* xr = x + (size_t)row*K;
    double s1 = 0.0;
    for (int i = tid; i < K; i += 256) { double v = xr[i]; rb[i] = v; s1 += v; }
    red[tid] = s1; __syncthreads();
    for (int s = 128; s > 0; s >>= 1) { if (tid < s) red[tid] += red[tid+s]; __syncthreads(); }
    double mu = red[0]/(double)K;
    __syncthreads();
    double s2 = 0.0;
    for (int i = tid; i < K; i += 256) { double d = rb[i]-mu; s2 += d*d; }
    red[tid] = s2; __syncthreads();
    for (int s = 128; s > 0; s >>= 1) { if (tid < s) red[tid] += red[tid+s]; __syncthreads(); }
    double r = 1.0 / sqrt(red[0]/(double)K + eps);
    const int bn = row >> 8;
    __syncthreads();
    double ss = 0.0, am = 0.0;
    for (int i = tid; i < K; i += 256) {
        double y = (rb[i]-mu)*r;
        if (gamma) y = y*(double)gamma[i] + (double)beta[i];
        if (sh)    y = y*(1.0 + sc[(size_t)bn*modstride + i]) + sh[(size_t)bn*modstride + i];
        rb[i] = y; ss += y*y; am = fmax(am, fabs(y));
    }
    red[tid] = ss; red2[tid] = am;
    __syncthreads();
    for (int s = 128; s > 0; s >>= 1) {
        if (tid < s) { red[tid] += red[tid+s]; red2[tid] = fmax(red2[tid], red2[tid+s]); }
        __syncthreads();
    }
    double rms = 1.0 / sqrt(red[0]/(double)K + 1e-8);
    double s   = 127.0 / fmax(red2[0]*rms, 1e-5);
    signed char* orow = q8 + (size_t)row*K;
    for (int i = tid; i < K; i += 256)
        orow[i] = (signed char)(int)fmin(fmax(rint(rb[i]*rms*s), -128.0), 127.0);
    if (tid == 0) dscale[row] = s;
}

// ---------------- ogate (rmsnorm*g*sig(g)) + rmsnorm + quant (f64) ---------
__global__ void k_ogateq8(const double* __restrict__ O, const double* __restrict__ G,
                          signed char* __restrict__ q8, double* __restrict__ dscale, int K)
{
    extern __shared__ double rb[];
    __shared__ double red[256], red2[256];
    const int row = blockIdx.x, tid = threadIdx.x;
    const double* orow = O + (size_t)row*K;
    const double* grow = G + (size_t)row*K;
    double ss = 0.0;
    for (int i = tid; i < K; i += 256) { double v = orow[i]; rb[i] = v; ss += v*v; }
    red[tid] = ss; __syncthreads();
    for (int s = 128; s > 0; s >>= 1) { if (tid < s) red[tid] += red[tid+s]; __syncthreads(); }
    double rmso = 1.0 / sqrt(red[0]/(double)K + 1e-8);
    __syncthreads();
    double ss2 = 0.0, am = 0.0;
    for (int i = tid; i < K; i += 256) {
        double g = grow[i];
        double y = rb[i]*rmso * g / (1.0 + exp(-g));
        rb[i] = y; ss2 += y*y; am = fmax(am, fabs(y));
    }
    red[tid] = ss2; red2[tid] = am;
    __syncthreads();
    for (int s = 128; s > 0; s >>= 1) {
        if (tid < s) { red[tid] += red[tid+s]; red2[tid] = fmax(red2[tid], red2[tid+s]); }
        __syncthreads();
    }
    double rms = 1.0 / sqrt(red[0]/(double)K + 1e-8);
    double s   = 127.0 / fmax(red2[0]*rms, 1e-5);
    signed char* qrow = q8 + (size_t)row*K;
    for (int i = tid; i < K; i += 256)
        qrow[i] = (signed char)(int)fmin(fmax(rint(rb[i]*rms*s), -128.0), 127.0);
    if (tid == 0) dscale[row] = s;
}

// ---------------- HGRN scans -----------------------------------------------
// fallback pair (non-useW8 path): gatepre + scan2
__global__ void k_gatepre(double* __restrict__ F, double* __restrict__ I, long long n)
{
    long long i = (long long)blockIdx.x*256 + threadIdx.x;
    if (i >= n) return;
    double fp = F[i], ip = I[i];
    double f = 1.0/(1.0+exp(-fp));
    double v = (ip/(1.0+exp(-ip)))*(1.0-f);
    F[i] = f; I[i] = v;
}

__global__ void k_scan2(const double* __restrict__ F, const double* __restrict__ V,
                        double* __restrict__ O, int n_outer, long long outer_stride,
                        int n_inner, long long t_stride, int T)
{
    long long chain = (long long)blockIdx.x*blockDim.x + threadIdx.x;
    if (chain >= (long long)n_outer*n_inner) return;
    long long base = (chain / n_inner)*outer_stride + (chain % n_inner);
    double h = 0.0;
    for (int t = 0; t < T; ++t) {
        long long idx = base + (long long)t*t_stride;
        h = F[idx]*h + V[idx];
        O[idx] = h;
    }
}

// main path: F = sigma(raw), Isilu = silu(raw) (from k_qgemm3 epilogue);
// v = Isilu*(1-f) computed inline — same f64 ops/order as gatepre+scan2.
__global__ void k_scan3(const double* __restrict__ F, const double* __restrict__ Isilu,
                        double* __restrict__ O, int n_outer, long long outer_stride,
                        int n_inner, long long t_stride, int T)
{
    long long chain = (long long)blockIdx.x*blockDim.x + threadIdx.x;
    if (chain >= (long long)n_outer*n_inner) return;
    long long base = (chain / n_inner)*outer_stride + (chain % n_inner);
    double h = 0.0;
    for (int t = 0; t < T; ++t) {
        long long idx = base + (long long)t*t_stride;
        double f = F[idx];
        double v = Isilu[idx]*(1.0-f);
        h = f*h + v;
        O[idx] = h;
    }
}

// ---------------- misc elementwise (f64) -----------------------------------
__global__ void k_add(const double* __restrict__ a, const double* __restrict__ b,
                      double* __restrict__ o, int n)
{
    int i = blockIdx.x*256 + threadIdx.x;
    if (i < n) o[i] = a[i] + b[i];
}

__global__ void k_resid_attn(double* __restrict__ xt, const double* __restrict__ acc,
                             const double* __restrict__ refo, const double* __restrict__ mod)
{
    int idx = blockIdx.x*256 + threadIdx.x;            // 2048*1152 exact
    int r = idx / 1152, d = idx - r*1152;
    int bn = r >> 8, l = r & 255;
    double ga = mod[(size_t)bn*6912 + 2*1152 + d];
    double rv = refo[((size_t)((bn>>2)*256 + l))*1152 + d];
    xt[idx] += ga*(acc[idx] + rv);
}

__global__ void k_resid_mlp(double* __restrict__ xt, const double* __restrict__ t2,
                            const double* __restrict__ mod)
{
    int idx = blockIdx.x*256 + threadIdx.x;
    int r = idx / 1152, d = idx - r*1152;
    int bn = r >> 8;
    xt[idx] += mod[(size_t)bn*6912 + 5*1152 + d] * t2[idx];
}

__global__ void k_patchify(const float* __restrict__ x, const float* __restrict__ w,
                           const float* __restrict__ bias, const float* __restrict__ pos,
                           const double* __restrict__ f0, double* __restrict__ xt)
{
    int idx = blockIdx.x*256 + threadIdx.x;            // 2048*1152 exact
    int r = idx / 1152, o = idx - r*1152;
    int bn = r >> 8, p = r & 255;
    int y = p >> 4, xx = p & 15;
    double acc = (double)bias[o] + (double)pos[(size_t)p*1152 + o] + f0[idx];
#pragma unroll
    for (int c = 0; c < 4; ++c)
#pragma unroll
        for (int ky = 0; ky < 2; ++ky)
#pragma unroll
            for (int kx = 0; kx < 2; ++kx)
                acc += (double)x[((size_t)(bn*4 + c)*32 + 2*y+ky)*32 + 2*xx+kx]
                     * (double)w[o*16 + c*4 + ky*2 + kx];
    xt[idx] = acc;
}

__global__ void k_unpatch(const double* __restrict__ flo, float* __restrict__ out)
{
    int idx = blockIdx.x*256 + threadIdx.x;            // 65536 exact
    int xx = idx & 31, y = (idx>>5)&31, ch = (idx>>10)&7, b = idx>>13;
    int hp = y>>1, py = y&1, wp = xx>>1, px = xx&1;
    out[idx] = (float)flo[((size_t)(b*256 + hp*16 + wp))*32 + (py*2+px)*8 + ch];
}

// ---------------- f64 GEMM: probed MFMA path + proven SIMT fallback --------
template<int AMODE>
DEV void load_a4d(const void* __restrict__ A, int row, int k, int M, double o[4])
{
    if (row >= M) { o[0]=o[1]=o[2]=o[3]=0.0; return; }
    if constexpr (AMODE == 1) {
        const float* Af = (const float*)A;
        int b = row>>10, p = row&1023, oy = p>>5, ox = p&31;
        int c = k>>8, ky = (k>>4)&15, kx = k&15;
        float4 v = *reinterpret_cast<const float4*>(
            Af + (((size_t)(b*6+c)*512 + (size_t)(oy*16+ky))*512 + (size_t)(ox*16+kx)));
        o[0]=v.x; o[1]=v.y; o[2]=v.z; o[3]=v.w;
    } else {
        const double* Ad = (const double*)A;
        int b = row>>8, y = (row>>4)&15, x = row&15;
        int q = k/1152, c = k - q*1152, ky = q>>1, kx = q&1;
        const double* p = Ad + (size_t)(b*1024 + (2*y+ky)*32 + 2*x+kx)*1152 + c;
        o[0]=p[0]; o[1]=p[1]; o[2]=p[2]; o[3]=p[3];
    }
}

template<int WMODE>
DEV void load_w4d(const float* __restrict__ W, int row, int k, int Nb, int K, double o[4])
{
    if (row >= Nb) { o[0]=o[1]=o[2]=o[3]=0.0; return; }
    if constexpr (WMODE == 0) {
        float4 v = *reinterpret_cast<const float4*>(W + (size_t)row*K + k);
        o[0]=v.x; o[1]=v.y; o[2]=v.z; o[3]=v.w;
    } else {
        int q = k/1152, c = k - q*1152;
        const float* p = W + (size_t)row*4608 + (size_t)c*4 + q;
        o[0]=p[0]; o[1]=p[4]; o[2]=p[8]; o[3]=p[12];
    }
}

template<int AMODE, int WMODE>
__global__ __launch_bounds__(256)
void k_dgemm(const void* __restrict__ A, const float* __restrict__ W,
             const float* __restrict__ bias, double* __restrict__ C,
             int M, int N, int K, int gridx, const int* __restrict__ mfma_flag)
{
    __shared__ double As[64][17];                  // [m][k], +1 pad
    __shared__ double Ws[64][17];                  // [n][k]
    const int tid = threadIdx.x;
    const int2 bxy = xcd_swz(gridx);
    const int m0 = bxy.y*64, n0 = bxy.x*64;
    const int lr = tid >> 2;                       // staging row 0..63
    const int lc = (tid & 3) * 4;                  // staging k {0,4,8,12}
    const int flag = *mfma_flag;                   // uniform

    if (flag) {
        const int cmb = flag - 1;
        const int a_alt = cmb & 1, b_alt = (cmb >> 1) & 1, dv = (cmb >> 2) & 3;
        const int lane = tid & 63, wid = tid >> 6;
        const int wm = wid >> 1, wn = wid & 1;     // 2x2 waves of 32x32
        const int ai = a_alt ? (lane >> 2) : (lane & 15);
        const int ak = a_alt ? (lane & 3)  : (lane >> 4);
        const int bj = b_alt ? (lane >> 2) : (lane & 15);
        const int bk = b_alt ? (lane & 3)  : (lane >> 4);
        f64x4 fa[2][2];
#pragma unroll
        for (int i = 0; i < 2; ++i)
#pragma unroll
            for (int j = 0; j < 2; ++j) fa[i][j] = f64x4{0.0,0.0,0.0,0.0};

        for (int kt = 0; kt < K; kt += 16) {
            {
                double v[4];
                load_a4d<AMODE>(A, m0+lr, kt+lc, M, v);
                As[lr][lc+0]=v[0]; As[lr][lc+1]=v[1]; As[lr][lc+2]=v[2]; As[lr][lc+3]=v[3];
            }
            {
                double wv[4];
                load_w4d<WMODE>(W, n0+lr, kt+lc, N, K, wv);
                Ws[lr][lc+0]=wv[0]; Ws[lr][lc+1]=wv[1]; Ws[lr][lc+2]=wv[2]; Ws[lr][lc+3]=wv[3];
            }
            __syncthreads();
#pragma unroll
            for (int k4 = 0; k4 < 4; ++k4) {
                double a0 = As[wm*32 + ai][k4*4 + ak];
                double a1 = As[wm*32 + 16 + ai][k4*4 + ak];
                double b0 = Ws[wn*32 + bj][k4*4 + bk];
                double b1 = Ws[wn*32 + 16 + bj][k4*4 + bk];
                fa[0][0] = __builtin_amdgcn_mfma_f64_16x16x4f64(a0, b0, fa[0][0], 0, 0, 0);
                fa[0][1] = __builtin_amdgcn_mfma_f64_16x16x4f64(a0, b1, fa[0][1], 0, 0, 0);
                fa[1][0] = __builtin_amdgcn_mfma_f64_16x16x4f64(a1, b0, fa[1][0], 0, 0, 0);
                fa[1][1] = __builtin_amdgcn_mfma_f64_16x16x4f64(a1, b1, fa[1][1], 0, 0, 0);
            }
            __syncthreads();
        }
#pragma unroll
        for (int i = 0; i < 2; ++i)
#pragma unroll
            for (int j = 0; j < 2; ++j)
#pragma unroll
                for (int r = 0; r < 4; ++r) {
                    int ir = (dv & 2) ? (4*r + (lane >> 4)) : (4*(lane >> 4) + r);
                    int ic = lane & 15;
                    if (dv & 1) { int t = ir; ir = ic; ic = t; }
                    int row = m0 + wm*32 + i*16 + ir;
                    int col = n0 + wn*32 + j*16 + ic;
                    if (row < M && col < N)
                        C[(size_t)row*N + col] = fa[i][j][r] + (bias ? (double)bias[col] : 0.0);
                }
        return;
    }

    // ---- SIMT fallback (proven rounds 3-11) ----
    const int tx = tid & 15, ty = tid >> 4;
    double acc[4][4] = {};
    for (int kt = 0; kt < K; kt += 16) {
        {
            double v[4];
            load_a4d<AMODE>(A, m0+lr, kt+lc, M, v);
            As[lr][lc+0]=v[0]; As[lr][lc+1]=v[1]; As[lr][lc+2]=v[2]; As[lr][lc+3]=v[3];
        }
        {
            double wv[4];
            load_w4d<WMODE>(W, n0+lr, kt+lc, N, K, wv);
            Ws[lr][lc+0]=wv[0]; Ws[lr][lc+1]=wv[1]; Ws[lr][lc+2]=wv[2]; Ws[lr][lc+3]=wv[3];
        }
        __syncthreads();
#pragma unroll
        for (int k = 0; k < 16; ++k) {
            double a[4], b[4];
#pragma unroll
            for (int e = 0; e < 4; ++e) { a[e] = As[ty + 16*e][k]; b[e] = Ws[tx + 16*e][k]; }
#pragma unroll
            for (int i = 0; i < 4; ++i)
#pragma unroll
                for (int j = 0; j < 4; ++j) acc[i][j] += a[i]*b[j];
        }
        __syncthreads();
    }
#pragma unroll
    for (int i = 0; i < 4; ++i) {
        int row = m0 + ty + 16*i;
        if (row >= M) continue;
#pragma unroll
        for (int j = 0; j < 4; ++j) {
            int col = n0 + tx + 16*j;
            if (col >= N) continue;
            C[(size_t)row*N + col] = acc[i][j] + (bias ? (double)bias[col] : 0.0);
        }
    }
}

// ---------------- int8 MFMA GEMM (exact), 256 thr + XCD swizzle ------------
template<int GATE, int PRE>
__global__ __launch_bounds__(256)
void k_qgemm(const signed char* __restrict__ A8, const double* __restrict__ ascale,
             const float* __restrict__ Wf, const signed char* __restrict__ W8,
             const double* __restrict__ wsum, long long wcount,
             const float* __restrict__ bias, double* __restrict__ C,
             int M, int N, int K, int accum, int gridM)
{
    __shared__ __align__(16) signed char Als[4][128][16];
    __shared__ __align__(16) signed char Bls[4][128][16];
    __shared__ __align__(16) signed char B2ls[GATE?4:1][GATE?128:1][16];
    const int tid = threadIdx.x;
    const int lane = tid & 63, wid = tid >> 6;
    const int wr = wid >> 1, wc = wid & 1;             // 2x2 waves, 64x64 each
    const int2 bxy = xcd_swz(gridM);
    const int m0 = bxy.x*128, n0 = bxy.y*128;
    const int ks = lane >> 4, fr = lane & 15;

    const double dqw = fmax(*wsum / (double)wcount, 1e-5);
    const double thr = 0.5 * dqw;

    i32x4 acc[4][4];
    i32x4 acc2[GATE?4:1][4];
#pragma unroll
    for (int i = 0; i < 4; ++i)
#pragma unroll
        for (int j = 0; j < 4; ++j) {
            acc[i][j] = i32x4{0,0,0,0};
            if constexpr (GATE) acc2[i][j] = i32x4{0,0,0,0};
        }

    for (int kt = 0; kt < K; kt += 64) {
#pragma unroll
        for (int c = 0; c < 2; ++c) {
            int idx = tid + c*256;
            int row = idx & 127, kslot = idx >> 7;
            i32x4 v = {0,0,0,0};
            if (m0 + row < M)
                v = *reinterpret_cast<const i32x4*>(A8 + (size_t)(m0+row)*K + kt + kslot*16);
            *reinterpret_cast<i32x4*>(&Als[kslot][row][0]) = v;
        }
#pragma unroll
        for (int c = 0; c < 2; ++c) {
            int idx = tid + c*256;
            int row = idx & 127, kslot = idx >> 7;
            i32x4 pv = {0,0,0,0};
            if (n0 + row < N) {
                if constexpr (PRE) {
                    pv = *reinterpret_cast<const i32x4*>(W8 + (size_t)(n0+row)*K + kt + kslot*16);
                } else {
                    const float* wp = Wf + (size_t)(n0+row)*K + kt + kslot*16;
#pragma unroll
                    for (int d = 0; d < 4; ++d) {
                        float4 wv = *reinterpret_cast<const float4*>(wp + d*4);
                        float we[4] = {wv.x, wv.y, wv.z, wv.w};
                        unsigned p = 0;
#pragma unroll
                        for (int e = 0; e < 4; ++e) {
                            double wd = (double)we[e];
                            int q = (wd > thr) - (wd < -thr);
                            p |= ((unsigned)(q & 255)) << (8*e);
                        }
                        pv[d] = (int)p;
                    }
                }
            }
            *reinterpret_cast<i32x4*>(&Bls[kslot][row][0]) = pv;
        }
        if constexpr (GATE) {
#pragma unroll
            for (int c = 0; c < 2; ++c) {
                int idx = tid + c*256;
                int row = idx & 127, kslot = idx >> 7;
                i32x4 pv = {0,0,0,0};
                if (n0 + row < N) {
                    if constexpr (PRE) {
                        pv = *reinterpret_cast<const i32x4*>(W8 + (size_t)(n0+row+N)*K + kt + kslot*16);
                    } else {
                        const float* wp = Wf + (size_t)(n0+row+N)*K + kt + kslot*16;
#pragma unroll
                        for (int d = 0; d < 4; ++d) {
                            float4 wv = *reinterpret_cast<const float4*>(wp + d*4);
                            float we[4] = {wv.x, wv.y, wv.z, wv.w};
                            unsigned p = 0;
#pragma unroll
                            for (int e = 0; e < 4; ++e) {
                                double wd = (double)we[e];
                                int q = (wd > thr) - (wd < -thr);
                                p |= ((unsigned)(q & 255)) << (8*e);
                            }
                            pv[d] = (int)p;
                        }
                    }
                }
                *reinterpret_cast<i32x4*>(&B2ls[kslot][row][0]) = pv;
            }
        }
        __syncthreads();
        i32x4 a[4];
#pragma unroll
        for (int i = 0; i < 4; ++i)
            a[i] = *reinterpret_cast<const i32x4*>(&Als[ks][wr*64 + i*16 + fr][0]);
#pragma unroll
        for (int j = 0; j < 4; ++j) {
            i32x4 b = *reinterpret_cast<const i32x4*>(&Bls[ks][wc*64 + j*16 + fr][0]);
#pragma unroll
            for (int i = 0; i < 4; ++i)
                acc[i][j] = __builtin_amdgcn_mfma_i32_16x16x64_i8(a[i], b, acc[i][j], 0, 0, 0);
            if constexpr (GATE) {
                i32x4 b2 = *reinterpret_cast<const i32x4*>(&B2ls[ks][wc*64 + j*16 + fr][0]);
#pragma unroll
                for (int i = 0; i < 4; ++i)
                    acc2[i][j] = __builtin_amdgcn_mfma_i32_16x16x64_i8(a[i], b2, acc2[i][j], 0, 0, 0);
            }
        }
        __syncthreads();
    }

#pragma unroll
    for (int i = 0; i < 4; ++i) {
#pragma unroll
        for (int r = 0; r < 4; ++r) {
            int row = m0 + wr*64 + i*16 + (lane>>4)*4 + r;
            if (row >= M) continue;
            double mul = dqw / ascale[row];
#pragma unroll
            for (int j = 0; j < 4; ++j) {
                int col = n0 + wc*64 + j*16 + (lane & 15);
                if (col >= N) continue;
                size_t o = (size_t)row*N + col;
                if constexpr (GATE) {
                    double g = (double)acc[i][j][r] * mul;
                    double y = (double)acc2[i][j][r] * mul;
                    C[o] = g/(1.0+exp(-g)) * y;
                } else {
                    double v = (double)acc[i][j][r] * mul;
                    if (bias) v += (double)bias[col];
                    C[o] = accum ? C[o] + v : v;
                }
            }
        }
    }
}

// ---------------- fused wf/wi/wg GEMM (N=K=1152), per-group epilogue -------
// grid = gridM*27 blocks; yy=tile/gridM in [0,27): group g=yy/9 (0=f,1=i,2=g),
// n-tile = yy%9. Epilogue: g==0 -> sigma(v) (gatepre's f), g==1 -> silu(v),
// g==2 -> raw. Same f64 expressions/order as gatepre on identical values.
__global__ __launch_bounds__(256)
void k_qgemm3(const signed char* __restrict__ A8, const double* __restrict__ ascale,
              W3 w3, long long wcount, int M, int gridM)
{
    __shared__ __align__(16) signed char Als[4][128][16];
    __shared__ __align__(16) signed char Bls[4][128][16];
    const int tid = threadIdx.x;
    const int lane = tid & 63, wid = tid >> 6;
    const int wr = wid >> 1, wc = wid & 1;
    const int2 bxy = xcd_swz(gridM);
    const int m0 = bxy.x*128;
    const int yy = bxy.y;
    const int g = yy / 9, nt = yy - g*9;
    const int n0 = nt*128;
    const signed char* W8 = w3.w[g];
    double* C = w3.c[g];
    const int ks = lane >> 4, fr = lane & 15;

    const double dqw = fmax(*w3.sc[g] / (double)wcount, 1e-5);

    i32x4 acc[4][4];
#pragma unroll
    for (int i = 0; i < 4; ++i)
#pragma unroll
        for (int j = 0; j < 4; ++j) acc[i][j] = i32x4{0,0,0,0};

    for (int kt = 0; kt < 1152; kt += 64) {
#pragma unroll
        for (int c = 0; c < 2; ++c) {
            int idx = tid + c*256;
            int row = idx & 127, kslot = idx >> 7;
            i32x4 v = {0,0,0,0};
            if (m0 + row < M)
                v = *reinterpret_cast<const i32x4*>(A8 + (size_t)(m0+row)*1152 + kt + kslot*16);
            *reinterpret_cast<i32x4*>(&Als[kslot][row][0]) = v;
        }
#pragma unroll
        for (int c = 0; c < 2; ++c) {
            int idx = tid + c*256;
            int row = idx & 127, kslot = idx >> 7;
            i32x4 pv = *reinterpret_cast<const i32x4*>(W8 + (size_t)(n0+row)*1152 + kt + kslot*16);
            *reinterpret_cast<i32x4*>(&Bls[kslot][row][0]) = pv;
        }
        __syncthreads();
        i32x4 a[4];
#pragma unroll
        for (int i = 0; i < 4; ++i)
            a[i] = *reinterpret_cast<const i32x4*>(&Als[ks][wr*64 + i*16 + fr][0]);
#pragma unroll
        for (int j = 0; j < 4; ++j) {
            i32x4 b = *reinterpret_cast<const i32x4*>(&Bls[ks][wc*64 + j*16 + fr][0]);
#pragma unroll
            for (int i = 0; i < 4; ++i)
                acc[i][j] = __builtin_amdgcn_mfma_i32_16x16x64_i8(a[i], b, acc[i][j], 0, 0, 0);
        }
        __syncthreads();
    }

#pragma unroll
    for (int i = 0; i < 4; ++i) {
#pragma unroll
        for (int r = 0; r < 4; ++r) {
            int row = m0 + wr*64 + i*16 + (lane>>4)*4 + r;
            if (row >= M) continue;
            double mul = dqw / ascale[row];
#pragma unroll
            for (int j = 0; j < 4; ++j) {
                int col = n0 + wc*64 + j*16 + (lane & 15);
                double v = (double)acc[i][j][r] * mul;
                if (g == 0)      v = 1.0/(1.0+exp(-v));          // sigma(F)
                else if (g == 1) v = v/(1.0+exp(-v));            // silu(I)
                C[(size_t)row*1152 + col] = v;
            }
        }
    }
}

// ---------------------------------------------------------------------------
extern "C" void kernel_launch(void* const* d_in, const int* in_sizes, int n_in,
                              void* d_out, int out_size, void* d_ws, size_t ws_size,
                              hipStream_t stream)
{
    (void)in_sizes; (void)n_in; (void)out_size;
    auto in = [&](int i){ return (const float*)d_in[i]; };

    const float *X = in(0), *T = in(1), *Y = in(2), *XC = in(3), *REF = in(4);
    const float *xe_w = in(6), *xe_b = in(7), *pos = in(8);
    const float *te_w1 = in(9), *te_b1 = in(10), *te_w2 = in(11), *te_b2 = in(12);
    const float *pp_w = in(13), *pp_b = in(14);
    const float *sa_pe_w = in(15), *sa_pe_b = in(16);
    const float *sa_ln_g = in(17), *sa_ln_b = in(18);
    const float *sa_gate_w = in(19), *sa_down_w = in(20);
    const float *sa_dc_w = in(21), *sa_dc_b = in(22);
    const float *ada_w = in(23), *ada_b = in(24);
    const float *sa_wi = in(25), *sa_wf = in(26), *sa_wg = in(27), *sa_wo = in(28);
    const float *mv_wi = in(29), *mv_wf = in(30), *mv_wg = in(31), *mv_wo = in(32);
    const float *rf_wi = in(33), *rf_wf = in(34), *rf_wg = in(35), *rf_wo = in(36);
    const float *gate_w = in(37), *down_w = in(38);
    const float *fl_w = in(39), *fl_b = in(40), *fl_ada_w = in(41), *fl_ada_b = in(42);
    float* OUT = (float*)d_out;

    // ---------- workspace layout ----------
    size_t off = 0;
    auto AL = [&](size_t bytes){ off = (off+255)&~(size_t)255; size_t r = off; off += bytes; return r; };
    const size_t oScale = AL(37*8);
    const size_t oPart  = AL(37*32*8);
    const size_t oProbe = AL(64*4*8);
    const size_t oFlag  = AL(256);
    const size_t oSM1 = AL(8*1152*8), oSM2 = AL(8*1152*8), oSM3 = AL(8*1152*8);
    const size_t oCB  = AL(8*1152*8);
    const size_t oMOD = AL(8*6912*8);
    const size_t oH   = AL((size_t)8192*1152*8);    // 75.5 MB; reused as OB later
    const size_t oINT = AL((size_t)1024*4608*8);
    const size_t oF0  = AL((size_t)2048*1152*8);    // also ACC
    const size_t oXT  = AL((size_t)2048*1152*8);
    const size_t oFB  = AL((size_t)2048*1152*8);
    const size_t oIB  = AL((size_t)2048*1152*8);
    const size_t oGB  = AL((size_t)2048*1152*8);
    const size_t oRO  = AL((size_t)512*1152*8);
    const size_t oQ8X = AL((size_t)2048*1152);
    const size_t oQ8I = AL((size_t)1024*4608);
    const size_t oQ8O = AL((size_t)2048*1152);
    const size_t oQ8R = AL((size_t)512*1152);
    const size_t oQ8T = AL((size_t)8*1152);
    const size_t oQ8C = AL((size_t)8*1152);
    const size_t oDSX = AL(2048*8), oDSI = AL(1024*8), oDSO = AL(2048*8);
    const size_t oDSR = AL(512*8),  oDST = AL(8*8),    oDSC = AL(8*8);
    if (off > ws_size) return;

    // ---------- weight list + optional pre-ternarized region ----------
    WList wl{}; WOffs wo{};
    long long wn[37];
    int nw = 0;
    auto addw = [&](const float* w, long long n){ wl.p[nw]=w; wl.n[nw]=n; wn[nw]=n; nw++; };
    addw(te_w1, 294912); addw(te_w2, 1327104); addw(pp_w, 884736);
    addw(sa_gate_w, 10616832); addw(sa_down_w, 5308416);
    for (int l = 0; l < 2; ++l) {
        addw(ada_w + (size_t)l*7962624, 7962624);
        addw(sa_wi + (size_t)l*1327104, 1327104);
        addw(sa_wf + (size_t)l*1327104, 1327104);
        addw(sa_wg + (size_t)l*1327104, 1327104);
        addw(sa_wo + (size_t)l*1327104, 1327104);
        addw(mv_wi + (size_t)l*1327104, 1327104);
        addw(mv_wf + (size_t)l*1327104, 1327104);
        addw(mv_wg + (size_t)l*1327104, 1327104);
        addw(mv_wo + (size_t)l*1327104, 1327104);
        addw(rf_wi + (size_t)l*1327104, 1327104);
        addw(rf_wf + (size_t)l*1327104, 1327104);
        addw(rf_wg + (size_t)l*1327104, 1327104);
        addw(rf_wo + (size_t)l*1327104, 1327104);
        addw(gate_w + (size_t)l*10616832, 10616832);
        addw(down_w + (size_t)l*5308416, 5308416);
    }
    addw(fl_ada_w, 2654208); addw(fl_w, 36864);

    size_t off_saved = off;
    long long wtot = 0;
    for (int i = 0; i < 37; ++i) { wo.o[i] = wtot; wtot += (wn[i] + 255) & ~255LL; }
    const size_t oW8 = AL((size_t)wtot);
    const bool useW8 = (off <= ws_size);
    if (!useW8) off = off_saved;

    // ---------- optional transposed down-conv weight (f32, 21 MB) ----------
    size_t off_wt = off;
    const size_t oWt = AL((size_t)1152*4608*4);
    const bool useWt = (off <= ws_size);
    if (!useWt) off = off_wt;

    // ---------- tiered SA/MLP chunk enlargement (row-independent) ----------
    int schunk = 1024;
    size_t oINTb = 0, oQ8Ib = 0, oQ8Xb = 0, oDSXb = 0, oDSIb = 0;
    if (useW8) {
        size_t off_w8 = off;
        oINTb = AL((size_t)4096*4608*8); oQ8Ib = AL((size_t)4096*4608);
        oQ8Xb = AL((size_t)4096*1152);   oDSXb = AL(4096*8); oDSIb = AL(4096*8);
        if (off <= ws_size) schunk = 4096;
        else {
            off = off_w8;
            oINTb = AL((size_t)2048*4608*8); oQ8Ib = AL((size_t)2048*4608); oDSIb = AL(2048*8);
            if (off <= ws_size) schunk = 2048;
            else off = off_w8;
        }
    }

    char* w8p = (char*)d_ws;
    double* scales = (double*)(w8p + oScale);
    double* parts  = (double*)(w8p + oPart);
    double* probeD = (double*)(w8p + oProbe);
    int*    mflag  = (int*)(w8p + oFlag);
    double *SM1=(double*)(w8p+oSM1), *SM2=(double*)(w8p+oSM2), *SM3=(double*)(w8p+oSM3);
    double *CB=(double*)(w8p+oCB), *MOD=(double*)(w8p+oMOD);
    double *H=(double*)(w8p+oH), *INT=(double*)(w8p+oINT);
    double *F0=(double*)(w8p+oF0), *XT=(double*)(w8p+oXT);
    double *FB=(double*)(w8p+oFB), *IB=(double*)(w8p+oIB), *GB=(double*)(w8p+oGB);
    double *ACC=F0, *OB=H, *RO=(double*)(w8p+oRO);
    signed char *Q8X=(signed char*)(w8p+oQ8X), *Q8I=(signed char*)(w8p+oQ8I);
    signed char *Q8O=(signed char*)(w8p+oQ8O), *Q8R=(signed char*)(w8p+oQ8R);
    signed char *Q8T=(signed char*)(w8p+oQ8T), *Q8C=(signed char*)(w8p+oQ8C);
    double *DSX=(double*)(w8p+oDSX), *DSI=(double*)(w8p+oDSI), *DSO=(double*)(w8p+oDSO);
    double *DSR=(double*)(w8p+oDSR), *DST=(double*)(w8p+oDST), *DSC=(double*)(w8p+oDSC);
    signed char* W8 = (signed char*)(w8p + oW8);
    float* Wt = (float*)(w8p + oWt);

    double*      INTs = (schunk > 1024) ? (double*)(w8p + oINTb) : INT;
    signed char* Q8Is = (schunk > 1024) ? (signed char*)(w8p + oQ8Ib) : Q8I;
    double*      DSIs = (schunk > 1024) ? (double*)(w8p + oDSIb) : DSI;
    signed char* Q8Xs = (schunk == 4096) ? (signed char*)(w8p + oQ8Xb) : Q8X;
    double*      DSXs = (schunk == 4096) ? (double*)(w8p + oDSXb) : DSX;

    // ---------- probe + scales + ternarize + dc-w transpose ----------
    k_mfma64_probe<<<1, 64, 0, stream>>>(probeD);
    k_mfma64_check<<<1, 64, 0, stream>>>(probeD, mflag);
    k_abssum_all<<<dim3(32,37), 256, 0, stream>>>(wl, parts);
    k_abssum_fin<<<37, 64, 0, stream>>>(parts, scales);
    if (useW8)
        k_ternarize<<<dim3(64,37), 256, 0, stream>>>(wl, wo, scales, W8);
    if (useWt)
        k_dcw_prep<<<1152, 256, 0, stream>>>(sa_dc_w, Wt);

    // ---------- launch helpers ----------
    auto qgemm = [&](const signed char* A8, const double* as, const float* Win, int slot,
                     const float* b, double* Cout, int M, int N, int K, int accum){
        int gm = (M+127)/128, gn = (N+127)/128;
        if (useW8)
            k_qgemm<0,1><<<gm*gn, 256, 0, stream>>>(A8, as, Win, W8 + wo.o[slot],
                                                    scales+slot, wn[slot], b, Cout, M, N, K, accum, gm);
        else
            k_qgemm<0,0><<<gm*gn, 256, 0, stream>>>(A8, as, Win, nullptr,
                                                    scales+slot, wn[slot], b, Cout, M, N, K, accum, gm);
    };
    auto qgemmGate = [&](const signed char* A8, const double* as, const float* Win, int slot,
                         double* Cout, int M){
        int gm = (M+127)/128;
        if (useW8)
            k_qgemm<1,1><<<gm*36, 256, 0, stream>>>(A8, as, Win, W8 + wo.o[slot],
                                                    scales+slot, wn[slot], nullptr, Cout, M, 4608, 1152, 0, gm);
        else
            k_qgemm<1,0><<<gm*36, 256, 0, stream>>>(A8, as, Win, nullptr,
                                                    scales+slot, wn[slot], nullptr, Cout, M, 4608, 1152, 0, gm);
    };
    // fused f/i/g projection + scan3; fallback = 3x qgemm + gatepre + scan2
    auto fig = [&](const signed char* A8, const double* as, int sF, int sI, int sG,
                   const float* wF, const float* wI, const float* wG, int M,
                   int n_outer, long long ostr, int n_inner, long long tstr, int Tlen){
        if (useW8) {
            W3 w3{ {W8+wo.o[sF], W8+wo.o[sI], W8+wo.o[sG]},
                   {scales+sF, scales+sI, scales+sG},
                   {FB, IB, GB} };
            int gm = M/128;
            k_qgemm3<<<gm*27, 256, 0, stream>>>(A8, as, w3, 1327104, M, gm);
            long long nch = (long long)n_outer*n_inner;
            k_scan3<<<(unsigned)((nch+255)/256), 256, 0, stream>>>(FB, IB, OB, n_outer, ostr, n_inner, tstr, Tlen);
        } else {
            qgemm(A8, as, wF, sF, nullptr, FB, M, 1152, 1152, 0);
            qgemm(A8, as, wI, sI, nullptr, IB, M, 1152, 1152, 0);
            qgemm(A8, as, wG, sG, nullptr, GB, M, 1152, 1152, 0);
            long long nel = (long long)M*1152;
            k_gatepre<<<(unsigned)((nel+255)/256), 256, 0, stream>>>(FB, IB, nel);
            long long nch = (long long)n_outer*n_inner;
            k_scan2<<<(unsigned)((nch+255)/256), 256, 0, stream>>>(FB, IB, OB, n_outer, ostr, n_inner, tstr, Tlen);
        }
    };

    // ---------- conditioning vector c ----------
    k_temb<<<8, 128, 0, stream>>>(T, SM1);
    k_rsq8<double><<<8, 256, 0, stream>>>(SM1, Q8T, DST, 256, 0);
    qgemm(Q8T, DST, te_w1, 0, te_b1, SM3, 8, 1152, 256, 0);
    k_rsq8<double><<<8, 256, 0, stream>>>(SM3, Q8T, DST, 1152, 1);
    qgemm(Q8T, DST, te_w2, 1, te_b2, SM2, 8, 1152, 1152, 0);
    k_rsq8<float><<<8, 256, 0, stream>>>(Y, Q8T, DST, 768, 0);
    qgemm(Q8T, DST, pp_w, 2, pp_b, SM3, 8, 1152, 768, 0);
    k_add<<<36, 256, 0, stream>>>(SM2, SM3, CB, 9216);
    k_rsq8<double><<<8, 256, 0, stream>>>(CB, Q8C, DSC, 1152, 1);

    // ---------- spatial adapter: patch embed + block 0 only ----------
    k_dgemm<1,0><<<18*128, 256, 0, stream>>>(XC, sa_pe_w, sa_pe_b, H, 8192, 1152, 1536, 18, mflag);
    {
        const int nch = 8192 / schunk;
        for (int ch = 0; ch < nch; ++ch) {
            double* Hrow = H + (size_t)ch*schunk*1152;
            k_lnq8<<<schunk, 256, 1152*8, stream>>>(Hrow, Q8Xs, DSXs, 1152, sa_ln_g, sa_ln_b,
                                                    nullptr, nullptr, 0, 1e-5);
            qgemmGate(Q8Xs, DSXs, sa_gate_w, 3, INTs, schunk);
            k_rsq8<double><<<schunk, 256, 0, stream>>>(INTs, Q8Is, DSIs, 4608, 0);
            qgemm(Q8Is, DSIs, sa_down_w, 4, nullptr, Hrow, schunk, 1152, 4608, 0);
        }
    }
    if (useWt)
        k_dgemm<2,0><<<18*32, 256, 0, stream>>>(H, Wt, sa_dc_b, F0, 2048, 1152, 4608, 18, mflag);
    else
        k_dgemm<2,1><<<18*32, 256, 0, stream>>>(H, sa_dc_w, sa_dc_b, F0, 2048, 1152, 4608, 18, mflag);

    // ---------- patchify latents + pos + feats0 ----------
    k_patchify<<<9216, 256, 0, stream>>>(X, xe_w, xe_b, pos, F0, XT);
    k_rsq8<float><<<512, 256, 0, stream>>>(REF, Q8R, DSR, 1152, 0);

    // ---------- transformer blocks (OB aliases dead H) ----------
    for (int l = 0; l < 2; ++l) {
        int sb = 5 + l*15;
        const float *wada = ada_w + (size_t)l*7962624, *bada = ada_b + (size_t)l*6912;
        const float *swi = sa_wi + (size_t)l*1327104, *swf = sa_wf + (size_t)l*1327104;
        const float *swg = sa_wg + (size_t)l*1327104, *swo = sa_wo + (size_t)l*1327104;
        const float *mwi = mv_wi + (size_t)l*1327104, *mwf = mv_wf + (size_t)l*1327104;
        const float *mwg = mv_wg + (size_t)l*1327104, *mwo = mv_wo + (size_t)l*1327104;
        const float *rwi = rf_wi + (size_t)l*1327104, *rwf = rf_wf + (size_t)l*1327104;
        const float *rwg = rf_wg + (size_t)l*1327104, *rwo = rf_wo + (size_t)l*1327104;
        const float *wgt = gate_w + (size_t)l*10616832, *wdn = down_w + (size_t)l*5308416;

        qgemm(Q8C, DSC, wada, sb+0, bada, MOD, 8, 6912, 1152, 0);

        k_lnq8<<<2048, 256, 1152*8, stream>>>(XT, Q8X, DSX, 1152, nullptr, nullptr,
                                              MOD+0, MOD+1152, 6912, 1e-6);

        // self attention (seq = 256 tokens)
        fig(Q8X, DSX, sb+2, sb+1, sb+3, swf, swi, swg, 2048, 8, 294912LL, 1152, 1152LL, 256);
        k_ogateq8<<<2048, 256, 1152*8, stream>>>(OB, GB, Q8O, DSO, 1152);
        qgemm(Q8O, DSO, swo, sb+4, nullptr, ACC, 2048, 1152, 1152, 0);

        // multi-view attention (seq = 4 views; token layout unchanged)
        fig(Q8X, DSX, sb+6, sb+5, sb+7, mwf, mwi, mwg, 2048, 2, 1179648LL, 294912, 294912LL, 4);
        k_ogateq8<<<2048, 256, 1152*8, stream>>>(OB, GB, Q8O, DSO, 1152);
        qgemm(Q8O, DSO, mwo, sb+8, nullptr, ACC, 2048, 1152, 1152, 1);   // +=

        // ref attention on 2 unique batches
        fig(Q8R, DSR, sb+10, sb+9, sb+11, rwf, rwi, rwg, 512, 2, 294912LL, 1152, 1152LL, 256);
        k_ogateq8<<<512, 256, 1152*8, stream>>>(OB, GB, Q8O, DSO, 1152);
        qgemm(Q8O, DSO, rwo, sb+12, nullptr, RO, 512, 1152, 1152, 0);

        k_resid_attn<<<9216, 256, 0, stream>>>(XT, ACC, RO, MOD);

        // MLP
        k_lnq8<<<2048, 256, 1152*8, stream>>>(XT, Q8X, DSX, 1152, nullptr, nullptr,
                                              MOD+3*1152, MOD+4*1152, 6912, 1e-6);
        if (schunk >= 2048) {
            qgemmGate(Q8X, DSX, wgt, sb+13, INTs, 2048);
            k_rsq8<double><<<2048, 256, 0, stream>>>(INTs, Q8Is, DSIs, 4608, 0);
            qgemm(Q8Is, DSIs, wdn, sb+14, nullptr, OB, 2048, 1152, 4608, 0);
        } else {
            for (int ch = 0; ch < 2; ++ch) {
                qgemmGate(Q8X + (size_t)ch*1024*1152, DSX + ch*1024, wgt, sb+13, INT, 1024);
                k_rsq8<double><<<1024, 256, 0, stream>>>(INT, Q8I, DSI, 4608, 0);
                qgemm(Q8I, DSI, wdn, sb+14, nullptr, OB + (size_t)ch*1024*1152, 1024, 1152, 4608, 0);
            }
        }
        k_resid_mlp<<<9216, 256, 0, stream>>>(XT, OB, MOD);
    }

    // ---------- final layer + unpatchify ----------
    qgemm(Q8C, DSC, fl_ada_w, 35, fl_ada_b, MOD, 8, 2304, 1152, 0);
    k_lnq8<<<2048, 256, 1152*8, stream>>>(XT, Q8X, DSX, 1152, nullptr, nullptr,
                                          MOD+0, MOD+1152, 2304, 1e-6);
    qgemm(Q8X, DSX, fl_w, 36, fl_b, FB, 2048, 32, 1152, 0);
    k_unpatch<<<256, 256, 0, stream>>>(FB, OUT);
}

// Round 13
// 4702.996 us; speedup vs baseline: 1.3947x; 1.0310x over previous
//
#include <hip/hip_runtime.h>

#define DEV __device__ __forceinline__

typedef __attribute__((ext_vector_type(4))) int i32x4;
typedef __attribute__((ext_vector_type(4))) double f64x4;

// ---------------------------------------------------------------------------
// TernaryMVAdapter forward on MI355X. Round 13: round-12 pipeline (4849us) +
// deeper K-windows: k_dgemm MFMA path BK=32, k_qgemm/k_qgemm3 BK=128.
// Halves barrier counts, doubles MFMA per window. dgemm per-acc f64 MFMA
// order unchanged (bitwise identical); qgemm is exact integer (order-free).
// ---------------------------------------------------------------------------

struct WList { const float* p[37]; long long n[37]; };
struct WOffs { long long o[37]; };
struct W3 { const signed char* w[3]; const double* sc[3]; double* c[3]; };

DEV int2 xcd_swz(int gridx)
{
    const int nwg = (int)gridDim.x, b = (int)blockIdx.x;
    const int q = nwg >> 3, r = nwg & 7, xcd = b & 7, idx = b >> 3;
    const int lb = (xcd < r ? xcd*(q+1) : r*(q+1) + (xcd-r)*q) + idx;
    return make_int2(lb % gridx, lb / gridx);
}

// ---------------- f64 MFMA layout probe (exact-integer classification) -----
__global__ void k_mfma64_probe(double* __restrict__ out)
{
    const int lane = threadIdx.x;                      // 64 threads
    double a = (double)(1 + lane);                     // injective per-lane
    double b = (double)(101 + 3*lane);
    f64x4 acc = {0.0, 0.0, 0.0, 0.0};
    acc = __builtin_amdgcn_mfma_f64_16x16x4f64(a, b, acc, 0, 0, 0);
#pragma unroll
    for (int r = 0; r < 4; ++r) out[lane*4 + r] = acc[r];
}

__global__ void k_mfma64_check(const double* __restrict__ probe, int* __restrict__ flag)
{
    if (threadIdx.x != 0) return;
    int best = 0;
    for (int c = 0; c < 16 && !best; ++c) {
        const int a_alt = c & 1, b_alt = (c >> 1) & 1, dv = (c >> 2) & 3;
        double Amat[16][4], Bmat[4][16];
        for (int l = 0; l < 64; ++l) {
            int ai = a_alt ? (l >> 2) : (l & 15);
            int ak = a_alt ? (l & 3)  : (l >> 4);
            Amat[ai][ak] = (double)(1 + l);
            int bj = b_alt ? (l >> 2) : (l & 15);
            int bk = b_alt ? (l & 3)  : (l >> 4);
            Bmat[bk][bj] = (double)(101 + 3*l);
        }
        double C[16][16];
        for (int i = 0; i < 16; ++i)
            for (int j = 0; j < 16; ++j) {
                double s = 0.0;
                for (int k = 0; k < 4; ++k) s += Amat[i][k] * Bmat[k][j];
                C[i][j] = s;
            }
        bool ok = true;
        for (int l = 0; l < 64 && ok; ++l)
            for (int r = 0; r < 4 && ok; ++r) {
                int ir = (dv & 2) ? (4*r + (l >> 4)) : (4*(l >> 4) + r);
                int ic = l & 15;
                if (dv & 1) { int t = ir; ir = ic; ic = t; }
                if (probe[l*4 + r] != C[ir][ic]) ok = false;
            }
        if (ok) best = 1 + c;
    }
    *flag = best;
}

// ---------------- fused deterministic |w| sums (37 slots) ------------------
__global__ void k_abssum_all(WList wl, double* __restrict__ partials)
{
    const int slot = blockIdx.y;
    const float* w = wl.p[slot];
    const long long n = wl.n[slot];
    __shared__ double sm[256];
    double s = 0.0;
    for (long long i = (long long)blockIdx.x*256 + threadIdx.x; i < n; i += 32LL*256)
        s += (double)fabsf(w[i]);
    sm[threadIdx.x] = s;
    __syncthreads();
    for (int k = 128; k > 0; k >>= 1) {
        if ((int)threadIdx.x < k) sm[threadIdx.x] += sm[threadIdx.x + k];
        __syncthreads();
    }
    if (threadIdx.x == 0) partials[slot*32 + blockIdx.x] = sm[0];
}

__global__ void k_abssum_fin(const double* __restrict__ partials, double* __restrict__ out)
{
    const int slot = blockIdx.x;
    if (threadIdx.x == 0) {
        double s = 0.0;
        for (int i = 0; i < 32; ++i) s += partials[slot*32 + i];
        out[slot] = s;
    }
}

// ---------------- one-time weight ternarization (f64-exact decision) -------
__global__ void k_ternarize(WList wl, WOffs wo, const double* __restrict__ scales,
                            signed char* __restrict__ W8)
{
    const int slot = blockIdx.y;
    const float* w = wl.p[slot];
    const long long n4 = wl.n[slot] >> 2;
    const double dqw = fmax(scales[slot] / (double)wl.n[slot], 1e-5);
    const double thr = 0.5 * dqw;
    signed char* o = W8 + wo.o[slot];
    for (long long i = (long long)blockIdx.x*256 + threadIdx.x; i < n4; i += 64LL*256) {
        float4 v = *reinterpret_cast<const float4*>(w + i*4);
        float we[4] = {v.x, v.y, v.z, v.w};
        char r[4];
#pragma unroll
        for (int e = 0; e < 4; ++e) {
            double wd = (double)we[e];
            r[e] = (char)((wd > thr) - (wd < -thr));
        }
        *reinterpret_cast<char4*>(o + i*4) = make_char4(r[0], r[1], r[2], r[3]);
    }
}

// ---------------- sa_dc_w pre-transpose to linear k' -----------------------
__global__ void k_dcw_prep(const float* __restrict__ w, float* __restrict__ wt)
{
    int row = blockIdx.x;                              // 1152
    for (int k = threadIdx.x; k < 4608; k += 256) {
        int q = k / 1152, c = k - q*1152;
        wt[(size_t)row*4608 + k] = w[(size_t)row*4608 + (size_t)c*4 + q];
    }
}

// ---------------- timestep frequency embedding (f64) -----------------------
__global__ void k_temb(const float* __restrict__ t, double* __restrict__ out)
{
    int b = blockIdx.x, j = threadIdx.x;               // 8 x 128
    double fr  = exp(-9.210340371976184 * (double)j / 128.0);
    double ang = (double)t[b] * fr;
    out[b*256 + j]       = cos(ang);
    out[b*256 + 128 + j] = sin(ang);
}

// ---------------- rmsnorm + int8 absmax quant (f64, LDS-free) --------------
template<typename TI>
__global__ void k_rsq8(const TI* __restrict__ x, signed char* __restrict__ q8,
                       double* __restrict__ dscale, int K, int pre_silu)
{
    __shared__ double red[256], red2[256];
    const int row = blockIdx.x, tid = threadIdx.x;
    const TI* xr = x + (size_t)row*K;
    double ss = 0.0, am = 0.0;
    for (int i = tid; i < K; i += 256) {
        double v = (double)xr[i];
        if (pre_silu) v = v / (1.0 + exp(-v));
        ss += v*v; am = fmax(am, fabs(v));
    }
    red[tid] = ss; red2[tid] = am;
    __syncthreads();
    for (int s = 128; s > 0; s >>= 1) {
        if (tid < s) { red[tid] += red[tid+s]; red2[tid] = fmax(red2[tid], red2[tid+s]); }
        __syncthreads();
    }
    double rms = 1.0 / sqrt(red[0]/(double)K + 1e-8);
    double s   = 127.0 / fmax(red2[0]*rms, 1e-5);
    signed char* orow = q8 + (size_t)row*K;
    for (int i = tid; i < K; i += 256) {
        double v = (double)xr[i];
        if (pre_silu) v = v / (1.0 + exp(-v));
        orow[i] = (signed char)(int)fmin(fmax(rint(v*rms*s), -128.0), 127.0);
    }
    if (tid == 0) dscale[row] = s;
}

// ---------------- layernorm(+gb/+mod) + rmsnorm + int8 quant (f64) ---------
__global__ void k_lnq8(const double* __restrict__ x, signed char* __restrict__ q8,
                       double* __restrict__ dscale, int K,
                       const float* __restrict__ gamma, const float* __restrict__ beta,
                       const double* __restrict__ sh, const double* __restrict__ sc,
                       int modstride, double eps)
{
    extern __shared__ double rb[];
    __shared__ double red[256], red2[256];
    const int row = blockIdx.x, tid = threadIdx.x;
    const double* xr = x + (size_t)row*K;
    double s1 = 0.0;
    for (int i = tid; i < K; i += 256) { double v = xr[i]; rb[i] = v; s1 += v; }
    red[tid] = s1; __syncthreads();
    for (int s = 128; s > 0; s >>= 1) { if (tid < s) red[tid] += red[tid+s]; __syncthreads(); }
    double mu = red[0]/(double)K;
    __syncthreads();
    double s2 = 0.0;
    for (int i = tid; i < K; i += 256) { double d = rb[i]-mu; s2 += d*d; }
    red[tid] = s2; __syncthreads();
    for (int s = 128; s > 0; s >>= 1) { if (tid < s) red[tid] += red[tid+s]; __syncthreads(); }
    double r = 1.0 / sqrt(red[0]/(double)K + eps);
    const int bn = row >> 8;
    __syncthreads();
    double ss = 0.0, am = 0.0;
    for (int i = tid; i < K; i += 256) {
        double y = (rb[i]-mu)*r;
        if (gamma) y = y*(double)gamma[i] + (double)beta[i];
        if (sh)    y = y*(1.0 + sc[(size_t)bn*modstride + i]) + sh[(size_t)bn*modstride + i];
        rb[i] = y; ss += y*y; am = fmax(am, fabs(y));
    }
    red[tid] = ss; red2[tid] = am;
    __syncthreads();
    for (int s = 128; s > 0; s >>= 1) {
        if (tid < s) { red[tid] += red[tid+s]; red2[tid] = fmax(red2[tid], red2[tid+s]); }
        __syncthreads();
    }
    double rms = 1.0 / sqrt(red[0]/(double)K + 1e-8);
    double s   = 127.0 / fmax(red2[0]*rms, 1e-5);
    signed char* orow = q8 + (size_t)row*K;
    for (int i = tid; i < K; i += 256)
        orow[i] = (signed char)(int)fmin(fmax(rint(rb[i]*rms*s), -128.0), 127.0);
    if (tid == 0) dscale[row] = s;
}

// ---------------- ogate (rmsnorm*g*sig(g)) + rmsnorm + quant (f64) ---------
__global__ void k_ogateq8(const double* __restrict__ O, const double* __restrict__ G,
                          signed char* __restrict__ q8, double* __restrict__ dscale, int K)
{
    extern __shared__ double rb[];
    __shared__ double red[256], red2[256];
    const int row = blockIdx.x, tid = threadIdx.x;
    const double* orow = O + (size_t)row*K;
    const double* grow = G + (size_t)row*K;
    double ss = 0.0;
    for (int i = tid; i < K; i += 256) { double v = orow[i]; rb[i] = v; ss += v*v; }
    red[tid] = ss; __syncthreads();
    for (int s = 128; s > 0; s >>= 1) { if (tid < s) red[tid] += red[tid+s]; __syncthreads(); }
    double rmso = 1.0 / sqrt(red[0]/(double)K + 1e-8);
    __syncthreads();
    double ss2 = 0.0, am = 0.0;
    for (int i = tid; i < K; i += 256) {
        double g = grow[i];
        double y = rb[i]*rmso * g / (1.0 + exp(-g));
        rb[i] = y; ss2 += y*y; am = fmax(am, fabs(y));
    }
    red[tid] = ss2; red2[tid] = am;
    __syncthreads();
    for (int s = 128; s > 0; s >>= 1) {
        if (tid < s) { red[tid] += red[tid+s]; red2[tid] = fmax(red2[tid], red2[tid+s]); }
        __syncthreads();
    }
    double rms = 1.0 / sqrt(red[0]/(double)K + 1e-8);
    double s   = 127.0 / fmax(red2[0]*rms, 1e-5);
    signed char* qrow = q8 + (size_t)row*K;
    for (int i = tid; i < K; i += 256)
        qrow[i] = (signed char)(int)fmin(fmax(rint(rb[i]*rms*s), -128.0), 127.0);
    if (tid == 0) dscale[row] = s;
}

// ---------------- HGRN scans -----------------------------------------------
__global__ void k_gatepre(double* __restrict__ F, double* __restrict__ I, long long n)
{
    long long i = (long long)blockIdx.x*256 + threadIdx.x;
    if (i >= n) return;
    double fp = F[i], ip = I[i];
    double f = 1.0/(1.0+exp(-fp));
    double v = (ip/(1.0+exp(-ip)))*(1.0-f);
    F[i] = f; I[i] = v;
}

__global__ void k_scan2(const double* __restrict__ F, const double* __restrict__ V,
                        double* __restrict__ O, int n_outer, long long outer_stride,
                        int n_inner, long long t_stride, int T)
{
    long long chain = (long long)blockIdx.x*blockDim.x + threadIdx.x;
    if (chain >= (long long)n_outer*n_inner) return;
    long long base = (chain / n_inner)*outer_stride + (chain % n_inner);
    double h = 0.0;
    for (int t = 0; t < T; ++t) {
        long long idx = base + (long long)t*t_stride;
        h = F[idx]*h + V[idx];
        O[idx] = h;
    }
}

__global__ void k_scan3(const double* __restrict__ F, const double* __restrict__ Isilu,
                        double* __restrict__ O, int n_outer, long long outer_stride,
                        int n_inner, long long t_stride, int T)
{
    long long chain = (long long)blockIdx.x*blockDim.x + threadIdx.x;
    if (chain >= (long long)n_outer*n_inner) return;
    long long base = (chain / n_inner)*outer_stride + (chain % n_inner);
    double h = 0.0;
    for (int t = 0; t < T; ++t) {
        long long idx = base + (long long)t*t_stride;
        double f = F[idx];
        double v = Isilu[idx]*(1.0-f);
        h = f*h + v;
        O[idx] = h;
    }
}

// ---------------- misc elementwise (f64) -----------------------------------
__global__ void k_add(const double* __restrict__ a, const double* __restrict__ b,
                      double* __restrict__ o, int n)
{
    int i = blockIdx.x*256 + threadIdx.x;
    if (i < n) o[i] = a[i] + b[i];
}

__global__ void k_resid_attn(double* __restrict__ xt, const double* __restrict__ acc,
                             const double* __restrict__ refo, const double* __restrict__ mod)
{
    int idx = blockIdx.x*256 + threadIdx.x;            // 2048*1152 exact
    int r = idx / 1152, d = idx - r*1152;
    int bn = r >> 8, l = r & 255;
    double ga = mod[(size_t)bn*6912 + 2*1152 + d];
    double rv = refo[((size_t)((bn>>2)*256 + l))*1152 + d];
    xt[idx] += ga*(acc[idx] + rv);
}

__global__ void k_resid_mlp(double* __restrict__ xt, const double* __restrict__ t2,
                            const double* __restrict__ mod)
{
    int idx = blockIdx.x*256 + threadIdx.x;
    int r = idx / 1152, d = idx - r*1152;
    int bn = r >> 8;
    xt[idx] += mod[(size_t)bn*6912 + 5*1152 + d] * t2[idx];
}

__global__ void k_patchify(const float* __restrict__ x, const float* __restrict__ w,
                           const float* __restrict__ bias, const float* __restrict__ pos,
                           const double* __restrict__ f0, double* __restrict__ xt)
{
    int idx = blockIdx.x*256 + threadIdx.x;            // 2048*1152 exact
    int r = idx / 1152, o = idx - r*1152;
    int bn = r >> 8, p = r & 255;
    int y = p >> 4, xx = p & 15;
    double acc = (double)bias[o] + (double)pos[(size_t)p*1152 + o] + f0[idx];
#pragma unroll
    for (int c = 0; c < 4; ++c)
#pragma unroll
        for (int ky = 0; ky < 2; ++ky)
#pragma unroll
            for (int kx = 0; kx < 2; ++kx)
                acc += (double)x[((size_t)(bn*4 + c)*32 + 2*y+ky)*32 + 2*xx+kx]
                     * (double)w[o*16 + c*4 + ky*2 + kx];
    xt[idx] = acc;
}

__global__ void k_unpatch(const double* __restrict__ flo, float* __restrict__ out)
{
    int idx = blockIdx.x*256 + threadIdx.x;            // 65536 exact
    int xx = idx & 31, y = (idx>>5)&31, ch = (idx>>10)&7, b = idx>>13;
    int hp = y>>1, py = y&1, wp = xx>>1, px = xx&1;
    out[idx] = (float)flo[((size_t)(b*256 + hp*16 + wp))*32 + (py*2+px)*8 + ch];
}

// ---------------- f64 GEMM: probed MFMA (BK=32) + proven SIMT fallback -----
template<int AMODE>
DEV void load_a4d(const void* __restrict__ A, int row, int k, int M, double o[4])
{
    if (row >= M) { o[0]=o[1]=o[2]=o[3]=0.0; return; }
    if constexpr (AMODE == 1) {
        const float* Af = (const float*)A;
        int b = row>>10, p = row&1023, oy = p>>5, ox = p&31;
        int c = k>>8, ky = (k>>4)&15, kx = k&15;
        float4 v = *reinterpret_cast<const float4*>(
            Af + (((size_t)(b*6+c)*512 + (size_t)(oy*16+ky))*512 + (size_t)(ox*16+kx)));
        o[0]=v.x; o[1]=v.y; o[2]=v.z; o[3]=v.w;
    } else {
        const double* Ad = (const double*)A;
        int b = row>>8, y = (row>>4)&15, x = row&15;
        int q = k/1152, c = k - q*1152, ky = q>>1, kx = q&1;
        const double* p = Ad + (size_t)(b*1024 + (2*y+ky)*32 + 2*x+kx)*1152 + c;
        o[0]=p[0]; o[1]=p[1]; o[2]=p[2]; o[3]=p[3];
    }
}

template<int WMODE>
DEV void load_w4d(const float* __restrict__ W, int row, int k, int Nb, int K, double o[4])
{
    if (row >= Nb) { o[0]=o[1]=o[2]=o[3]=0.0; return; }
    if constexpr (WMODE == 0) {
        float4 v = *reinterpret_cast<const float4*>(W + (size_t)row*K + k);
        o[0]=v.x; o[1]=v.y; o[2]=v.z; o[3]=v.w;
    } else {
        int q = k/1152, c = k - q*1152;
        const float* p = W + (size_t)row*4608 + (size_t)c*4 + q;
        o[0]=p[0]; o[1]=p[4]; o[2]=p[8]; o[3]=p[12];
    }
}

template<int AMODE, int WMODE>
__global__ __launch_bounds__(256)
void k_dgemm(const void* __restrict__ A, const float* __restrict__ W,
             const float* __restrict__ bias, double* __restrict__ C,
             int M, int N, int K, int gridx, const int* __restrict__ mfma_flag)
{
    __shared__ double As[64][33];                  // [m][k0..31], +1 pad
    __shared__ double Ws[64][33];                  // [n][k0..31]
    const int tid = threadIdx.x;
    const int2 bxy = xcd_swz(gridx);
    const int m0 = bxy.y*64, n0 = bxy.x*64;
    const int lr = tid >> 2;                       // staging row 0..63
    const int lc = (tid & 3) * 4;                  // staging k {0,4,8,12}
    const int flag = *mfma_flag;                   // uniform

    if (flag) {
        const int cmb = flag - 1;
        const int a_alt = cmb & 1, b_alt = (cmb >> 1) & 1, dv = (cmb >> 2) & 3;
        const int lane = tid & 63, wid = tid >> 6;
        const int wm = wid >> 1, wn = wid & 1;     // 2x2 waves of 32x32
        const int ai = a_alt ? (lane >> 2) : (lane & 15);
        const int ak = a_alt ? (lane & 3)  : (lane >> 4);
        const int bj = b_alt ? (lane >> 2) : (lane & 15);
        const int bk = b_alt ? (lane & 3)  : (lane >> 4);
        f64x4 fa[2][2];
#pragma unroll
        for (int i = 0; i < 2; ++i)
#pragma unroll
            for (int j = 0; j < 2; ++j) fa[i][j] = f64x4{0.0,0.0,0.0,0.0};

        for (int kt = 0; kt < K; kt += 32) {       // BK=32: half the barriers
#pragma unroll
            for (int h = 0; h < 2; ++h) {
                double v[4];
                load_a4d<AMODE>(A, m0+lr, kt + h*16 + lc, M, v);
                As[lr][h*16+lc+0]=v[0]; As[lr][h*16+lc+1]=v[1];
                As[lr][h*16+lc+2]=v[2]; As[lr][h*16+lc+3]=v[3];
                double wv[4];
                load_w4d<WMODE>(W, n0+lr, kt + h*16 + lc, N, K, wv);
                Ws[lr][h*16+lc+0]=wv[0]; Ws[lr][h*16+lc+1]=wv[1];
                Ws[lr][h*16+lc+2]=wv[2]; Ws[lr][h*16+lc+3]=wv[3];
            }
            __syncthreads();
#pragma unroll
            for (int k4 = 0; k4 < 8; ++k4) {       // sequential k order preserved
                double a0 = As[wm*32 + ai][k4*4 + ak];
                double a1 = As[wm*32 + 16 + ai][k4*4 + ak];
                double b0 = Ws[wn*32 + bj][k4*4 + bk];
                double b1 = Ws[wn*32 + 16 + bj][k4*4 + bk];
                fa[0][0] = __builtin_amdgcn_mfma_f64_16x16x4f64(a0, b0, fa[0][0], 0, 0, 0);
                fa[0][1] = __builtin_amdgcn_mfma_f64_16x16x4f64(a0, b1, fa[0][1], 0, 0, 0);
                fa[1][0] = __builtin_amdgcn_mfma_f64_16x16x4f64(a1, b0, fa[1][0], 0, 0, 0);
                fa[1][1] = __builtin_amdgcn_mfma_f64_16x16x4f64(a1, b1, fa[1][1], 0, 0, 0);
            }
            __syncthreads();
        }
#pragma unroll
        for (int i = 0; i < 2; ++i)
#pragma unroll
            for (int j = 0; j < 2; ++j)
#pragma unroll
                for (int r = 0; r < 4; ++r) {
                    int ir = (dv & 2) ? (4*r + (lane >> 4)) : (4*(lane >> 4) + r);
                    int ic = lane & 15;
                    if (dv & 1) { int t = ir; ir = ic; ic = t; }
                    int row = m0 + wm*32 + i*16 + ir;
                    int col = n0 + wn*32 + j*16 + ic;
                    if (row < M && col < N)
                        C[(size_t)row*N + col] = fa[i][j][r] + (bias ? (double)bias[col] : 0.0);
                }
        return;
    }

    // ---- SIMT fallback (proven rounds 3-12; BK=16, unchanged) ----
    const int tx = tid & 15, ty = tid >> 4;
    double acc[4][4] = {};
    for (int kt = 0; kt < K; kt += 16) {
        {
            double v[4];
            load_a4d<AMODE>(A, m0+lr, kt+lc, M, v);
            As[lr][lc+0]=v[0]; As[lr][lc+1]=v[1]; As[lr][lc+2]=v[2]; As[lr][lc+3]=v[3];
        }
        {
            double wv[4];
            load_w4d<WMODE>(W, n0+lr, kt+lc, N, K, wv);
            Ws[lr][lc+0]=wv[0]; Ws[lr][lc+1]=wv[1]; Ws[lr][lc+2]=wv[2]; Ws[lr][lc+3]=wv[3];
        }
        __syncthreads();
#pragma unroll
        for (int k = 0; k < 16; ++k) {
            double a[4], b[4];
#pragma unroll
            for (int e = 0; e < 4; ++e) { a[e] = As[ty + 16*e][k]; b[e] = Ws[tx + 16*e][k]; }
#pragma unroll
            for (int i = 0; i < 4; ++i)
#pragma unroll
                for (int j = 0; j < 4; ++j) acc[i][j] += a[i]*b[j];
        }
        __syncthreads();
    }
#pragma unroll
    for (int i = 0; i < 4; ++i) {
        int row = m0 + ty + 16*i;
        if (row >= M) continue;
#pragma unroll
        for (int j = 0; j < 4; ++j) {
            int col = n0 + tx + 16*j;
            if (col >= N) continue;
            C[(size_t)row*N + col] = acc[i][j] + (bias ? (double)bias[col] : 0.0);
        }
    }
}

// ---------------- int8 MFMA GEMM (exact), BK=128, XCD swizzle --------------
template<int GATE, int PRE>
__global__ __launch_bounds__(256)
void k_qgemm(const signed char* __restrict__ A8, const double* __restrict__ ascale,
             const float* __restrict__ Wf, const signed char* __restrict__ W8,
             const double* __restrict__ wsum, long long wcount,
             const float* __restrict__ bias, double* __restrict__ C,
             int M, int N, int K, int accum, int gridM)
{
    __shared__ __align__(16) signed char Als[8][128][16];
    __shared__ __align__(16) signed char Bls[8][128][16];
    __shared__ __align__(16) signed char B2ls[GATE?8:1][GATE?128:1][16];
    const int tid = threadIdx.x;
    const int lane = tid & 63, wid = tid >> 6;
    const int wr = wid >> 1, wc = wid & 1;             // 2x2 waves, 64x64 each
    const int2 bxy = xcd_swz(gridM);
    const int m0 = bxy.x*128, n0 = bxy.y*128;
    const int ks = lane >> 4, fr = lane & 15;

    const double dqw = fmax(*wsum / (double)wcount, 1e-5);
    const double thr = 0.5 * dqw;

    i32x4 acc[4][4];
    i32x4 acc2[GATE?4:1][4];
#pragma unroll
    for (int i = 0; i < 4; ++i)
#pragma unroll
        for (int j = 0; j < 4; ++j) {
            acc[i][j] = i32x4{0,0,0,0};
            if constexpr (GATE) acc2[i][j] = i32x4{0,0,0,0};
        }

    for (int kt = 0; kt < K; kt += 128) {          // all K divide 128
#pragma unroll
        for (int c = 0; c < 4; ++c) {
            int idx = tid + c*256;
            int row = idx & 127, kslot = idx >> 7;  // kslot 0..7
            i32x4 v = {0,0,0,0};
            if (m0 + row < M)
                v = *reinterpret_cast<const i32x4*>(A8 + (size_t)(m0+row)*K + kt + kslot*16);
            *reinterpret_cast<i32x4*>(&Als[kslot][row][0]) = v;
        }
#pragma unroll
        for (int c = 0; c < 4; ++c) {
            int idx = tid + c*256;
            int row = idx & 127, kslot = idx >> 7;
            i32x4 pv = {0,0,0,0};
            if (n0 + row < N) {
                if constexpr (PRE) {
                    pv = *reinterpret_cast<const i32x4*>(W8 + (size_t)(n0+row)*K + kt + kslot*16);
                } else {
                    const float* wp = Wf + (size_t)(n0+row)*K + kt + kslot*16;
#pragma unroll
                    for (int d = 0; d < 4; ++d) {
                        float4 wv = *reinterpret_cast<const float4*>(wp + d*4);
                        float we[4] = {wv.x, wv.y, wv.z, wv.w};
                        unsigned p = 0;
#pragma unroll
                        for (int e = 0; e < 4; ++e) {
                            double wd = (double)we[e];
                            int q = (wd > thr) - (wd < -thr);
                            p |= ((unsigned)(q & 255)) << (8*e);
                        }
                        pv[d] = (int)p;
                    }
                }
            }
            *reinterpret_cast<i32x4*>(&Bls[kslot][row][0]) = pv;
        }
        if constexpr (GATE) {
#pragma unroll
            for (int c = 0; c < 4; ++c) {
                int idx = tid + c*256;
                int row = idx & 127, kslot = idx >> 7;
                i32x4 pv = {0,0,0,0};
                if (n0 + row < N) {
                    if constexpr (PRE) {
                        pv = *reinterpret_cast<const i32x4*>(W8 + (size_t)(n0+row+N)*K + kt + kslot*16);
                    } else {
                        const float* wp = Wf + (size_t)(n0+row+N)*K + kt + kslot*16;
#pragma unroll
                        for (int d = 0; d < 4; ++d) {
                            float4 wv = *reinterpret_cast<const float4*>(wp + d*4);
                            float we[4] = {wv.x, wv.y, wv.z, wv.w};
                            unsigned p = 0;
#pragma unroll
                            for (int e = 0; e < 4; ++e) {
                                double wd = (double)we[e];
                                int q = (wd > thr) - (wd < -thr);
                                p |= ((unsigned)(q & 255)) << (8*e);
                            }
                            pv[d] = (int)p;
                        }
                    }
                }
                *reinterpret_cast<i32x4*>(&B2ls[kslot][row][0]) = pv;
            }
        }
        __syncthreads();
#pragma unroll
        for (int kk = 0; kk < 2; ++kk) {
            const int kb = kk*4 + ks;
            i32x4 a[4];
#pragma unroll
            for (int i = 0; i < 4; ++i)
                a[i] = *reinterpret_cast<const i32x4*>(&Als[kb][wr*64 + i*16 + fr][0]);
#pragma unroll
            for (int j = 0; j < 4; ++j) {
                i32x4 b = *reinterpret_cast<const i32x4*>(&Bls[kb][wc*64 + j*16 + fr][0]);
#pragma unroll
                for (int i = 0; i < 4; ++i)
                    acc[i][j] = __builtin_amdgcn_mfma_i32_16x16x64_i8(a[i], b, acc[i][j], 0, 0, 0);
                if constexpr (GATE) {
                    i32x4 b2 = *reinterpret_cast<const i32x4*>(&B2ls[kb][wc*64 + j*16 + fr][0]);
#pragma unroll
                    for (int i = 0; i < 4; ++i)
                        acc2[i][j] = __builtin_amdgcn_mfma_i32_16x16x64_i8(a[i], b2, acc2[i][j], 0, 0, 0);
                }
            }
        }
        __syncthreads();
    }

#pragma unroll
    for (int i = 0; i < 4; ++i) {
#pragma unroll
        for (int r = 0; r < 4; ++r) {
            int row = m0 + wr*64 + i*16 + (lane>>4)*4 + r;
            if (row >= M) continue;
            double mul = dqw / ascale[row];
#pragma unroll
            for (int j = 0; j < 4; ++j) {
                int col = n0 + wc*64 + j*16 + (lane & 15);
                if (col >= N) continue;
                size_t o = (size_t)row*N + col;
                if constexpr (GATE) {
                    double g = (double)acc[i][j][r] * mul;
                    double y = (double)acc2[i][j][r] * mul;
                    C[o] = g/(1.0+exp(-g)) * y;
                } else {
                    double v = (double)acc[i][j][r] * mul;
                    if (bias) v += (double)bias[col];
                    C[o] = accum ? C[o] + v : v;
                }
            }
        }
    }
}

// ---------------- fused wf/wi/wg GEMM (N=K=1152), BK=128 -------------------
__global__ __launch_bounds__(256)
void k_qgemm3(const signed char* __restrict__ A8, const double* __restrict__ ascale,
              W3 w3, long long wcount, int M, int gridM)
{
    __shared__ __align__(16) signed char Als[8][128][16];
    __shared__ __align__(16) signed char Bls[8][128][16];
    const int tid = threadIdx.x;
    const int lane = tid & 63, wid = tid >> 6;
    const int wr = wid >> 1, wc = wid & 1;
    const int2 bxy = xcd_swz(gridM);
    const int m0 = bxy.x*128;
    const int yy = bxy.y;
    const int g = yy / 9, nt = yy - g*9;
    const int n0 = nt*128;
    const signed char* W8 = w3.w[g];
    double* C = w3.c[g];
    const int ks = lane >> 4, fr = lane & 15;

    const double dqw = fmax(*w3.sc[g] / (double)wcount, 1e-5);

    i32x4 acc[4][4];
#pragma unroll
    for (int i = 0; i < 4; ++i)
#pragma unroll
        for (int j = 0; j < 4; ++j) acc[i][j] = i32x4{0,0,0,0};

    for (int kt = 0; kt < 1152; kt += 128) {
#pragma unroll
        for (int c = 0; c < 4; ++c) {
            int idx = tid + c*256;
            int row = idx & 127, kslot = idx >> 7;
            i32x4 v = {0,0,0,0};
            if (m0 + row < M)
                v = *reinterpret_cast<const i32x4*>(A8 + (size_t)(m0+row)*1152 + kt + kslot*16);
            *reinterpret_cast<i32x4*>(&Als[kslot][row][0]) = v;
        }
#pragma unroll
        for (int c = 0; c < 4; ++c) {
            int idx = tid + c*256;
            int row = idx & 127, kslot = idx >> 7;
            i32x4 pv = *reinterpret_cast<const i32x4*>(W8 + (size_t)(n0+row)*1152 + kt + kslot*16);
            *reinterpret_cast<i32x4*>(&Bls[kslot][row][0]) = pv;
        }
        __syncthreads();
#pragma unroll
        for (int kk = 0; kk < 2; ++kk) {
            const int kb = kk*4 + ks;
            i32x4 a[4];
#pragma unroll
            for (int i = 0; i < 4; ++i)
                a[i] = *reinterpret_cast<const i32x4*>(&Als[kb][wr*64 + i*16 + fr][0]);
#pragma unroll
            for (int j = 0; j < 4; ++j) {
                i32x4 b = *reinterpret_cast<const i32x4*>(&Bls[kb][wc*64 + j*16 + fr][0]);
#pragma unroll
                for (int i = 0; i < 4; ++i)
                    acc[i][j] = __builtin_amdgcn_mfma_i32_16x16x64_i8(a[i], b, acc[i][j], 0, 0, 0);
            }
        }
        __syncthreads();
    }

#pragma unroll
    for (int i = 0; i < 4; ++i) {
#pragma unroll
        for (int r = 0; r < 4; ++r) {
            int row = m0 + wr*64 + i*16 + (lane>>4)*4 + r;
            if (row >= M) continue;
            double mul = dqw / ascale[row];
#pragma unroll
            for (int j = 0; j < 4; ++j) {
                int col = n0 + wc*64 + j*16 + (lane & 15);
                double v = (double)acc[i][j][r] * mul;
                if (g == 0)      v = 1.0/(1.0+exp(-v));          // sigma(F)
                else if (g == 1) v = v/(1.0+exp(-v));            // silu(I)
                C[(size_t)row*1152 + col] = v;
            }
        }
    }
}

// ---------------------------------------------------------------------------
extern "C" void kernel_launch(void* const* d_in, const int* in_sizes, int n_in,
                              void* d_out, int out_size, void* d_ws, size_t ws_size,
                              hipStream_t stream)
{
    (void)in_sizes; (void)n_in; (void)out_size;
    auto in = [&](int i){ return (const float*)d_in[i]; };

    const float *X = in(0), *T = in(1), *Y = in(2), *XC = in(3), *REF = in(4);
    const float *xe_w = in(6), *xe_b = in(7), *pos = in(8);
    const float *te_w1 = in(9), *te_b1 = in(10), *te_w2 = in(11), *te_b2 = in(12);
    const float *pp_w = in(13), *pp_b = in(14);
    const float *sa_pe_w = in(15), *sa_pe_b = in(16);
    const float *sa_ln_g = in(17), *sa_ln_b = in(18);
    const float *sa_gate_w = in(19), *sa_down_w = in(20);
    const float *sa_dc_w = in(21), *sa_dc_b = in(22);
    const float *ada_w = in(23), *ada_b = in(24);
    const float *sa_wi = in(25), *sa_wf = in(26), *sa_wg = in(27), *sa_wo = in(28);
    const float *mv_wi = in(29), *mv_wf = in(30), *mv_wg = in(31), *mv_wo = in(32);
    const float *rf_wi = in(33), *rf_wf = in(34), *rf_wg = in(35), *rf_wo = in(36);
    const float *gate_w = in(37), *down_w = in(38);
    const float *fl_w = in(39), *fl_b = in(40), *fl_ada_w = in(41), *fl_ada_b = in(42);
    float* OUT = (float*)d_out;

    // ---------- workspace layout ----------
    size_t off = 0;
    auto AL = [&](size_t bytes){ off = (off+255)&~(size_t)255; size_t r = off; off += bytes; return r; };
    const size_t oScale = AL(37*8);
    const size_t oPart  = AL(37*32*8);
    const size_t oProbe = AL(64*4*8);
    const size_t oFlag  = AL(256);
    const size_t oSM1 = AL(8*1152*8), oSM2 = AL(8*1152*8), oSM3 = AL(8*1152*8);
    const size_t oCB  = AL(8*1152*8);
    const size_t oMOD = AL(8*6912*8);
    const size_t oH   = AL((size_t)8192*1152*8);    // 75.5 MB; reused as OB later
    const size_t oINT = AL((size_t)1024*4608*8);
    const size_t oF0  = AL((size_t)2048*1152*8);    // also ACC
    const size_t oXT  = AL((size_t)2048*1152*8);
    const size_t oFB  = AL((size_t)2048*1152*8);
    const size_t oIB  = AL((size_t)2048*1152*8);
    const size_t oGB  = AL((size_t)2048*1152*8);
    const size_t oRO  = AL((size_t)512*1152*8);
    const size_t oQ8X = AL((size_t)2048*1152);
    const size_t oQ8I = AL((size_t)1024*4608);
    const size_t oQ8O = AL((size_t)2048*1152);
    const size_t oQ8R = AL((size_t)512*1152);
    const size_t oQ8T = AL((size_t)8*1152);
    const size_t oQ8C = AL((size_t)8*1152);
    const size_t oDSX = AL(2048*8), oDSI = AL(1024*8), oDSO = AL(2048*8);
    const size_t oDSR = AL(512*8),  oDST = AL(8*8),    oDSC = AL(8*8);
    if (off > ws_size) return;

    // ---------- weight list + optional pre-ternarized region ----------
    WList wl{}; WOffs wo{};
    long long wn[37];
    int nw = 0;
    auto addw = [&](const float* w, long long n){ wl.p[nw]=w; wl.n[nw]=n; wn[nw]=n; nw++; };
    addw(te_w1, 294912); addw(te_w2, 1327104); addw(pp_w, 884736);
    addw(sa_gate_w, 10616832); addw(sa_down_w, 5308416);
    for (int l = 0; l < 2; ++l) {
        addw(ada_w + (size_t)l*7962624, 7962624);
        addw(sa_wi + (size_t)l*1327104, 1327104);
        addw(sa_wf + (size_t)l*1327104, 1327104);
        addw(sa_wg + (size_t)l*1327104, 1327104);
        addw(sa_wo + (size_t)l*1327104, 1327104);
        addw(mv_wi + (size_t)l*1327104, 1327104);
        addw(mv_wf + (size_t)l*1327104, 1327104);
        addw(mv_wg + (size_t)l*1327104, 1327104);
        addw(mv_wo + (size_t)l*1327104, 1327104);
        addw(rf_wi + (size_t)l*1327104, 1327104);
        addw(rf_wf + (size_t)l*1327104, 1327104);
        addw(rf_wg + (size_t)l*1327104, 1327104);
        addw(rf_wo + (size_t)l*1327104, 1327104);
        addw(gate_w + (size_t)l*10616832, 10616832);
        addw(down_w + (size_t)l*5308416, 5308416);
    }
    addw(fl_ada_w, 2654208); addw(fl_w, 36864);

    size_t off_saved = off;
    long long wtot = 0;
    for (int i = 0; i < 37; ++i) { wo.o[i] = wtot; wtot += (wn[i] + 255) & ~255LL; }
    const size_t oW8 = AL((size_t)wtot);
    const bool useW8 = (off <= ws_size);
    if (!useW8) off = off_saved;

    // ---------- optional transposed down-conv weight (f32, 21 MB) ----------
    size_t off_wt = off;
    const size_t oWt = AL((size_t)1152*4608*4);
    const bool useWt = (off <= ws_size);
    if (!useWt) off = off_wt;

    // ---------- tiered SA/MLP chunk enlargement (row-independent) ----------
    int schunk = 1024;
    size_t oINTb = 0, oQ8Ib = 0, oQ8Xb = 0, oDSXb = 0, oDSIb = 0;
    if (useW8) {
        size_t off_w8 = off;
        oINTb = AL((size_t)4096*4608*8); oQ8Ib = AL((size_t)4096*4608);
        oQ8Xb = AL((size_t)4096*1152);   oDSXb = AL(4096*8); oDSIb = AL(4096*8);
        if (off <= ws_size) schunk = 4096;
        else {
            off = off_w8;
            oINTb = AL((size_t)2048*4608*8); oQ8Ib = AL((size_t)2048*4608); oDSIb = AL(2048*8);
            if (off <= ws_size) schunk = 2048;
            else off = off_w8;
        }
    }

    char* w8p = (char*)d_ws;
    double* scales = (double*)(w8p + oScale);
    double* parts  = (double*)(w8p + oPart);
    double* probeD = (double*)(w8p + oProbe);
    int*    mflag  = (int*)(w8p + oFlag);
    double *SM1=(double*)(w8p+oSM1), *SM2=(double*)(w8p+oSM2), *SM3=(double*)(w8p+oSM3);
    double *CB=(double*)(w8p+oCB), *MOD=(double*)(w8p+oMOD);
    double *H=(double*)(w8p+oH), *INT=(double*)(w8p+oINT);
    double *F0=(double*)(w8p+oF0), *XT=(double*)(w8p+oXT);
    double *FB=(double*)(w8p+oFB), *IB=(double*)(w8p+oIB), *GB=(double*)(w8p+oGB);
    double *ACC=F0, *OB=H, *RO=(double*)(w8p+oRO);
    signed char *Q8X=(signed char*)(w8p+oQ8X), *Q8I=(signed char*)(w8p+oQ8I);
    signed char *Q8O=(signed char*)(w8p+oQ8O), *Q8R=(signed char*)(w8p+oQ8R);
    signed char *Q8T=(signed char*)(w8p+oQ8T), *Q8C=(signed char*)(w8p+oQ8C);
    double *DSX=(double*)(w8p+oDSX), *DSI=(double*)(w8p+oDSI), *DSO=(double*)(w8p+oDSO);
    double *DSR=(double*)(w8p+oDSR), *DST=(double*)(w8p+oDST), *DSC=(double*)(w8p+oDSC);
    signed char* W8 = (signed char*)(w8p + oW8);
    float* Wt = (float*)(w8p + oWt);

    double*      INTs = (schunk > 1024) ? (double*)(w8p + oINTb) : INT;
    signed char* Q8Is = (schunk > 1024) ? (signed char*)(w8p + oQ8Ib) : Q8I;
    double*      DSIs = (schunk > 1024) ? (double*)(w8p + oDSIb) : DSI;
    signed char* Q8Xs = (schunk == 4096) ? (signed char*)(w8p + oQ8Xb) : Q8X;
    double*      DSXs = (schunk == 4096) ? (double*)(w8p + oDSXb) : DSX;

    // ---------- probe + scales + ternarize + dc-w transpose ----------
    k_mfma64_probe<<<1, 64, 0, stream>>>(probeD);
    k_mfma64_check<<<1, 64, 0, stream>>>(probeD, mflag);
    k_abssum_all<<<dim3(32,37), 256, 0, stream>>>(wl, parts);
    k_abssum_fin<<<37, 64, 0, stream>>>(parts, scales);
    if (useW8)
        k_ternarize<<<dim3(64,37), 256, 0, stream>>>(wl, wo, scales, W8);
    if (useWt)
        k_dcw_prep<<<1152, 256, 0, stream>>>(sa_dc_w, Wt);

    // ---------- launch helpers ----------
    auto qgemm = [&](const signed char* A8, const double* as, const float* Win, int slot,
                     const float* b, double* Cout, int M, int N, int K, int accum){
        int gm = (M+127)/128, gn = (N+127)/128;
        if (useW8)
            k_qgemm<0,1><<<gm*gn, 256, 0, stream>>>(A8, as, Win, W8 + wo.o[slot],
                                                    scales+slot, wn[slot], b, Cout, M, N, K, accum, gm);
        else
            k_qgemm<0,0><<<gm*gn, 256, 0, stream>>>(A8, as, Win, nullptr,
                                                    scales+slot, wn[slot], b, Cout, M, N, K, accum, gm);
    };
    auto qgemmGate = [&](const signed char* A8, const double* as, const float* Win, int slot,
                         double* Cout, int M){
        int gm = (M+127)/128;
        if (useW8)
            k_qgemm<1,1><<<gm*36, 256, 0, stream>>>(A8, as, Win, W8 + wo.o[slot],
                                                    scales+slot, wn[slot], nullptr, Cout, M, 4608, 1152, 0, gm);
        else
            k_qgemm<1,0><<<gm*36, 256, 0, stream>>>(A8, as, Win, nullptr,
                                                    scales+slot, wn[slot], nullptr, Cout, M, 4608, 1152, 0, gm);
    };
    auto fig = [&](const signed char* A8, const double* as, int sF, int sI, int sG,
                   const float* wF, const float* wI, const float* wG, int M,
                   int n_outer, long long ostr, int n_inner, long long tstr, int Tlen){
        if (useW8) {
            W3 w3{ {W8+wo.o[sF], W8+wo.o[sI], W8+wo.o[sG]},
                   {scales+sF, scales+sI, scales+sG},
                   {FB, IB, GB} };
            int gm = M/128;
            k_qgemm3<<<gm*27, 256, 0, stream>>>(A8, as, w3, 1327104, M, gm);
            long long nch = (long long)n_outer*n_inner;
            k_scan3<<<(unsigned)((nch+255)/256), 256, 0, stream>>>(FB, IB, OB, n_outer, ostr, n_inner, tstr, Tlen);
        } else {
            qgemm(A8, as, wF, sF, nullptr, FB, M, 1152, 1152, 0);
            qgemm(A8, as, wI, sI, nullptr, IB, M, 1152, 1152, 0);
            qgemm(A8, as, wG, sG, nullptr, GB, M, 1152, 1152, 0);
            long long nel = (long long)M*1152;
            k_gatepre<<<(unsigned)((nel+255)/256), 256, 0, stream>>>(FB, IB, nel);
            long long nch = (long long)n_outer*n_inner;
            k_scan2<<<(unsigned)((nch+255)/256), 256, 0, stream>>>(FB, IB, OB, n_outer, ostr, n_inner, tstr, Tlen);
        }
    };

    // ---------- conditioning vector c ----------
    k_temb<<<8, 128, 0, stream>>>(T, SM1);
    k_rsq8<double><<<8, 256, 0, stream>>>(SM1, Q8T, DST, 256, 0);
    qgemm(Q8T, DST, te_w1, 0, te_b1, SM3, 8, 1152, 256, 0);
    k_rsq8<double><<<8, 256, 0, stream>>>(SM3, Q8T, DST, 1152, 1);
    qgemm(Q8T, DST, te_w2, 1, te_b2, SM2, 8, 1152, 1152, 0);
    k_rsq8<float><<<8, 256, 0, stream>>>(Y, Q8T, DST, 768, 0);
    qgemm(Q8T, DST, pp_w, 2, pp_b, SM3, 8, 1152, 768, 0);
    k_add<<<36, 256, 0, stream>>>(SM2, SM3, CB, 9216);
    k_rsq8<double><<<8, 256, 0, stream>>>(CB, Q8C, DSC, 1152, 1);

    // ---------- spatial adapter: patch embed + block 0 only ----------
    k_dgemm<1,0><<<18*128, 256, 0, stream>>>(XC, sa_pe_w, sa_pe_b, H, 8192, 1152, 1536, 18, mflag);
    {
        const int nch = 8192 / schunk;
        for (int ch = 0; ch < nch; ++ch) {
            double* Hrow = H + (size_t)ch*schunk*1152;
            k_lnq8<<<schunk, 256, 1152*8, stream>>>(Hrow, Q8Xs, DSXs, 1152, sa_ln_g, sa_ln_b,
                                                    nullptr, nullptr, 0, 1e-5);
            qgemmGate(Q8Xs, DSXs, sa_gate_w, 3, INTs, schunk);
            k_rsq8<double><<<schunk, 256, 0, stream>>>(INTs, Q8Is, DSIs, 4608, 0);
            qgemm(Q8Is, DSIs, sa_down_w, 4, nullptr, Hrow, schunk, 1152, 4608, 0);
        }
    }
    if (useWt)
        k_dgemm<2,0><<<18*32, 256, 0, stream>>>(H, Wt, sa_dc_b, F0, 2048, 1152, 4608, 18, mflag);
    else
        k_dgemm<2,1><<<18*32, 256, 0, stream>>>(H, sa_dc_w, sa_dc_b, F0, 2048, 1152, 4608, 18, mflag);

    // ---------- patchify latents + pos + feats0 ----------
    k_patchify<<<9216, 256, 0, stream>>>(X, xe_w, xe_b, pos, F0, XT);
    k_rsq8<float><<<512, 256, 0, stream>>>(REF, Q8R, DSR, 1152, 0);

    // ---------- transformer blocks (OB aliases dead H) ----------
    for (int l = 0; l < 2; ++l) {
        int sb = 5 + l*15;
        const float *wada = ada_w + (size_t)l*7962624, *bada = ada_b + (size_t)l*6912;
        const float *swi = sa_wi + (size_t)l*1327104, *swf = sa_wf + (size_t)l*1327104;
        const float *swg = sa_wg + (size_t)l*1327104, *swo = sa_wo + (size_t)l*1327104;
        const float *mwi = mv_wi + (size_t)l*1327104, *mwf = mv_wf + (size_t)l*1327104;
        const float *mwg = mv_wg + (size_t)l*1327104, *mwo = mv_wo + (size_t)l*1327104;
        const float *rwi = rf_wi + (size_t)l*1327104, *rwf = rf_wf + (size_t)l*1327104;
        const float *rwg = rf_wg + (size_t)l*1327104, *rwo = rf_wo + (size_t)l*1327104;
        const float *wgt = gate_w + (size_t)l*10616832, *wdn = down_w + (size_t)l*5308416;

        qgemm(Q8C, DSC, wada, sb+0, bada, MOD, 8, 6912, 1152, 0);

        k_lnq8<<<2048, 256, 1152*8, stream>>>(XT, Q8X, DSX, 1152, nullptr, nullptr,
                                              MOD+0, MOD+1152, 6912, 1e-6);

        // self attention (seq = 256 tokens)
        fig(Q8X, DSX, sb+2, sb+1, sb+3, swf, swi, swg, 2048, 8, 294912LL, 1152, 1152LL, 256);
        k_ogateq8<<<2048, 256, 1152*8, stream>>>(OB, GB, Q8O, DSO, 1152);
        qgemm(Q8O, DSO, swo, sb+4, nullptr, ACC, 2048, 1152, 1152, 0);

        // multi-view attention (seq = 4 views; token layout unchanged)
        fig(Q8X, DSX, sb+6, sb+5, sb+7, mwf, mwi, mwg, 2048, 2, 1179648LL, 294912, 294912LL, 4);
        k_ogateq8<<<2048, 256, 1152*8, stream>>>(OB, GB, Q8O, DSO, 1152);
        qgemm(Q8O, DSO, mwo, sb+8, nullptr, ACC, 2048, 1152, 1152, 1);   // +=

        // ref attention on 2 unique batches
        fig(Q8R, DSR, sb+10, sb+9, sb+11, rwf, rwi, rwg, 512, 2, 294912LL, 1152, 1152LL, 256);
        k_ogateq8<<<512, 256, 1152*8, stream>>>(OB, GB, Q8O, DSO, 1152);
        qgemm(Q8O, DSO, rwo, sb+12, nullptr, RO, 512, 1152, 1152, 0);

        k_resid_attn<<<9216, 256, 0, stream>>>(XT, ACC, RO, MOD);

        // MLP
        k_lnq8<<<2048, 256, 1152*8, stream>>>(XT, Q8X, DSX, 1152, nullptr, nullptr,
                                              MOD+3*1152, MOD+4*1152, 6912, 1e-6);
        if (schunk >= 2048) {
            qgemmGate(Q8X, DSX, wgt, sb+13, INTs, 2048);
            k_rsq8<double><<<2048, 256, 0, stream>>>(INTs, Q8Is, DSIs, 4608, 0);
            qgemm(Q8Is, DSIs, wdn, sb+14, nullptr, OB, 2048, 1152, 4608, 0);
        } else {
            for (int ch = 0; ch < 2; ++ch) {
                qgemmGate(Q8X + (size_t)ch*1024*1152, DSX + ch*1024, wgt, sb+13, INT, 1024);
                k_rsq8<double><<<1024, 256, 0, stream>>>(INT, Q8I, DSI, 4608, 0);
                qgemm(Q8I, DSI, wdn, sb+14, nullptr, OB + (size_t)ch*1024*1152, 1024, 1152, 4608, 0);
            }
        }
        k_resid_mlp<<<9216, 256, 0, stream>>>(XT, OB, MOD);
    }

    // ---------- final layer + unpatchify ----------
    qgemm(Q8C, DSC, fl_ada_w, 35, fl_ada_b, MOD, 8, 2304, 1152, 0);
    k_lnq8<<<2048, 256, 1152*8, stream>>>(XT, Q8X, DSX, 1152, nullptr, nullptr,
                                          MOD+0, MOD+1152, 2304, 1e-6);
    qgemm(Q8X, DSX, fl_w, 36, fl_b, FB, 2048, 32, 1152, 0);
    k_unpatch<<<256, 256, 0, stream>>>(FB, OUT);
}